// Round 10
// baseline (1523.063 us; speedup 1.0000x reference)
//
#include <hip/hip_runtime.h>
#include <hip/hip_bf16.h>

#define NUM_E   20000
#define H_DIM   200
#define TD_DIM  48
#define HD_DIM  24
#define L_HIST  32
#define N_HIST  3
#define E_EDGES 200000
#define BATCH   512

// ---------------------------------------------------------------- utilities

__device__ inline float wave_sum64(float x) {
    #pragma unroll
    for (int m = 1; m < 64; m <<= 1) x += __shfl_xor(x, m);
    return x;
}

__device__ inline ushort f2bf(float f) {
    unsigned u = __float_as_uint(f);
    u += 0x7fffu + ((u >> 16) & 1u);
    return (ushort)(u >> 16);
}
__device__ inline float bf2f(ushort u) {
    return __uint_as_float(((unsigned)u) << 16);
}
__device__ inline float4 bf4_to_f4(ushort4 v) {
    return (float4){bf2f(v.x), bf2f(v.y), bf2f(v.z), bf2f(v.w)};
}

__global__ void fill_i32(int* __restrict__ p, long n, int v) {
    long i = (long)blockIdx.x * blockDim.x + threadIdx.x;
    if (i < n) p[i] = v;
}

__global__ void bias_sum(float* __restrict__ bsum, const float* __restrict__ b_ih,
                         const float* __restrict__ b_hh) {
    int j = blockIdx.x * 256 + threadIdx.x;
    if (j < 600) bsum[j] = b_ih[j] + b_hh[j];
}

__global__ void cvt_bf16_k(ushort* __restrict__ o, const float* __restrict__ in, long n) {
    long i = (long)blockIdx.x * 256 + threadIdx.x;
    if (i < n) o[i] = f2bf(in[i]);
}

// lo[i] = bf16(x[i] - f32(hi[i]))
__global__ void make_lo(ushort* __restrict__ lo, const float* __restrict__ x,
                        const ushort* __restrict__ hi, long n) {
    long i = (long)blockIdx.x * 256 + threadIdx.x;
    if (i < n) lo[i] = f2bf(x[i] - bf2f(hi[i]));
}

// in (R,C) row-major f32 -> o (C,R) row-major bf16
__global__ void tcvt_bf16_k(ushort* __restrict__ o, const float* __restrict__ in, int R, int C) {
    int i = blockIdx.x * 256 + threadIdx.x;
    if (i >= R * C) return;
    int r = i / C, c = i - r * C;
    o[(size_t)c * R + r] = f2bf(in[i]);
}

// ---------------------------------------------------------------- f32 split-K GEMM (B^T)
struct Segs {
    const float* A[4];
    const float* B[4];
    int lda[4], ldb[4], Ks[4];
    int nseg, Ktot;
};

__device__ inline void seg_find(const Segs& sg, int gk, int& s, int& loc) {
    s = 0; loc = gk;
    #pragma unroll
    for (int t = 0; t < 3; t++) {
        if (s + 1 < sg.nseg && loc >= sg.Ks[s]) { loc -= sg.Ks[s]; s++; }
    }
}

// Partial GEMM: P[kc][M][N] = A@B^T over k-chunk kc. BM=64, BN=64, BK=32.
__global__ __launch_bounds__(256) void sgemm_splitk(
    float* __restrict__ P, const Segs sg, int M, int N, int nbx, int nby,
    int KS, int tpc)
{
    __shared__ float As[32][68];
    __shared__ float Bs[32][68];

    int tot = nbx * nby;
    int tot_all = tot * KS;
    int chunk = (tot_all + 7) >> 3;
    int v = (int)(blockIdx.x & 7) * chunk + (int)(blockIdx.x >> 3);
    if (v >= tot_all) return;
    int kc = v / tot;
    int tile = v - kc * tot;
    int by = tile / nbx, bx = tile - by * nbx;
    const int bn = bx * 64;
    const int bm = by * 64;
    const int tid = threadIdx.x;
    const int m0 = (tid >> 4) * 4;
    const int n0 = (tid & 15) * 4;

    float acc[4][4];
    #pragma unroll
    for (int i = 0; i < 4; i++)
        #pragma unroll
        for (int j = 0; j < 4; j++) acc[i][j] = 0.f;

    const int Ktot = sg.Ktot;
    const int ntile = (Ktot + 31) / 32;
    const int kt0 = kc * tpc;
    const int kt1 = min(ntile, kt0 + tpc);

    const int a_m  = tid & 31;
    const int a_k4 = (tid >> 5) * 4;
    const int b1_n = tid & 63;
    const int b1_k = (tid >> 6) * 4;

    float4 ra[2], rb[2];
    auto loadA = [&](int k0) {
        int gk = k0 + a_k4;
        bool kin = gk < Ktot;
        int s = 0, loc = 0;
        if (kin) seg_find(sg, gk, s, loc);
        const float* Ab = sg.A[s];
        const int lda = sg.lda[s];
        #pragma unroll
        for (int r = 0; r < 2; r++) {
            int row = bm + a_m + 32 * r;
            float4 vv = {0.f, 0.f, 0.f, 0.f};
            if (kin && row < M) vv = *(const float4*)(Ab + (size_t)row * lda + loc);
            ra[r] = vv;
        }
    };
    auto loadB = [&](int k0) {
        #pragma unroll
        for (int r = 0; r < 2; r++) {
            int k4 = b1_k + 16 * r;
            int gk = k0 + k4;
            bool kin = gk < Ktot;
            int s = 0, loc = 0;
            if (kin) seg_find(sg, gk, s, loc);
            const float* Bb = sg.B[s];
            const int ldb = sg.ldb[s];
            int gn = bn + b1_n;
            float4 vv = {0.f, 0.f, 0.f, 0.f};
            if (kin && gn < N) vv = *(const float4*)(Bb + (size_t)gn * ldb + loc);
            rb[r] = vv;
        }
    };

    if (kt0 < kt1) {
        loadA(kt0 * 32); loadB(kt0 * 32);
        for (int t = kt0; t < kt1; t++) {
            #pragma unroll
            for (int r = 0; r < 2; r++) {
                int m = a_m + 32 * r;
                As[a_k4 + 0][m] = ra[r].x;
                As[a_k4 + 1][m] = ra[r].y;
                As[a_k4 + 2][m] = ra[r].z;
                As[a_k4 + 3][m] = ra[r].w;
            }
            #pragma unroll
            for (int r = 0; r < 2; r++) {
                int k4 = b1_k + 16 * r;
                Bs[k4 + 0][b1_n] = rb[r].x;
                Bs[k4 + 1][b1_n] = rb[r].y;
                Bs[k4 + 2][b1_n] = rb[r].z;
                Bs[k4 + 3][b1_n] = rb[r].w;
            }
            __syncthreads();
            if (t + 1 < kt1) { loadA((t + 1) * 32); loadB((t + 1) * 32); }
            #pragma unroll 8
            for (int kk = 0; kk < 32; kk++) {
                float4 b = *(float4*)&Bs[kk][n0];
                float4 av = *(float4*)&As[kk][m0];
                float a[4] = {av.x, av.y, av.z, av.w};
                #pragma unroll
                for (int i = 0; i < 4; i++) {
                    acc[i][0] += a[i] * b.x;
                    acc[i][1] += a[i] * b.y;
                    acc[i][2] += a[i] * b.z;
                    acc[i][3] += a[i] * b.w;
                }
            }
            __syncthreads();
        }
    }

    int col = bn + n0;
    if (col < N) {
        #pragma unroll
        for (int i = 0; i < 4; i++) {
            int row = bm + m0 + i;
            if (row < M) {
                float4 o = {acc[i][0], acc[i][1], acc[i][2], acc[i][3]};
                *(float4*)(P + ((size_t)kc * M + row) * N + col) = o;
            }
        }
    }
}

// out = relu(sum_kc P + bias)
__global__ void reduce_relu(float* __restrict__ out, const float* __restrict__ P,
                            const float* __restrict__ bias, int MN, int N, int KS)
{
    int i = blockIdx.x * 256 + threadIdx.x;
    if (i >= MN) return;
    float s = bias[i % N];
    for (int k = 0; k < KS; k++) s += P[(size_t)k * MN + i];
    out[i] = fmaxf(s, 0.f);
}

// qhi/qlo = hi/lo bf16 split of relu(sum_kc P + bias)
__global__ void reduce_relu_split(ushort* __restrict__ qhi, ushort* __restrict__ qlo,
                                  const float* __restrict__ P, const float* __restrict__ bias,
                                  int MN, int N, int KS)
{
    int i = blockIdx.x * 256 + threadIdx.x;
    if (i >= MN) return;
    float s = bias[i % N];
    for (int k = 0; k < KS; k++) s += P[(size_t)k * MN + i];
    s = fmaxf(s, 0.f);
    ushort h = f2bf(s);
    qhi[i] = h;
    qlo[i] = f2bf(s - bf2f(h));
}

// ---------------------------------------------------------------- bf16 MFMA multi-GEMM
// 4 INDEPENDENT waves per block; each wave owns one 32x32 output tile and a
// private 8KB LDS slice. LDS is used only for coalesced staging (global rows
// are loaded contiguously, then read back in MFMA fragment layout). Zero
// barriers: same-wave ds_write->ds_read ordering is enforced by the compiler
// via lgkmcnt; prefetch global loads wait at their use via counted vmcnt.
// This combines R4's wave-independence (no barrier convoy) with R5's
// coalescing (LDS staging) while avoiding both failure modes.
typedef __attribute__((ext_vector_type(8))) short bfrag;
typedef __attribute__((ext_vector_type(4))) float ffrag;

struct BfSegs {
    const ushort* A[3];
    const ushort* B[3];
    int lda[3], ldb[3], Ks[3];
    int nseg, Ktot;
};

__device__ inline void bseg_find(const BfSegs& sg, int gk, int& s, int& loc) {
    s = 0; loc = gk;
    #pragma unroll
    for (int t = 0; t < 2; t++) {
        if (s + 1 < sg.nseg && loc >= sg.Ks[s]) { loc -= sg.Ks[s]; s++; }
    }
}

// One GEMM description; tile bookkeeping in WAVE units (32x32 tiles).
// act: 0 none, 1 relu, 2 sigmoid.  flags: 1 = write f32 C, 2 = write bf16 Cb.
// order: 0 = A-reuse (consecutive waves share A rows), 1 = B-reuse.
struct GemmDesc {
    BfSegs sg;
    float* C;
    ushort* Cb;
    const float* bias;
    int M, N, ldc;
    int act, flags, order;
    int nbx, nby, blk0, nblk;   // nblk = nbx*nby wave-tiles
};

struct MultiArgs {
    GemmDesc d[3];
    int nd;
    int tot;        // total wave-tiles
};

template<int DI>
__device__ __forceinline__ void gemm_wave(const MultiArgs& ma, int gw,
                                          ushort* __restrict__ Als,
                                          ushort* __restrict__ Bls)
{
    const GemmDesc& D = ma.d[DI];
    const BfSegs& sg = D.sg;
    const int t0 = gw - D.blk0;
    int my, mx;
    if (D.order == 0) { my = t0 / D.nbx; mx = t0 - my * D.nbx; }
    else              { mx = t0 / D.nby; my = t0 - mx * D.nby; }
    const int bm = my * 32, bn = mx * 32;
    const int M = D.M, N = D.N;
    const int lane = (int)(threadIdx.x & 63);

    ffrag acc[2][2];
    #pragma unroll
    for (int i = 0; i < 2; i++)
        #pragma unroll
        for (int j = 0; j < 2; j++) acc[i][j] = (ffrag){0.f, 0.f, 0.f, 0.f};

    const int Ktot = sg.Ktot;
    const int nkt = (Ktot + 63) >> 6;

    // staging: 4 chunks of 16B per lane; c = i*64+lane; row = c>>3, kq = c&7
    // (8 consecutive lanes cover one row's 128B contiguously -> coalesced)
    int s_m[4], s_kq[4], s_wc[4];
    #pragma unroll
    for (int i = 0; i < 4; i++) {
        int c = i * 64 + lane;
        s_m[i] = c >> 3; s_kq[i] = c & 7;
        s_wc[i] = ((s_m[i] >> 4) * 2 + (s_kq[i] >> 2)) * 64 + (s_kq[i] & 3) * 16 + (s_m[i] & 15);
    }

    uint4 ra[4], rb[4];
    auto loadA = [&](int k0) {
        #pragma unroll
        for (int i = 0; i < 4; i++) {
            int gk = k0 + s_kq[i] * 8;
            int row = bm + s_m[i];
            uint4 vv = {0u, 0u, 0u, 0u};
            if (gk < Ktot && row < M) {
                int s, loc; bseg_find(sg, gk, s, loc);
                vv = *(const uint4*)(sg.A[s] + (size_t)row * sg.lda[s] + loc);
            }
            ra[i] = vv;
        }
    };
    auto loadB = [&](int k0) {
        #pragma unroll
        for (int i = 0; i < 4; i++) {
            int gk = k0 + s_kq[i] * 8;
            int gn = bn + s_m[i];
            uint4 vv = {0u, 0u, 0u, 0u};
            if (gk < Ktot && gn < N) {
                int s, loc; bseg_find(sg, gk, s, loc);
                vv = *(const uint4*)(sg.B[s] + (size_t)gn * sg.ldb[s] + loc);
            }
            rb[i] = vv;
        }
    };

    loadA(0); loadB(0);

    for (int t = 0; t < nkt; t++) {
        #pragma unroll
        for (int i = 0; i < 4; i++) *(uint4*)(&Als[s_wc[i] * 8]) = ra[i];
        #pragma unroll
        for (int i = 0; i < 4; i++) *(uint4*)(&Bls[s_wc[i] * 8]) = rb[i];

        if (t + 1 < nkt) { loadA((t + 1) << 6); loadB((t + 1) << 6); }

        #pragma unroll
        for (int kt = 0; kt < 2; kt++) {
            bfrag af[2], bf[2];
            #pragma unroll
            for (int i = 0; i < 2; i++)
                af[i] = *(const bfrag*)(&Als[((i * 2 + kt) * 64 + lane) * 8]);
            #pragma unroll
            for (int j = 0; j < 2; j++)
                bf[j] = *(const bfrag*)(&Bls[((j * 2 + kt) * 64 + lane) * 8]);
            #pragma unroll
            for (int i = 0; i < 2; i++)
                #pragma unroll
                for (int j = 0; j < 2; j++)
                    acc[i][j] = __builtin_amdgcn_mfma_f32_16x16x32_bf16(af[i], bf[j], acc[i][j], 0, 0, 0);
        }
    }

    const int rbase = (lane >> 4) * 4;
    const int cl = lane & 15;
    #pragma unroll
    for (int j = 0; j < 2; j++) {
        int col = bn + j * 16 + cl;
        if (col >= N) continue;
        float bv = D.bias ? D.bias[col] : 0.f;
        #pragma unroll
        for (int i = 0; i < 2; i++) {
            int mrow = bm + i * 16 + rbase;
            #pragma unroll
            for (int r = 0; r < 4; r++) {
                int row = mrow + r;
                if (row < M) {
                    float o = acc[i][j][r] + bv;
                    if (D.act == 1) o = fmaxf(o, 0.f);
                    else if (D.act == 2) o = 1.f / (1.f + expf(-o));
                    if (D.flags & 1) D.C[(size_t)row * D.ldc + col] = o;
                    if (D.flags & 2) D.Cb[(size_t)row * D.ldc + col] = f2bf(o);
                }
            }
        }
    }
}

__global__ __launch_bounds__(256) void mfma_multi(MultiArgs ma)
{
    __shared__ __align__(16) ushort lds[16384];   // 4 waves x (A 2048 + B 2048)

    const int w = (int)(threadIdx.x >> 6);
    ushort* Als = lds + w * 4096;
    ushort* Bls = Als + 2048;

    int tot = ma.tot;
    int nblk = (tot + 3) >> 2;
    int chunk = (nblk + 7) >> 3;
    int v = (int)(blockIdx.x & 7) * chunk + (int)(blockIdx.x >> 3);
    if (v >= nblk) return;
    int gw = v * 4 + w;
    if (gw >= tot) return;

    int di = 0;
    if (ma.nd > 1 && gw >= ma.d[1].blk0) di = 1;
    if (ma.nd > 2 && gw >= ma.d[2].blk0) di = 2;

    if (di == 0)      gemm_wave<0>(ma, gw, Als, Bls);
    else if (di == 1) gemm_wave<1>(ma, gw, Als, Bls);
    else              gemm_wave<2>(ma, gw, Als, Bls);
}

// ---------------------------------------------------------------- CSR build (all 3 graphs, hoisted)

// count over all 3 graphs: cnt[g*NUM_E + d]
__global__ void count_dst3(const int* __restrict__ dst, int* __restrict__ cnt) {
    long e = (long)blockIdx.x * 256 + threadIdx.x;
    if (e < (long)N_HIST * E_EDGES) {
        int g = (int)(e / E_EDGES);
        atomicAdd(&cnt[g * NUM_E + dst[e]], 1);
    }
}

// one block per graph (3 concurrent scans)
__global__ __launch_bounds__(1024) void scan_rows3(
    const int* __restrict__ cnt_all, int* __restrict__ row_start_all,
    int* __restrict__ cursor_all, float* __restrict__ degf_all,
    float* __restrict__ invd_all)
{
    __shared__ int part[1024];
    const int g = blockIdx.x;
    const int* cnt = cnt_all + g * NUM_E;
    int* row_start  = row_start_all + g * (NUM_E + 4);
    int* cursor     = cursor_all + g * NUM_E;
    float* degf     = degf_all + g * NUM_E;
    float* invd     = invd_all + g * NUM_E;

    const int CH = (NUM_E + 1023) / 1024;
    int t = threadIdx.x;
    int base = t * CH;
    int local[32];
    int s = 0;
    for (int j = 0; j < CH; j++) {
        int idx = base + j;
        int c = (idx < NUM_E) ? cnt[idx] : 0;
        local[j] = s; s += c;
    }
    part[t] = s;
    __syncthreads();
    for (int off = 1; off < 1024; off <<= 1) {
        int vv = (t >= off) ? part[t - off] : 0;
        __syncthreads();
        part[t] += vv;
        __syncthreads();
    }
    int pre = (t == 0) ? 0 : part[t - 1];
    for (int j = 0; j < CH; j++) {
        int idx = base + j;
        if (idx < NUM_E) {
            int rs = pre + local[j];
            row_start[idx] = rs;
            cursor[idx] = rs;
            int c = cnt[idx];
            degf[idx] = (float)c;
            invd[idx] = 1.f / fmaxf((float)c, 1.f);
        }
    }
    if (t == 1023) row_start[NUM_E] = part[1023];
}

__global__ void build_perm3(const int* __restrict__ src, const int* __restrict__ dst,
                            const int* __restrict__ etype, int* __restrict__ cursor_all,
                            int* __restrict__ ssrc_all, int* __restrict__ setype_all)
{
    long e = (long)blockIdx.x * 256 + threadIdx.x;
    if (e >= (long)N_HIST * E_EDGES) return;
    int g = (int)(e / E_EDGES);
    int pos = atomicAdd(&cursor_all[g * NUM_E + dst[e]], 1);
    ssrc_all[(long)g * E_EDGES + pos]   = src[e];
    setype_all[(long)g * E_EDGES + pos] = etype[e];
}

// ---------------------------------------------------------------- gathers (bf16 in/out)

__global__ __launch_bounds__(256) void seg_gather_norm_bf(
    ushort* __restrict__ bh, const ushort* __restrict__ bprev,
    const int* __restrict__ ssrc, const int* __restrict__ row_start,
    const float* __restrict__ invd)
{
    int v = blockIdx.x * 4 + (threadIdx.x >> 6);
    int lane = threadIdx.x & 63;
    if (v >= NUM_E) return;
    int s0 = row_start[v], s1 = row_start[v + 1];
    bool act = lane < 50;
    float4 acc = {0.f, 0.f, 0.f, 0.f};
    int j = s0;
    for (; j + 1 < s1; j += 2) {
        int sa = ssrc[j], sb = ssrc[j + 1];
        if (act) {
            float4 xa = bf4_to_f4(*(const ushort4*)(bprev + (long)sa * H_DIM + lane * 4));
            float4 xb = bf4_to_f4(*(const ushort4*)(bprev + (long)sb * H_DIM + lane * 4));
            acc.x += xa.x + xb.x; acc.y += xa.y + xb.y;
            acc.z += xa.z + xb.z; acc.w += xa.w + xb.w;
        }
    }
    if (j < s1) {
        int sa = ssrc[j];
        if (act) {
            float4 xa = bf4_to_f4(*(const ushort4*)(bprev + (long)sa * H_DIM + lane * 4));
            acc.x += xa.x; acc.y += xa.y; acc.z += xa.z; acc.w += xa.w;
        }
    }
    float iv = invd[v];
    acc.x *= iv; acc.y *= iv; acc.z *= iv; acc.w *= iv;
    float ss = act ? (acc.x*acc.x + acc.y*acc.y + acc.z*acc.z + acc.w*acc.w) : 0.f;
    ss = wave_sum64(ss);
    float r = 1.f / fmaxf(sqrtf(ss), 1e-12f);
    if (act) {
        ushort4 ob = {f2bf(acc.x * r), f2bf(acc.y * r), f2bf(acc.z * r), f2bf(acc.w * r)};
        *(ushort4*)(bh + (long)v * H_DIM + lane * 4) = ob;
    }
}

__global__ __launch_bounds__(256) void seg_gather_layer_bf(
    ushort* __restrict__ btmp, const ushort* __restrict__ bh, const ushort* __restrict__ brel,
    const int* __restrict__ ssrc, const int* __restrict__ setype,
    const int* __restrict__ row_start, const float* __restrict__ invd)
{
    int v = blockIdx.x * 4 + (threadIdx.x >> 6);
    int lane = threadIdx.x & 63;
    if (v >= NUM_E) return;
    int s0 = row_start[v], s1 = row_start[v + 1];
    bool act = lane < 50;
    float4 acc = {0.f, 0.f, 0.f, 0.f};
    int j = s0;
    for (; j + 1 < s1; j += 2) {
        int sa = ssrc[j], ta = setype[j];
        int sb = ssrc[j + 1], tb = setype[j + 1];
        if (act) {
            float4 xa = bf4_to_f4(*(const ushort4*)(bh   + (long)sa * H_DIM + lane * 4));
            float4 ya = bf4_to_f4(*(const ushort4*)(brel + (long)ta * H_DIM + lane * 4));
            float4 xb = bf4_to_f4(*(const ushort4*)(bh   + (long)sb * H_DIM + lane * 4));
            float4 yb = bf4_to_f4(*(const ushort4*)(brel + (long)tb * H_DIM + lane * 4));
            acc.x += (xa.x + ya.x) + (xb.x + yb.x);
            acc.y += (xa.y + ya.y) + (xb.y + yb.y);
            acc.z += (xa.z + ya.z) + (xb.z + yb.z);
            acc.w += (xa.w + ya.w) + (xb.w + yb.w);
        }
    }
    if (j < s1) {
        int s = ssrc[j];
        int t = setype[j];
        if (act) {
            float4 x = bf4_to_f4(*(const ushort4*)(bh   + (long)s * H_DIM + lane * 4));
            float4 y = bf4_to_f4(*(const ushort4*)(brel + (long)t * H_DIM + lane * 4));
            acc.x += x.x + y.x; acc.y += x.y + y.y;
            acc.z += x.z + y.z; acc.w += x.w + y.w;
        }
    }
    float iv = invd[v];
    if (act) {
        ushort4 ob = {f2bf(acc.x * iv), f2bf(acc.y * iv), f2bf(acc.z * iv), f2bf(acc.w * iv)};
        *(ushort4*)(btmp + (long)v * H_DIM + lane * 4) = ob;
    }
}

// ---------------------------------------------------------------- row kernels

__global__ __launch_bounds__(256) void l2norm_rows4(
    float* __restrict__ out, ushort* __restrict__ bout,
    const float* __restrict__ in, int nrows)
{
    int v = blockIdx.x * 4 + (threadIdx.x >> 6);
    int lane = threadIdx.x & 63;
    if (v >= nrows) return;
    bool act = lane < 50;
    float4 x = {0.f, 0.f, 0.f, 0.f};
    if (act) x = *(const float4*)(in + (long)v * H_DIM + lane * 4);
    float ss = x.x*x.x + x.y*x.y + x.z*x.z + x.w*x.w;
    ss = wave_sum64(ss);
    float r = 1.f / fmaxf(sqrtf(ss), 1e-12f);
    if (act) {
        long base = (long)v * H_DIM + lane * 4;
        float4 o = {x.x * r, x.y * r, x.z * r, x.w * r};
        *(float4*)(out + base) = o;
        if (bout) {
            ushort4 ob = {f2bf(o.x), f2bf(o.y), f2bf(o.z), f2bf(o.w)};
            *(ushort4*)(bout + base) = ob;
        }
    }
}

__global__ __launch_bounds__(256) void l2norm_bf4(ushort* __restrict__ b, int nrows)
{
    int v = blockIdx.x * 4 + (threadIdx.x >> 6);
    int lane = threadIdx.x & 63;
    if (v >= nrows) return;
    bool act = lane < 50;
    float4 x = {0.f, 0.f, 0.f, 0.f};
    long base = (long)v * H_DIM + lane * 4;
    if (act) x = bf4_to_f4(*(const ushort4*)(b + base));
    float ss = x.x*x.x + x.y*x.y + x.z*x.z + x.w*x.w;
    ss = wave_sum64(ss);
    float r = 1.f / fmaxf(sqrtf(ss), 1e-12f);
    if (act) {
        ushort4 ob = {f2bf(x.x * r), f2bf(x.y * r), f2bf(x.z * r), f2bf(x.w * r)};
        *(ushort4*)(b + base) = ob;
    }
}

// 3 graphs x 2 rows x 48 bf16 time-encoding table (row stride 64)
__global__ void tenc_table3(ushort* __restrict__ tbl, const float* __restrict__ af,
                            const float* __restrict__ ap, const float* __restrict__ cf,
                            const float* __restrict__ cp)
{
    int j = blockIdx.x * 256 + threadIdx.x;
    if (j >= 384) return;
    int g = j >> 7;
    int r = j & 127;
    int half = r >> 6;
    int jj = r & 63;
    if (jj >= TD_DIM) return;
    float tcnt = (float)(N_HIST - 1 - g);
    float t = half ? 100.0f : tcnt;
    float val;
    if (jj < HD_DIM) val = tanhf((t + 1.f) * af[jj] + ap[jj]);
    else             val = cosf(t * cf[jj - HD_DIM] + cp[jj - HD_DIM]);
    tbl[g * 128 + half * 64 + jj] = f2bf(val);
}

// bte3[g][v][:] = tbl[g][deg>0 ? 0 : 1][:]  (uint4 copies)
__global__ void tenc_fill3(ushort* __restrict__ bte3, const float* __restrict__ degf_all,
                           const ushort* __restrict__ tbl)
{
    long idx = (long)blockIdx.x * 256 + threadIdx.x;
    if (idx >= (long)N_HIST * NUM_E * 6) return;
    int g = (int)(idx / (NUM_E * 6));
    int rem = (int)(idx - (long)g * NUM_E * 6);
    int v = rem / 6, c = rem - v * 6;
    int base = (degf_all[g * NUM_E + v] > 0.f) ? 0 : 64;
    *(uint4*)(bte3 + ((long)g * NUM_E + v) * TD_DIM + c * 8) =
        *(const uint4*)(tbl + g * 128 + base + c * 8);
}

__global__ __launch_bounds__(256) void gru_fused(
    float* __restrict__ prev, ushort* __restrict__ bprev, const float* __restrict__ rz,
    const float* __restrict__ iN, const float* __restrict__ hN)
{
    int v = blockIdx.x * 4 + (threadIdx.x >> 6);
    int lane = threadIdx.x & 63;
    if (v >= NUM_E) return;
    bool act = lane < 50;
    long b200 = (long)v * H_DIM + lane * 4;
    long b400 = (long)v * 400 + lane * 4;
    float4 o = {0.f, 0.f, 0.f, 0.f};
    if (act) {
        float4 r4 = *(const float4*)(rz + b400);
        float4 z4 = *(const float4*)(rz + b400 + 200);
        float4 n4 = *(const float4*)(iN + b200);
        float4 g4 = *(const float4*)(hN + b200);
        float4 p4 = *(const float4*)(prev + b200);
        float ngx = tanhf(n4.x + r4.x * g4.x);
        float ngy = tanhf(n4.y + r4.y * g4.y);
        float ngz = tanhf(n4.z + r4.z * g4.z);
        float ngw = tanhf(n4.w + r4.w * g4.w);
        o.x = (1.f - z4.x) * ngx + z4.x * p4.x;
        o.y = (1.f - z4.y) * ngy + z4.y * p4.y;
        o.z = (1.f - z4.z) * ngz + z4.z * p4.z;
        o.w = (1.f - z4.w) * ngw + z4.w * p4.w;
    }
    float ss = o.x*o.x + o.y*o.y + o.z*o.z + o.w*o.w;
    ss = wave_sum64(ss);
    float r = 1.f / fmaxf(sqrtf(ss), 1e-12f);
    if (act) {
        float4 wv = {o.x * r, o.y * r, o.z * r, o.w * r};
        *(float4*)(prev + b200) = wv;
        ushort4 ob = {f2bf(wv.x), f2bf(wv.y), f2bf(wv.z), f2bf(wv.w)};
        *(ushort4*)(bprev + b200) = ob;
    }
}

// ---------------------------------------------------------------- batch head

__global__ void gather_qs_qr3(float* __restrict__ qs3, float* __restrict__ qr3,
                              const float* __restrict__ out, const float* __restrict__ reln,
                              const int* __restrict__ data)
{
    long i = (long)blockIdx.x * 256 + threadIdx.x;
    if (i >= (long)BATCH * H_DIM) return;
    int b = (int)(i / H_DIM), j = (int)(i % H_DIM);
    float vs = out[(long)data[b * 4 + 0] * H_DIM + j];
    float vr = reln[(long)data[b * 4 + 1] * H_DIM + j];
    const long S = (long)BATCH * H_DIM;
    qs3[i] = vs; qs3[i + S] = vs; qs3[i + 2*S] = vs;
    qr3[i] = vr; qr3[i + S] = vr; qr3[i + 2*S] = vr;
}

__global__ __launch_bounds__(64) void semb_kernel(
    float* __restrict__ semb, const float* __restrict__ out,
    const int* __restrict__ his_idx, const int* __restrict__ his_len)
{
    int b = blockIdx.x, k = blockIdx.y;
    int lane = threadIdx.x;
    int ln = his_len[b * 3 + k];
    if (ln > L_HIST) ln = L_HIST;
    float vals[4] = {0.f, 0.f, 0.f, 0.f};
    for (int l = 0; l < ln; l++) {
        int idx = his_idx[((long)b * 3 + k) * L_HIST + l];
        #pragma unroll
        for (int t = 0; t < 4; t++) {
            int j = lane + t * 64;
            if (j < H_DIM) vals[t] += out[(long)idx * H_DIM + j];
        }
    }
    float scale = 1.f / fmaxf((float)ln, 1.f);
    float ss = 0.f;
    #pragma unroll
    for (int t = 0; t < 4; t++) { vals[t] *= scale; ss += vals[t] * vals[t]; }
    ss = wave_sum64(ss);
    float r = 1.f / fmaxf(sqrtf(ss), 1e-12f);
    #pragma unroll
    for (int t = 0; t < 4; t++) {
        int j = lane + t * 64;
        if (j < H_DIM) semb[((long)k * BATCH + b) * H_DIM + j] = vals[t] * r;
    }
}

__global__ void tenc_batch(float* __restrict__ teb, const int* __restrict__ his_len,
                           const float* __restrict__ af, const float* __restrict__ ap,
                           const float* __restrict__ cf, const float* __restrict__ cp)
{
    int idx = blockIdx.x * 256 + threadIdx.x;
    if (idx >= 3 * BATCH * TD_DIM) return;
    int k = idx / (BATCH * TD_DIM);
    int rem = idx - k * (BATCH * TD_DIM);
    int b = rem / TD_DIM, j = rem % TD_DIM;
    int ln = his_len[b * 3 + k];
    float t = (ln > 0) ? (float)(2 - k) : 100.0f;
    float val;
    if (j < HD_DIM) val = tanhf((t + 1.f) * af[j] + ap[j]);
    else            val = cosf(t * cf[j - HD_DIM] + cp[j - HD_DIM]);
    teb[idx] = val;
}

__global__ __launch_bounds__(256) void att_logits_rows(
    float* __restrict__ atts, const float* __restrict__ a,
    const float* __restrict__ Wc_w, const float* __restrict__ Wc_b)
{
    int row = blockIdx.x * 4 + (threadIdx.x >> 6);
    int lane = threadIdx.x & 63;
    if (row >= 3 * BATCH) return;
    int k = row >> 9;
    int b = row & 511;
    float s = 0.f;
    for (int j = lane; j < H_DIM; j += 64) s += a[(long)row * H_DIM + j] * Wc_w[j];
    s = wave_sum64(s);
    if (lane == 0) atts[b * 3 + k] = s + Wc_b[0];
}

__global__ void softmax_out2(float* __restrict__ out2, const float* __restrict__ atts,
                             const float* __restrict__ semb)
{
    long i = (long)blockIdx.x * 256 + threadIdx.x;
    if (i >= (long)BATCH * H_DIM) return;
    int b = (int)(i / H_DIM), j = (int)(i % H_DIM);
    float l0 = atts[b * 3 + 0], l1 = atts[b * 3 + 1], l2 = atts[b * 3 + 2];
    float m = fmaxf(l0, fmaxf(l1, l2));
    float e0 = expf(l0 - m), e1 = expf(l1 - m), e2 = expf(l2 - m);
    float s = e0 + e1 + e2;
    float v = (e0 * semb[((long)0 * BATCH + b) * H_DIM + j] +
               e1 * semb[((long)1 * BATCH + b) * H_DIM + j] +
               e2 * semb[((long)2 * BATCH + b) * H_DIM + j]) / s;
    out2[i] = v;
}

// ---------------------------------------------------------------- launch

extern "C" void kernel_launch(void* const* d_in, const int* in_sizes, int n_in,
                              void* d_out, int out_size, void* d_ws, size_t ws_size,
                              hipStream_t stream)
{
    (void)in_sizes; (void)n_in; (void)out_size; (void)ws_size;

    const int*   src     = (const int*)d_in[0];
    const int*   dst     = (const int*)d_in[1];
    const int*   etype   = (const int*)d_in[2];
    const int*   data    = (const int*)d_in[3];
    const int*   his_idx = (const int*)d_in[4];
    const int*   his_len = (const int*)d_in[5];
    const float* ent     = (const float*)d_in[6];
    const float* loop_w  = (const float*)d_in[7];
    const float* rel     = (const float*)d_in[8];
    const float* af      = (const float*)d_in[9];
    const float* ap      = (const float*)d_in[10];
    const float* cf      = (const float*)d_in[11];
    const float* cp      = (const float*)d_in[12];
    const float* Wn      = (const float*)d_in[13];
    const float* Ws      = (const float*)d_in[14];
    const float* W_ih    = (const float*)d_in[15];
    const float* W_hh    = (const float*)d_in[16];
    const float* b_ih    = (const float*)d_in[17];
    const float* b_hh    = (const float*)d_in[18];
    const float* Wb_w    = (const float*)d_in[19];
    const float* Wb_b    = (const float*)d_in[20];
    const float* Wc_w    = (const float*)d_in[21];
    const float* Wc_b    = (const float*)d_in[22];
    const float* Wd_w    = (const float*)d_in[23];
    const float* Wd_b    = (const float*)d_in[24];
    float* out_p = (float*)d_out;

    float* wp = (float*)d_ws;
    size_t off = 0;
    auto alloc = [&](size_t n) {
        size_t n4 = (n + 3) & ~(size_t)3;
        float* p = wp + off; off += n4; return p;
    };
    const long nE200 = (long)NUM_E * H_DIM;
    float* prev   = alloc(nE200);
    float* h1     = alloc(nE200);                       // GRU iN (f32); batch head: split-K partials
    float* tmp    = alloc(nE200);                       // init gemm out; GRU hN; qbuf partials
    float* rz     = out_p;                              // (NUM_E x 400) scratch in d_out
    ushort* bh0   = (ushort*)alloc(nE200 / 2);
    ushort* bh1   = (ushort*)alloc(nE200 / 2);
    ushort* btmp  = (ushort*)alloc(nE200 / 2);
    ushort* bprev = (ushort*)alloc(nE200 / 2);
    ushort* plo   = (ushort*)alloc(nE200 / 2);
    ushort* bte3  = (ushort*)alloc((size_t)N_HIST * NUM_E * TD_DIM / 2);
    ushort* brel  = (ushort*)alloc(400 * H_DIM / 2);
    ushort* bW_ih = (ushort*)alloc(600 * 248 / 2);
    ushort* bW_hh = (ushort*)alloc(600 * 200 / 2);
    ushort* bWn_t = (ushort*)alloc(2 * 200 * 200 / 2);
    ushort* bWs_t = (ushort*)alloc(2 * 200 * 200 / 2);
    ushort* bLp_t = (ushort*)alloc(200 * 200 / 2);
    ushort* qhi   = (ushort*)alloc(BATCH * H_DIM / 2);
    ushort* qlo   = (ushort*)alloc(BATCH * H_DIM / 2);
    ushort* ttbl  = (ushort*)alloc(256);                // 3*128 ushorts
    float* degf   = alloc(3 * NUM_E);
    float* invd   = alloc(3 * NUM_E);
    float* reln   = alloc(400 * H_DIM);
    float* bsum   = alloc(1024);
    float* qs3    = alloc(3 * BATCH * H_DIM);
    float* qr3    = alloc(3 * BATCH * H_DIM);
    float* semb   = alloc(3 * BATCH * H_DIM);
    float* teb    = alloc(3 * BATCH * TD_DIM);
    float* abuf   = alloc(3 * BATCH * H_DIM);
    float* atts   = alloc(2048);
    float* out2   = alloc(BATCH * H_DIM);
    int* cnt       = (int*)alloc(3 * NUM_E);
    int* row_start = (int*)alloc(3 * (NUM_E + 4));
    int* cursor    = (int*)alloc(3 * NUM_E);
    int* ssrc      = (int*)alloc(3L * E_EDGES);
    int* setype    = (int*)alloc(3L * E_EDGES);

    auto nblk = [](long n) { return (unsigned)((n + 255) / 256); };

    auto bseg1 = [](const ushort* A, int la, const ushort* B, int lb, int K) {
        BfSegs s{}; s.A[0]=A; s.lda[0]=la; s.B[0]=B; s.ldb[0]=lb; s.Ks[0]=K;
        s.nseg=1; s.Ktot=K; return s;
    };
    auto bseg2 = [](const ushort* A0, int la0, const ushort* B0, int lb0, int K0,
                    const ushort* A1, int la1, const ushort* B1, int lb1, int K1) {
        BfSegs s{}; s.A[0]=A0; s.lda[0]=la0; s.B[0]=B0; s.ldb[0]=lb0; s.Ks[0]=K0;
        s.A[1]=A1; s.lda[1]=la1; s.B[1]=B1; s.ldb[1]=lb1; s.Ks[1]=K1;
        s.nseg=2; s.Ktot=K0+K1; return s;
    };
    auto bseg3 = [](const ushort* A0, int la0, const ushort* B0, int lb0, int K0,
                    const ushort* A1, int la1, const ushort* B1, int lb1, int K1,
                    const ushort* A2, int la2, const ushort* B2, int lb2, int K2) {
        BfSegs s{}; s.A[0]=A0; s.lda[0]=la0; s.B[0]=B0; s.ldb[0]=lb0; s.Ks[0]=K0;
        s.A[1]=A1; s.lda[1]=la1; s.B[1]=B1; s.ldb[1]=lb1; s.Ks[1]=K1;
        s.A[2]=A2; s.lda[2]=la2; s.B[2]=B2; s.ldb[2]=lb2; s.Ks[2]=K2;
        s.nseg=3; s.Ktot=K0+K1+K2; return s;
    };

    // tile bookkeeping in 32x32 WAVE units
    auto desc = [](const BfSegs& sg, float* C, ushort* Cb, const float* bias,
                   int M, int N, int ldc, int act, int flags, int order) {
        GemmDesc D{}; D.sg=sg; D.C=C; D.Cb=Cb; D.bias=bias;
        D.M=M; D.N=N; D.ldc=ldc; D.act=act; D.flags=flags; D.order=order;
        D.nbx=(N+31)>>5; D.nby=(M+31)>>5; D.nblk=D.nbx*D.nby; D.blk0=0;
        return D;
    };
    auto launch_multi = [&](GemmDesc* ds, int nd) {
        MultiArgs ma{};
        int tot = 0;
        for (int i = 0; i < nd; i++) { ds[i].blk0 = tot; tot += ds[i].nblk; ma.d[i] = ds[i]; }
        ma.nd = nd; ma.tot = tot;
        unsigned blocks = (unsigned)((tot + 3) >> 2);
        unsigned grid = ((blocks + 7) >> 3) << 3;
        mfma_multi<<<grid, 256, 0, stream>>>(ma);
    };

    auto seg3 = [](const float* A0, int la0, const float* B0, int lb0, int K0,
                   const float* A1, int la1, const float* B1, int lb1, int K1,
                   const float* A2, int la2, const float* B2, int lb2, int K2) {
        Segs s{}; s.A[0]=A0; s.lda[0]=la0; s.B[0]=B0; s.ldb[0]=lb0; s.Ks[0]=K0;
        s.A[1]=A1; s.lda[1]=la1; s.B[1]=B1; s.ldb[1]=lb1; s.Ks[1]=K1;
        s.A[2]=A2; s.lda[2]=la2; s.B[2]=B2; s.ldb[2]=lb2; s.Ks[2]=K2;
        s.nseg=3; s.Ktot=K0+K1+K2; return s;
    };
    auto seg4 = [](const float* A0, int la0, const float* B0, int lb0, int K0,
                   const float* A1, int la1, const float* B1, int lb1, int K1,
                   const float* A2, int la2, const float* B2, int lb2, int K2,
                   const float* A3, int la3, const float* B3, int lb3, int K3) {
        Segs s{}; s.A[0]=A0; s.lda[0]=la0; s.B[0]=B0; s.ldb[0]=lb0; s.Ks[0]=K0;
        s.A[1]=A1; s.lda[1]=la1; s.B[1]=B1; s.ldb[1]=lb1; s.Ks[1]=K1;
        s.A[2]=A2; s.lda[2]=la2; s.B[2]=B2; s.ldb[2]=lb2; s.Ks[2]=K2;
        s.A[3]=A3; s.lda[3]=la3; s.B[3]=B3; s.ldb[3]=lb3; s.Ks[3]=K3;
        s.nseg=4; s.Ktot=K0+K1+K2+K3; return s;
    };
    // split-K partial gemm launcher
    auto splitk = [&](float* P, const Segs& sg, int M, int N, int KS) {
        int nbx = (N + 63) >> 6;
        int nby = (M + 63) >> 6;
        int ntile = (sg.Ktot + 31) / 32;
        int tpc = (ntile + KS - 1) / KS;
        int tot_all = nbx * nby * KS;
        unsigned grid = (unsigned)(((tot_all + 7) >> 3) << 3);
        sgemm_splitk<<<grid, 256, 0, stream>>>(P, sg, M, N, nbx, nby, KS, tpc);
    };

    const unsigned r4 = (NUM_E + 3) / 4;

    // ---- prelude ----
    l2norm_rows4<<<100, 256, 0, stream>>>(reln, brel, rel, 400);
    bias_sum<<<3, 256, 0, stream>>>(bsum, b_ih, b_hh);
    cvt_bf16_k<<<nblk(600L*248), 256, 0, stream>>>(bW_ih, W_ih, 600L*248);
    cvt_bf16_k<<<nblk(600L*200), 256, 0, stream>>>(bW_hh, W_hh, 600L*200);
    tcvt_bf16_k<<<nblk(40000), 256, 0, stream>>>(bLp_t, loop_w, 200, 200);
    tcvt_bf16_k<<<nblk(40000), 256, 0, stream>>>(bWn_t,          Wn,          200, 200);
    tcvt_bf16_k<<<nblk(40000), 256, 0, stream>>>(bWn_t + 40000,  Wn + 40000,  200, 200);
    tcvt_bf16_k<<<nblk(40000), 256, 0, stream>>>(bWs_t,          Ws,          200, 200);
    tcvt_bf16_k<<<nblk(40000), 256, 0, stream>>>(bWs_t + 40000,  Ws + 40000,  200, 200);

    // ---- CSR build for ALL 3 graphs (hoisted) ----
    fill_i32<<<nblk(3L * NUM_E), 256, 0, stream>>>(cnt, 3L * NUM_E, 0);
    count_dst3<<<nblk(3L * E_EDGES), 256, 0, stream>>>(dst, cnt);
    scan_rows3<<<3, 1024, 0, stream>>>(cnt, row_start, cursor, degf, invd);
    build_perm3<<<nblk(3L * E_EDGES), 256, 0, stream>>>(src, dst, etype, cursor, ssrc, setype);
    tenc_table3<<<2, 256, 0, stream>>>(ttbl, af, ap, cf, cp);
    tenc_fill3<<<nblk(3L * NUM_E * 6), 256, 0, stream>>>(bte3, degf, ttbl);

    // prev = l2norm(ent @ loop_weight)
    cvt_bf16_k<<<nblk(nE200), 256, 0, stream>>>(btmp, ent, nE200);
    {
        GemmDesc d0 = desc(bseg1(btmp, H_DIM, bLp_t, H_DIM, H_DIM),
                           tmp, nullptr, nullptr, NUM_E, H_DIM, H_DIM, 0, 1, 0);
        launch_multi(&d0, 1);
    }
    l2norm_rows4<<<r4, 256, 0, stream>>>(prev, bprev, tmp, NUM_E);

    for (int i = 0; i < N_HIST; i++) {
        const int* ssrc_g = ssrc + (long)i * E_EDGES;
        const int* sety_g = setype + (long)i * E_EDGES;
        const int* rs_g   = row_start + i * (NUM_E + 4);
        const float* iv_g = invd + i * NUM_E;
        ushort* bte_g     = bte3 + (long)i * NUM_E * TD_DIM;

        seg_gather_norm_bf<<<r4, 256, 0, stream>>>(bh0, bprev, ssrc_g, rs_g, iv_g);

        seg_gather_layer_bf<<<r4, 256, 0, stream>>>(btmp, bh0, brel, ssrc_g, sety_g, rs_g, iv_g);
        {
            GemmDesc d0 = desc(bseg2(btmp, H_DIM, bWn_t,         H_DIM, H_DIM,
                                     bh0,  H_DIM, bWs_t,         H_DIM, H_DIM),
                               nullptr, bh1, nullptr, NUM_E, H_DIM, H_DIM, 1, 2, 0);
            launch_multi(&d0, 1);
        }
        seg_gather_layer_bf<<<r4, 256, 0, stream>>>(btmp, bh1, brel, ssrc_g, sety_g, rs_g, iv_g);
        {
            GemmDesc d0 = desc(bseg2(btmp, H_DIM, bWn_t + 40000, H_DIM, H_DIM,
                                     bh1,  H_DIM, bWs_t + 40000, H_DIM, H_DIM),
                               nullptr, bh0, nullptr, NUM_E, H_DIM, H_DIM, 1, 2, 0);
            launch_multi(&d0, 1);
        }
        l2norm_bf4<<<r4, 256, 0, stream>>>(bh0, NUM_E);

        // Merged GRU GEMMs: rz (sigmoid, N=400), iN (h1), hN (tmp) — one launch,
        // ~16.9k independent wave-tiles, no barriers.
        {
            GemmDesc d3[3];
            d3[0] = desc(bseg3(bh0,   H_DIM,  bW_ih,       248, H_DIM,
                               bte_g, TD_DIM, bW_ih + 200, 248, TD_DIM,
                               bprev, H_DIM,  bW_hh,       200, H_DIM),
                         rz, nullptr, bsum, NUM_E, 400, 400, 2, 1, 0);
            d3[1] = desc(bseg2(bh0,   H_DIM,  bW_ih + 400*248,       248, H_DIM,
                               bte_g, TD_DIM, bW_ih + 400*248 + 200, 248, TD_DIM),
                         h1, nullptr, b_ih + 400, NUM_E, H_DIM, H_DIM, 0, 1, 0);
            d3[2] = desc(bseg1(bprev, H_DIM, bW_hh + 400*200, 200, H_DIM),
                         tmp, nullptr, b_hh + 400, NUM_E, H_DIM, H_DIM, 0, 1, 0);
            launch_multi(d3, 3);
        }

        gru_fused<<<r4, 256, 0, stream>>>(prev, bprev, rz, h1, tmp);
    }

    // ---- batch head ----
    gather_qs_qr3<<<nblk((long)BATCH * H_DIM), 256, 0, stream>>>(qs3, qr3, prev, reln, data);
    semb_kernel<<<dim3(BATCH, 3), 64, 0, stream>>>(semb, prev, his_idx, his_len);
    tenc_batch<<<nblk(3L * BATCH * TD_DIM), 256, 0, stream>>>(teb, his_len, af, ap, cf, cp);

    // abuf = relu([qs|qr|semb|teb] @ Wb_w^T + Wb_b)   -- split-K, partials in h1
    {
        const int KS = 8;
        const int MN = 3 * BATCH * H_DIM;
        splitk(h1, seg4(qs3, H_DIM,  Wb_w,       648, H_DIM,
                        qr3, H_DIM,  Wb_w + 200, 648, H_DIM,
                        semb, H_DIM, Wb_w + 400, 648, H_DIM,
                        teb, TD_DIM, Wb_w + 600, 648, TD_DIM),
               3 * BATCH, H_DIM, KS);
        reduce_relu<<<nblk(MN), 256, 0, stream>>>(abuf, h1, Wb_b, MN, H_DIM, KS);
    }
    att_logits_rows<<<(3 * BATCH + 3) / 4, 256, 0, stream>>>(atts, abuf, Wc_w, Wc_b);
    softmax_out2<<<nblk((long)BATCH * H_DIM), 256, 0, stream>>>(out2, atts, semb);

    // qbuf = relu([qs|qr|out2] @ Wd_w^T + Wd_b) -> hi/lo bf16 split (partials in tmp)
    {
        const int KS = 8;
        const int MN = BATCH * H_DIM;
        splitk(tmp, seg3(qs3, H_DIM,  Wd_w,       600, H_DIM,
                         qr3, H_DIM,  Wd_w + 200, 600, H_DIM,
                         out2, H_DIM, Wd_w + 400, 600, H_DIM),
               BATCH, H_DIM, KS);
        reduce_relu_split<<<nblk(MN), 256, 0, stream>>>(qhi, qlo, tmp, Wd_b, MN, H_DIM, KS);
    }

    // plo = bf16(prev - f32(bprev))  (bprev is the hi part)
    make_lo<<<nblk(nE200), 256, 0, stream>>>(plo, prev, bprev, nE200);

    // result = q @ prev^T via hi/lo-compensated bf16 MFMA:
    //   qhi@phi + qhi@plo + qlo@phi   (3 K-segments, Ktot=600), B-reuse tile order
    {
        GemmDesc d0 = desc(bseg3(qhi, H_DIM, bprev, H_DIM, H_DIM,
                                 qhi, H_DIM, plo,   H_DIM, H_DIM,
                                 qlo, H_DIM, bprev, H_DIM, H_DIM),
                           out_p, nullptr, nullptr, BATCH, NUM_E, NUM_E, 0, 1, 1);
        launch_multi(&d0, 1);
    }
}

// Round 11
// 1477.196 us; speedup vs baseline: 1.0310x; 1.0310x over previous
//
#include <hip/hip_runtime.h>
#include <hip/hip_bf16.h>

#define NUM_E   20000
#define H_DIM   200
#define TD_DIM  48
#define HD_DIM  24
#define L_HIST  32
#define N_HIST  3
#define E_EDGES 200000
#define BATCH   512

// ---------------------------------------------------------------- utilities

__device__ inline float wave_sum64(float x) {
    #pragma unroll
    for (int m = 1; m < 64; m <<= 1) x += __shfl_xor(x, m);
    return x;
}

__device__ inline ushort f2bf(float f) {
    unsigned u = __float_as_uint(f);
    u += 0x7fffu + ((u >> 16) & 1u);
    return (ushort)(u >> 16);
}
__device__ inline float bf2f(ushort u) {
    return __uint_as_float(((unsigned)u) << 16);
}
__device__ inline float4 bf4_to_f4(ushort4 v) {
    return (float4){bf2f(v.x), bf2f(v.y), bf2f(v.z), bf2f(v.w)};
}

__global__ void fill_i32(int* __restrict__ p, long n, int v) {
    long i = (long)blockIdx.x * blockDim.x + threadIdx.x;
    if (i < n) p[i] = v;
}

__global__ void bias_sum(float* __restrict__ bsum, const float* __restrict__ b_ih,
                         const float* __restrict__ b_hh) {
    int j = blockIdx.x * 256 + threadIdx.x;
    if (j < 600) bsum[j] = b_ih[j] + b_hh[j];
}

__global__ void cvt_bf16_k(ushort* __restrict__ o, const float* __restrict__ in, long n) {
    long i = (long)blockIdx.x * 256 + threadIdx.x;
    if (i < n) o[i] = f2bf(in[i]);
}

// lo[i] = bf16(x[i] - f32(hi[i]))
__global__ void make_lo(ushort* __restrict__ lo, const float* __restrict__ x,
                        const ushort* __restrict__ hi, long n) {
    long i = (long)blockIdx.x * 256 + threadIdx.x;
    if (i < n) lo[i] = f2bf(x[i] - bf2f(hi[i]));
}

// in (R,C) row-major f32 -> o (C,R) row-major bf16
__global__ void tcvt_bf16_k(ushort* __restrict__ o, const float* __restrict__ in, int R, int C) {
    int i = blockIdx.x * 256 + threadIdx.x;
    if (i >= R * C) return;
    int r = i / C, c = i - r * C;
    o[(size_t)c * R + r] = f2bf(in[i]);
}

// ---------------------------------------------------------------- f32 split-K GEMM (B^T)
struct Segs {
    const float* A[4];
    const float* B[4];
    int lda[4], ldb[4], Ks[4];
    int nseg, Ktot;
};

__device__ inline void seg_find(const Segs& sg, int gk, int& s, int& loc) {
    s = 0; loc = gk;
    #pragma unroll
    for (int t = 0; t < 3; t++) {
        if (s + 1 < sg.nseg && loc >= sg.Ks[s]) { loc -= sg.Ks[s]; s++; }
    }
}

// Partial GEMM: P[kc][M][N] = A@B^T over k-chunk kc. BM=64, BN=64, BK=32.
__global__ __launch_bounds__(256) void sgemm_splitk(
    float* __restrict__ P, const Segs sg, int M, int N, int nbx, int nby,
    int KS, int tpc)
{
    __shared__ float As[32][68];
    __shared__ float Bs[32][68];

    int tot = nbx * nby;
    int tot_all = tot * KS;
    int chunk = (tot_all + 7) >> 3;
    int v = (int)(blockIdx.x & 7) * chunk + (int)(blockIdx.x >> 3);
    if (v >= tot_all) return;
    int kc = v / tot;
    int tile = v - kc * tot;
    int by = tile / nbx, bx = tile - by * nbx;
    const int bn = bx * 64;
    const int bm = by * 64;
    const int tid = threadIdx.x;
    const int m0 = (tid >> 4) * 4;
    const int n0 = (tid & 15) * 4;

    float acc[4][4];
    #pragma unroll
    for (int i = 0; i < 4; i++)
        #pragma unroll
        for (int j = 0; j < 4; j++) acc[i][j] = 0.f;

    const int Ktot = sg.Ktot;
    const int ntile = (Ktot + 31) / 32;
    const int kt0 = kc * tpc;
    const int kt1 = min(ntile, kt0 + tpc);

    const int a_m  = tid & 31;
    const int a_k4 = (tid >> 5) * 4;
    const int b1_n = tid & 63;
    const int b1_k = (tid >> 6) * 4;

    float4 ra[2], rb[2];
    auto loadA = [&](int k0) {
        int gk = k0 + a_k4;
        bool kin = gk < Ktot;
        int s = 0, loc = 0;
        if (kin) seg_find(sg, gk, s, loc);
        const float* Ab = sg.A[s];
        const int lda = sg.lda[s];
        #pragma unroll
        for (int r = 0; r < 2; r++) {
            int row = bm + a_m + 32 * r;
            float4 vv = {0.f, 0.f, 0.f, 0.f};
            if (kin && row < M) vv = *(const float4*)(Ab + (size_t)row * lda + loc);
            ra[r] = vv;
        }
    };
    auto loadB = [&](int k0) {
        #pragma unroll
        for (int r = 0; r < 2; r++) {
            int k4 = b1_k + 16 * r;
            int gk = k0 + k4;
            bool kin = gk < Ktot;
            int s = 0, loc = 0;
            if (kin) seg_find(sg, gk, s, loc);
            const float* Bb = sg.B[s];
            const int ldb = sg.ldb[s];
            int gn = bn + b1_n;
            float4 vv = {0.f, 0.f, 0.f, 0.f};
            if (kin && gn < N) vv = *(const float4*)(Bb + (size_t)gn * ldb + loc);
            rb[r] = vv;
        }
    };

    if (kt0 < kt1) {
        loadA(kt0 * 32); loadB(kt0 * 32);
        for (int t = kt0; t < kt1; t++) {
            #pragma unroll
            for (int r = 0; r < 2; r++) {
                int m = a_m + 32 * r;
                As[a_k4 + 0][m] = ra[r].x;
                As[a_k4 + 1][m] = ra[r].y;
                As[a_k4 + 2][m] = ra[r].z;
                As[a_k4 + 3][m] = ra[r].w;
            }
            #pragma unroll
            for (int r = 0; r < 2; r++) {
                int k4 = b1_k + 16 * r;
                Bs[k4 + 0][b1_n] = rb[r].x;
                Bs[k4 + 1][b1_n] = rb[r].y;
                Bs[k4 + 2][b1_n] = rb[r].z;
                Bs[k4 + 3][b1_n] = rb[r].w;
            }
            __syncthreads();
            if (t + 1 < kt1) { loadA((t + 1) * 32); loadB((t + 1) * 32); }
            #pragma unroll 8
            for (int kk = 0; kk < 32; kk++) {
                float4 b = *(float4*)&Bs[kk][n0];
                float4 av = *(float4*)&As[kk][m0];
                float a[4] = {av.x, av.y, av.z, av.w};
                #pragma unroll
                for (int i = 0; i < 4; i++) {
                    acc[i][0] += a[i] * b.x;
                    acc[i][1] += a[i] * b.y;
                    acc[i][2] += a[i] * b.z;
                    acc[i][3] += a[i] * b.w;
                }
            }
            __syncthreads();
        }
    }

    int col = bn + n0;
    if (col < N) {
        #pragma unroll
        for (int i = 0; i < 4; i++) {
            int row = bm + m0 + i;
            if (row < M) {
                float4 o = {acc[i][0], acc[i][1], acc[i][2], acc[i][3]};
                *(float4*)(P + ((size_t)kc * M + row) * N + col) = o;
            }
        }
    }
}

// out = relu(sum_kc P + bias)
__global__ void reduce_relu(float* __restrict__ out, const float* __restrict__ P,
                            const float* __restrict__ bias, int MN, int N, int KS)
{
    int i = blockIdx.x * 256 + threadIdx.x;
    if (i >= MN) return;
    float s = bias[i % N];
    for (int k = 0; k < KS; k++) s += P[(size_t)k * MN + i];
    out[i] = fmaxf(s, 0.f);
}

// qhi/qlo = hi/lo bf16 split of relu(sum_kc P + bias)
__global__ void reduce_relu_split(ushort* __restrict__ qhi, ushort* __restrict__ qlo,
                                  const float* __restrict__ P, const float* __restrict__ bias,
                                  int MN, int N, int KS)
{
    int i = blockIdx.x * 256 + threadIdx.x;
    if (i >= MN) return;
    float s = bias[i % N];
    for (int k = 0; k < KS; k++) s += P[(size_t)k * MN + i];
    s = fmaxf(s, 0.f);
    ushort h = f2bf(s);
    qhi[i] = h;
    qlo[i] = f2bf(s - bf2f(h));
}

// ---------------------------------------------------------------- bf16 MFMA multi-GEMM
// 4 INDEPENDENT waves per block; each wave owns one 32x32 output tile and a
// private 8KB LDS slice, zero barriers (same-wave ds ordering via lgkmcnt).
// Staging mapping is the R5-proven one: consecutive lanes stage consecutive
// ROWS (LDS byte stride 16 -> conflict-free b128 writes & reads).
typedef __attribute__((ext_vector_type(8))) short bfrag;
typedef __attribute__((ext_vector_type(4))) float ffrag;

struct BfSegs {
    const ushort* A[3];
    const ushort* B[3];
    int lda[3], ldb[3], Ks[3];
    int nseg, Ktot;
};

__device__ inline void bseg_find(const BfSegs& sg, int gk, int& s, int& loc) {
    s = 0; loc = gk;
    #pragma unroll
    for (int t = 0; t < 2; t++) {
        if (s + 1 < sg.nseg && loc >= sg.Ks[s]) { loc -= sg.Ks[s]; s++; }
    }
}

// One GEMM description; tile bookkeeping in WAVE units (32x32 tiles).
// act: 0 none, 1 relu, 2 sigmoid.  flags: 1 = write f32 C, 2 = write bf16 Cb.
// order: 0 = A-reuse (consecutive waves share A rows), 1 = B-reuse.
struct GemmDesc {
    BfSegs sg;
    float* C;
    ushort* Cb;
    const float* bias;
    int M, N, ldc;
    int act, flags, order;
    int nbx, nby, blk0, nblk;   // nblk = nbx*nby wave-tiles
};

struct MultiArgs {
    GemmDesc d[3];
    int nd;
    int tot;        // total wave-tiles
};

template<int DI>
__device__ __forceinline__ void gemm_wave(const MultiArgs& ma, int gw,
                                          ushort* __restrict__ Als,
                                          ushort* __restrict__ Bls)
{
    const GemmDesc& D = ma.d[DI];
    const BfSegs& sg = D.sg;
    const int t0 = gw - D.blk0;
    int my, mx;
    if (D.order == 0) { my = t0 / D.nbx; mx = t0 - my * D.nbx; }
    else              { mx = t0 / D.nby; my = t0 - mx * D.nby; }
    const int bm = my * 32, bn = mx * 32;
    const int M = D.M, N = D.N;
    const int lane = (int)(threadIdx.x & 63);

    ffrag acc[2][2];
    #pragma unroll
    for (int i = 0; i < 2; i++)
        #pragma unroll
        for (int j = 0; j < 2; j++) acc[i][j] = (ffrag){0.f, 0.f, 0.f, 0.f};

    const int Ktot = sg.Ktot;
    const int nkt = (Ktot + 63) >> 6;

    // staging: 4 chunks of 16B per lane; c = i*64+lane; row = c&31, kq = c>>5
    // (consecutive lanes -> consecutive rows -> LDS wc stride 1 = 16B:
    //  conflict-free b128 writes; same mapping class as the proven R5 kernel)
    int s_m[4], s_kq[4], s_wc[4];
    #pragma unroll
    for (int i = 0; i < 4; i++) {
        int c = i * 64 + lane;
        s_m[i] = c & 31; s_kq[i] = (c >> 5) & 7;
        s_wc[i] = ((s_m[i] >> 4) * 2 + (s_kq[i] >> 2)) * 64 + (s_kq[i] & 3) * 16 + (s_m[i] & 15);
    }

    uint4 ra[4], rb[4];
    auto loadA = [&](int k0) {
        #pragma unroll
        for (int i = 0; i < 4; i++) {
            int gk = k0 + s_kq[i] * 8;
            int row = bm + s_m[i];
            uint4 vv = {0u, 0u, 0u, 0u};
            if (gk < Ktot && row < M) {
                int s, loc; bseg_find(sg, gk, s, loc);
                vv = *(const uint4*)(sg.A[s] + (size_t)row * sg.lda[s] + loc);
            }
            ra[i] = vv;
        }
    };
    auto loadB = [&](int k0) {
        #pragma unroll
        for (int i = 0; i < 4; i++) {
            int gk = k0 + s_kq[i] * 8;
            int gn = bn + s_m[i];
            uint4 vv = {0u, 0u, 0u, 0u};
            if (gk < Ktot && gn < N) {
                int s, loc; bseg_find(sg, gk, s, loc);
                vv = *(const uint4*)(sg.B[s] + (size_t)gn * sg.ldb[s] + loc);
            }
            rb[i] = vv;
        }
    };

    loadA(0); loadB(0);

    for (int t = 0; t < nkt; t++) {
        #pragma unroll
        for (int i = 0; i < 4; i++) *(uint4*)(&Als[s_wc[i] * 8]) = ra[i];
        #pragma unroll
        for (int i = 0; i < 4; i++) *(uint4*)(&Bls[s_wc[i] * 8]) = rb[i];

        if (t + 1 < nkt) { loadA((t + 1) << 6); loadB((t + 1) << 6); }

        #pragma unroll
        for (int kt = 0; kt < 2; kt++) {
            bfrag af[2], bf[2];
            #pragma unroll
            for (int i = 0; i < 2; i++)
                af[i] = *(const bfrag*)(&Als[((i * 2 + kt) * 64 + lane) * 8]);
            #pragma unroll
            for (int j = 0; j < 2; j++)
                bf[j] = *(const bfrag*)(&Bls[((j * 2 + kt) * 64 + lane) * 8]);
            #pragma unroll
            for (int i = 0; i < 2; i++)
                #pragma unroll
                for (int j = 0; j < 2; j++)
                    acc[i][j] = __builtin_amdgcn_mfma_f32_16x16x32_bf16(af[i], bf[j], acc[i][j], 0, 0, 0);
        }
    }

    const int rbase = (lane >> 4) * 4;
    const int cl = lane & 15;
    #pragma unroll
    for (int j = 0; j < 2; j++) {
        int col = bn + j * 16 + cl;
        if (col >= N) continue;
        float bv = D.bias ? D.bias[col] : 0.f;
        #pragma unroll
        for (int i = 0; i < 2; i++) {
            int mrow = bm + i * 16 + rbase;
            #pragma unroll
            for (int r = 0; r < 4; r++) {
                int row = mrow + r;
                if (row < M) {
                    float o = acc[i][j][r] + bv;
                    if (D.act == 1) o = fmaxf(o, 0.f);
                    else if (D.act == 2) o = 1.f / (1.f + expf(-o));
                    if (D.flags & 1) D.C[(size_t)row * D.ldc + col] = o;
                    if (D.flags & 2) D.Cb[(size_t)row * D.ldc + col] = f2bf(o);
                }
            }
        }
    }
}

__global__ __launch_bounds__(256) void mfma_multi(MultiArgs ma)
{
    __shared__ __align__(16) ushort lds[16384];   // 4 waves x (A 2048 + B 2048)

    const int w = (int)(threadIdx.x >> 6);
    ushort* Als = lds + w * 4096;
    ushort* Bls = Als + 2048;

    int tot = ma.tot;
    int nblk = (tot + 3) >> 2;
    int chunk = (nblk + 7) >> 3;
    int v = (int)(blockIdx.x & 7) * chunk + (int)(blockIdx.x >> 3);
    if (v >= nblk) return;
    int gw = v * 4 + w;
    if (gw >= tot) return;

    int di = 0;
    if (ma.nd > 1 && gw >= ma.d[1].blk0) di = 1;
    if (ma.nd > 2 && gw >= ma.d[2].blk0) di = 2;

    if (di == 0)      gemm_wave<0>(ma, gw, Als, Bls);
    else if (di == 1) gemm_wave<1>(ma, gw, Als, Bls);
    else              gemm_wave<2>(ma, gw, Als, Bls);
}

// ---------------------------------------------------------------- CSR build (all 3 graphs, hoisted)

// count over all 3 graphs: cnt[g*NUM_E + d]
__global__ void count_dst3(const int* __restrict__ dst, int* __restrict__ cnt) {
    long e = (long)blockIdx.x * 256 + threadIdx.x;
    if (e < (long)N_HIST * E_EDGES) {
        int g = (int)(e / E_EDGES);
        atomicAdd(&cnt[g * NUM_E + dst[e]], 1);
    }
}

// one block per graph (3 concurrent scans)
__global__ __launch_bounds__(1024) void scan_rows3(
    const int* __restrict__ cnt_all, int* __restrict__ row_start_all,
    int* __restrict__ cursor_all, float* __restrict__ degf_all,
    float* __restrict__ invd_all)
{
    __shared__ int part[1024];
    const int g = blockIdx.x;
    const int* cnt = cnt_all + g * NUM_E;
    int* row_start  = row_start_all + g * (NUM_E + 4);
    int* cursor     = cursor_all + g * NUM_E;
    float* degf     = degf_all + g * NUM_E;
    float* invd     = invd_all + g * NUM_E;

    const int CH = (NUM_E + 1023) / 1024;
    int t = threadIdx.x;
    int base = t * CH;
    int local[32];
    int s = 0;
    for (int j = 0; j < CH; j++) {
        int idx = base + j;
        int c = (idx < NUM_E) ? cnt[idx] : 0;
        local[j] = s; s += c;
    }
    part[t] = s;
    __syncthreads();
    for (int off = 1; off < 1024; off <<= 1) {
        int vv = (t >= off) ? part[t - off] : 0;
        __syncthreads();
        part[t] += vv;
        __syncthreads();
    }
    int pre = (t == 0) ? 0 : part[t - 1];
    for (int j = 0; j < CH; j++) {
        int idx = base + j;
        if (idx < NUM_E) {
            int rs = pre + local[j];
            row_start[idx] = rs;
            cursor[idx] = rs;
            int c = cnt[idx];
            degf[idx] = (float)c;
            invd[idx] = 1.f / fmaxf((float)c, 1.f);
        }
    }
    if (t == 1023) row_start[NUM_E] = part[1023];
}

__global__ void build_perm3(const int* __restrict__ src, const int* __restrict__ dst,
                            const int* __restrict__ etype, int* __restrict__ cursor_all,
                            int* __restrict__ ssrc_all, int* __restrict__ setype_all)
{
    long e = (long)blockIdx.x * 256 + threadIdx.x;
    if (e >= (long)N_HIST * E_EDGES) return;
    int g = (int)(e / E_EDGES);
    int pos = atomicAdd(&cursor_all[g * NUM_E + dst[e]], 1);
    ssrc_all[(long)g * E_EDGES + pos]   = src[e];
    setype_all[(long)g * E_EDGES + pos] = etype[e];
}

// ---------------------------------------------------------------- gathers (bf16 in/out)

__global__ __launch_bounds__(256) void seg_gather_norm_bf(
    ushort* __restrict__ bh, const ushort* __restrict__ bprev,
    const int* __restrict__ ssrc, const int* __restrict__ row_start,
    const float* __restrict__ invd)
{
    int v = blockIdx.x * 4 + (threadIdx.x >> 6);
    int lane = threadIdx.x & 63;
    if (v >= NUM_E) return;
    int s0 = row_start[v], s1 = row_start[v + 1];
    bool act = lane < 50;
    float4 acc = {0.f, 0.f, 0.f, 0.f};
    int j = s0;
    for (; j + 1 < s1; j += 2) {
        int sa = ssrc[j], sb = ssrc[j + 1];
        if (act) {
            float4 xa = bf4_to_f4(*(const ushort4*)(bprev + (long)sa * H_DIM + lane * 4));
            float4 xb = bf4_to_f4(*(const ushort4*)(bprev + (long)sb * H_DIM + lane * 4));
            acc.x += xa.x + xb.x; acc.y += xa.y + xb.y;
            acc.z += xa.z + xb.z; acc.w += xa.w + xb.w;
        }
    }
    if (j < s1) {
        int sa = ssrc[j];
        if (act) {
            float4 xa = bf4_to_f4(*(const ushort4*)(bprev + (long)sa * H_DIM + lane * 4));
            acc.x += xa.x; acc.y += xa.y; acc.z += xa.z; acc.w += xa.w;
        }
    }
    float iv = invd[v];
    acc.x *= iv; acc.y *= iv; acc.z *= iv; acc.w *= iv;
    float ss = act ? (acc.x*acc.x + acc.y*acc.y + acc.z*acc.z + acc.w*acc.w) : 0.f;
    ss = wave_sum64(ss);
    float r = 1.f / fmaxf(sqrtf(ss), 1e-12f);
    if (act) {
        ushort4 ob = {f2bf(acc.x * r), f2bf(acc.y * r), f2bf(acc.z * r), f2bf(acc.w * r)};
        *(ushort4*)(bh + (long)v * H_DIM + lane * 4) = ob;
    }
}

__global__ __launch_bounds__(256) void seg_gather_layer_bf(
    ushort* __restrict__ btmp, const ushort* __restrict__ bh, const ushort* __restrict__ brel,
    const int* __restrict__ ssrc, const int* __restrict__ setype,
    const int* __restrict__ row_start, const float* __restrict__ invd)
{
    int v = blockIdx.x * 4 + (threadIdx.x >> 6);
    int lane = threadIdx.x & 63;
    if (v >= NUM_E) return;
    int s0 = row_start[v], s1 = row_start[v + 1];
    bool act = lane < 50;
    float4 acc = {0.f, 0.f, 0.f, 0.f};
    int j = s0;
    for (; j + 1 < s1; j += 2) {
        int sa = ssrc[j], ta = setype[j];
        int sb = ssrc[j + 1], tb = setype[j + 1];
        if (act) {
            float4 xa = bf4_to_f4(*(const ushort4*)(bh   + (long)sa * H_DIM + lane * 4));
            float4 ya = bf4_to_f4(*(const ushort4*)(brel + (long)ta * H_DIM + lane * 4));
            float4 xb = bf4_to_f4(*(const ushort4*)(bh   + (long)sb * H_DIM + lane * 4));
            float4 yb = bf4_to_f4(*(const ushort4*)(brel + (long)tb * H_DIM + lane * 4));
            acc.x += (xa.x + ya.x) + (xb.x + yb.x);
            acc.y += (xa.y + ya.y) + (xb.y + yb.y);
            acc.z += (xa.z + ya.z) + (xb.z + yb.z);
            acc.w += (xa.w + ya.w) + (xb.w + yb.w);
        }
    }
    if (j < s1) {
        int s = ssrc[j];
        int t = setype[j];
        if (act) {
            float4 x = bf4_to_f4(*(const ushort4*)(bh   + (long)s * H_DIM + lane * 4));
            float4 y = bf4_to_f4(*(const ushort4*)(brel + (long)t * H_DIM + lane * 4));
            acc.x += x.x + y.x; acc.y += x.y + y.y;
            acc.z += x.z + y.z; acc.w += x.w + y.w;
        }
    }
    float iv = invd[v];
    if (act) {
        ushort4 ob = {f2bf(acc.x * iv), f2bf(acc.y * iv), f2bf(acc.z * iv), f2bf(acc.w * iv)};
        *(ushort4*)(btmp + (long)v * H_DIM + lane * 4) = ob;
    }
}

// ---------------------------------------------------------------- row kernels

__global__ __launch_bounds__(256) void l2norm_rows4(
    float* __restrict__ out, ushort* __restrict__ bout,
    const float* __restrict__ in, int nrows)
{
    int v = blockIdx.x * 4 + (threadIdx.x >> 6);
    int lane = threadIdx.x & 63;
    if (v >= nrows) return;
    bool act = lane < 50;
    float4 x = {0.f, 0.f, 0.f, 0.f};
    if (act) x = *(const float4*)(in + (long)v * H_DIM + lane * 4);
    float ss = x.x*x.x + x.y*x.y + x.z*x.z + x.w*x.w;
    ss = wave_sum64(ss);
    float r = 1.f / fmaxf(sqrtf(ss), 1e-12f);
    if (act) {
        long base = (long)v * H_DIM + lane * 4;
        float4 o = {x.x * r, x.y * r, x.z * r, x.w * r};
        *(float4*)(out + base) = o;
        if (bout) {
            ushort4 ob = {f2bf(o.x), f2bf(o.y), f2bf(o.z), f2bf(o.w)};
            *(ushort4*)(bout + base) = ob;
        }
    }
}

__global__ __launch_bounds__(256) void l2norm_bf4(ushort* __restrict__ b, int nrows)
{
    int v = blockIdx.x * 4 + (threadIdx.x >> 6);
    int lane = threadIdx.x & 63;
    if (v >= nrows) return;
    bool act = lane < 50;
    float4 x = {0.f, 0.f, 0.f, 0.f};
    long base = (long)v * H_DIM + lane * 4;
    if (act) x = bf4_to_f4(*(const ushort4*)(b + base));
    float ss = x.x*x.x + x.y*x.y + x.z*x.z + x.w*x.w;
    ss = wave_sum64(ss);
    float r = 1.f / fmaxf(sqrtf(ss), 1e-12f);
    if (act) {
        ushort4 ob = {f2bf(x.x * r), f2bf(x.y * r), f2bf(x.z * r), f2bf(x.w * r)};
        *(ushort4*)(b + base) = ob;
    }
}

// 3 graphs x 2 rows x 48 bf16 time-encoding table (row stride 64)
__global__ void tenc_table3(ushort* __restrict__ tbl, const float* __restrict__ af,
                            const float* __restrict__ ap, const float* __restrict__ cf,
                            const float* __restrict__ cp)
{
    int j = blockIdx.x * 256 + threadIdx.x;
    if (j >= 384) return;
    int g = j >> 7;
    int r = j & 127;
    int half = r >> 6;
    int jj = r & 63;
    if (jj >= TD_DIM) return;
    float tcnt = (float)(N_HIST - 1 - g);
    float t = half ? 100.0f : tcnt;
    float val;
    if (jj < HD_DIM) val = tanhf((t + 1.f) * af[jj] + ap[jj]);
    else             val = cosf(t * cf[jj - HD_DIM] + cp[jj - HD_DIM]);
    tbl[g * 128 + half * 64 + jj] = f2bf(val);
}

// bte3[g][v][:] = tbl[g][deg>0 ? 0 : 1][:]  (uint4 copies)
__global__ void tenc_fill3(ushort* __restrict__ bte3, const float* __restrict__ degf_all,
                           const ushort* __restrict__ tbl)
{
    long idx = (long)blockIdx.x * 256 + threadIdx.x;
    if (idx >= (long)N_HIST * NUM_E * 6) return;
    int g = (int)(idx / (NUM_E * 6));
    int rem = (int)(idx - (long)g * NUM_E * 6);
    int v = rem / 6, c = rem - v * 6;
    int base = (degf_all[g * NUM_E + v] > 0.f) ? 0 : 64;
    *(uint4*)(bte3 + ((long)g * NUM_E + v) * TD_DIM + c * 8) =
        *(const uint4*)(tbl + g * 128 + base + c * 8);
}

__global__ __launch_bounds__(256) void gru_fused(
    float* __restrict__ prev, ushort* __restrict__ bprev, const float* __restrict__ rz,
    const float* __restrict__ iN, const float* __restrict__ hN)
{
    int v = blockIdx.x * 4 + (threadIdx.x >> 6);
    int lane = threadIdx.x & 63;
    if (v >= NUM_E) return;
    bool act = lane < 50;
    long b200 = (long)v * H_DIM + lane * 4;
    long b400 = (long)v * 400 + lane * 4;
    float4 o = {0.f, 0.f, 0.f, 0.f};
    if (act) {
        float4 r4 = *(const float4*)(rz + b400);
        float4 z4 = *(const float4*)(rz + b400 + 200);
        float4 n4 = *(const float4*)(iN + b200);
        float4 g4 = *(const float4*)(hN + b200);
        float4 p4 = *(const float4*)(prev + b200);
        float ngx = tanhf(n4.x + r4.x * g4.x);
        float ngy = tanhf(n4.y + r4.y * g4.y);
        float ngz = tanhf(n4.z + r4.z * g4.z);
        float ngw = tanhf(n4.w + r4.w * g4.w);
        o.x = (1.f - z4.x) * ngx + z4.x * p4.x;
        o.y = (1.f - z4.y) * ngy + z4.y * p4.y;
        o.z = (1.f - z4.z) * ngz + z4.z * p4.z;
        o.w = (1.f - z4.w) * ngw + z4.w * p4.w;
    }
    float ss = o.x*o.x + o.y*o.y + o.z*o.z + o.w*o.w;
    ss = wave_sum64(ss);
    float r = 1.f / fmaxf(sqrtf(ss), 1e-12f);
    if (act) {
        float4 wv = {o.x * r, o.y * r, o.z * r, o.w * r};
        *(float4*)(prev + b200) = wv;
        ushort4 ob = {f2bf(wv.x), f2bf(wv.y), f2bf(wv.z), f2bf(wv.w)};
        *(ushort4*)(bprev + b200) = ob;
    }
}

// ---------------------------------------------------------------- batch head

__global__ void gather_qs_qr3(float* __restrict__ qs3, float* __restrict__ qr3,
                              const float* __restrict__ out, const float* __restrict__ reln,
                              const int* __restrict__ data)
{
    long i = (long)blockIdx.x * 256 + threadIdx.x;
    if (i >= (long)BATCH * H_DIM) return;
    int b = (int)(i / H_DIM), j = (int)(i % H_DIM);
    float vs = out[(long)data[b * 4 + 0] * H_DIM + j];
    float vr = reln[(long)data[b * 4 + 1] * H_DIM + j];
    const long S = (long)BATCH * H_DIM;
    qs3[i] = vs; qs3[i + S] = vs; qs3[i + 2*S] = vs;
    qr3[i] = vr; qr3[i + S] = vr; qr3[i + 2*S] = vr;
}

__global__ __launch_bounds__(64) void semb_kernel(
    float* __restrict__ semb, const float* __restrict__ out,
    const int* __restrict__ his_idx, const int* __restrict__ his_len)
{
    int b = blockIdx.x, k = blockIdx.y;
    int lane = threadIdx.x;
    int ln = his_len[b * 3 + k];
    if (ln > L_HIST) ln = L_HIST;
    float vals[4] = {0.f, 0.f, 0.f, 0.f};
    for (int l = 0; l < ln; l++) {
        int idx = his_idx[((long)b * 3 + k) * L_HIST + l];
        #pragma unroll
        for (int t = 0; t < 4; t++) {
            int j = lane + t * 64;
            if (j < H_DIM) vals[t] += out[(long)idx * H_DIM + j];
        }
    }
    float scale = 1.f / fmaxf((float)ln, 1.f);
    float ss = 0.f;
    #pragma unroll
    for (int t = 0; t < 4; t++) { vals[t] *= scale; ss += vals[t] * vals[t]; }
    ss = wave_sum64(ss);
    float r = 1.f / fmaxf(sqrtf(ss), 1e-12f);
    #pragma unroll
    for (int t = 0; t < 4; t++) {
        int j = lane + t * 64;
        if (j < H_DIM) semb[((long)k * BATCH + b) * H_DIM + j] = vals[t] * r;
    }
}

__global__ void tenc_batch(float* __restrict__ teb, const int* __restrict__ his_len,
                           const float* __restrict__ af, const float* __restrict__ ap,
                           const float* __restrict__ cf, const float* __restrict__ cp)
{
    int idx = blockIdx.x * 256 + threadIdx.x;
    if (idx >= 3 * BATCH * TD_DIM) return;
    int k = idx / (BATCH * TD_DIM);
    int rem = idx - k * (BATCH * TD_DIM);
    int b = rem / TD_DIM, j = rem % TD_DIM;
    int ln = his_len[b * 3 + k];
    float t = (ln > 0) ? (float)(2 - k) : 100.0f;
    float val;
    if (j < HD_DIM) val = tanhf((t + 1.f) * af[j] + ap[j]);
    else            val = cosf(t * cf[j - HD_DIM] + cp[j - HD_DIM]);
    teb[idx] = val;
}

__global__ __launch_bounds__(256) void att_logits_rows(
    float* __restrict__ atts, const float* __restrict__ a,
    const float* __restrict__ Wc_w, const float* __restrict__ Wc_b)
{
    int row = blockIdx.x * 4 + (threadIdx.x >> 6);
    int lane = threadIdx.x & 63;
    if (row >= 3 * BATCH) return;
    int k = row >> 9;
    int b = row & 511;
    float s = 0.f;
    for (int j = lane; j < H_DIM; j += 64) s += a[(long)row * H_DIM + j] * Wc_w[j];
    s = wave_sum64(s);
    if (lane == 0) atts[b * 3 + k] = s + Wc_b[0];
}

__global__ void softmax_out2(float* __restrict__ out2, const float* __restrict__ atts,
                             const float* __restrict__ semb)
{
    long i = (long)blockIdx.x * 256 + threadIdx.x;
    if (i >= (long)BATCH * H_DIM) return;
    int b = (int)(i / H_DIM), j = (int)(i % H_DIM);
    float l0 = atts[b * 3 + 0], l1 = atts[b * 3 + 1], l2 = atts[b * 3 + 2];
    float m = fmaxf(l0, fmaxf(l1, l2));
    float e0 = expf(l0 - m), e1 = expf(l1 - m), e2 = expf(l2 - m);
    float s = e0 + e1 + e2;
    float v = (e0 * semb[((long)0 * BATCH + b) * H_DIM + j] +
               e1 * semb[((long)1 * BATCH + b) * H_DIM + j] +
               e2 * semb[((long)2 * BATCH + b) * H_DIM + j]) / s;
    out2[i] = v;
}

// ---------------------------------------------------------------- launch

extern "C" void kernel_launch(void* const* d_in, const int* in_sizes, int n_in,
                              void* d_out, int out_size, void* d_ws, size_t ws_size,
                              hipStream_t stream)
{
    (void)in_sizes; (void)n_in; (void)out_size; (void)ws_size;

    const int*   src     = (const int*)d_in[0];
    const int*   dst     = (const int*)d_in[1];
    const int*   etype   = (const int*)d_in[2];
    const int*   data    = (const int*)d_in[3];
    const int*   his_idx = (const int*)d_in[4];
    const int*   his_len = (const int*)d_in[5];
    const float* ent     = (const float*)d_in[6];
    const float* loop_w  = (const float*)d_in[7];
    const float* rel     = (const float*)d_in[8];
    const float* af      = (const float*)d_in[9];
    const float* ap      = (const float*)d_in[10];
    const float* cf      = (const float*)d_in[11];
    const float* cp      = (const float*)d_in[12];
    const float* Wn      = (const float*)d_in[13];
    const float* Ws      = (const float*)d_in[14];
    const float* W_ih    = (const float*)d_in[15];
    const float* W_hh    = (const float*)d_in[16];
    const float* b_ih    = (const float*)d_in[17];
    const float* b_hh    = (const float*)d_in[18];
    const float* Wb_w    = (const float*)d_in[19];
    const float* Wb_b    = (const float*)d_in[20];
    const float* Wc_w    = (const float*)d_in[21];
    const float* Wc_b    = (const float*)d_in[22];
    const float* Wd_w    = (const float*)d_in[23];
    const float* Wd_b    = (const float*)d_in[24];
    float* out_p = (float*)d_out;

    float* wp = (float*)d_ws;
    size_t off = 0;
    auto alloc = [&](size_t n) {
        size_t n4 = (n + 3) & ~(size_t)3;
        float* p = wp + off; off += n4; return p;
    };
    const long nE200 = (long)NUM_E * H_DIM;
    float* prev   = alloc(nE200);
    float* h1     = alloc(nE200);                       // GRU iN (f32); batch head: split-K partials
    float* tmp    = alloc(nE200);                       // init gemm out; GRU hN; qbuf partials
    float* rz     = out_p;                              // (NUM_E x 400) scratch in d_out
    ushort* bh0   = (ushort*)alloc(nE200 / 2);
    ushort* bh1   = (ushort*)alloc(nE200 / 2);
    ushort* btmp  = (ushort*)alloc(nE200 / 2);
    ushort* bprev = (ushort*)alloc(nE200 / 2);
    ushort* plo   = (ushort*)alloc(nE200 / 2);
    ushort* bte3  = (ushort*)alloc((size_t)N_HIST * NUM_E * TD_DIM / 2);
    ushort* brel  = (ushort*)alloc(400 * H_DIM / 2);
    ushort* bW_ih = (ushort*)alloc(600 * 248 / 2);
    ushort* bW_hh = (ushort*)alloc(600 * 200 / 2);
    ushort* bWn_t = (ushort*)alloc(2 * 200 * 200 / 2);
    ushort* bWs_t = (ushort*)alloc(2 * 200 * 200 / 2);
    ushort* bLp_t = (ushort*)alloc(200 * 200 / 2);
    ushort* qhi   = (ushort*)alloc(BATCH * H_DIM / 2);
    ushort* qlo   = (ushort*)alloc(BATCH * H_DIM / 2);
    ushort* ttbl  = (ushort*)alloc(256);                // 3*128 ushorts
    float* degf   = alloc(3 * NUM_E);
    float* invd   = alloc(3 * NUM_E);
    float* reln   = alloc(400 * H_DIM);
    float* bsum   = alloc(1024);
    float* qs3    = alloc(3 * BATCH * H_DIM);
    float* qr3    = alloc(3 * BATCH * H_DIM);
    float* semb   = alloc(3 * BATCH * H_DIM);
    float* teb    = alloc(3 * BATCH * TD_DIM);
    float* abuf   = alloc(3 * BATCH * H_DIM);
    float* atts   = alloc(2048);
    float* out2   = alloc(BATCH * H_DIM);
    int* cnt       = (int*)alloc(3 * NUM_E);
    int* row_start = (int*)alloc(3 * (NUM_E + 4));
    int* cursor    = (int*)alloc(3 * NUM_E);
    int* ssrc      = (int*)alloc(3L * E_EDGES);
    int* setype    = (int*)alloc(3L * E_EDGES);

    auto nblk = [](long n) { return (unsigned)((n + 255) / 256); };

    auto bseg1 = [](const ushort* A, int la, const ushort* B, int lb, int K) {
        BfSegs s{}; s.A[0]=A; s.lda[0]=la; s.B[0]=B; s.ldb[0]=lb; s.Ks[0]=K;
        s.nseg=1; s.Ktot=K; return s;
    };
    auto bseg2 = [](const ushort* A0, int la0, const ushort* B0, int lb0, int K0,
                    const ushort* A1, int la1, const ushort* B1, int lb1, int K1) {
        BfSegs s{}; s.A[0]=A0; s.lda[0]=la0; s.B[0]=B0; s.ldb[0]=lb0; s.Ks[0]=K0;
        s.A[1]=A1; s.lda[1]=la1; s.B[1]=B1; s.ldb[1]=lb1; s.Ks[1]=K1;
        s.nseg=2; s.Ktot=K0+K1; return s;
    };
    auto bseg3 = [](const ushort* A0, int la0, const ushort* B0, int lb0, int K0,
                    const ushort* A1, int la1, const ushort* B1, int lb1, int K1,
                    const ushort* A2, int la2, const ushort* B2, int lb2, int K2) {
        BfSegs s{}; s.A[0]=A0; s.lda[0]=la0; s.B[0]=B0; s.ldb[0]=lb0; s.Ks[0]=K0;
        s.A[1]=A1; s.lda[1]=la1; s.B[1]=B1; s.ldb[1]=lb1; s.Ks[1]=K1;
        s.A[2]=A2; s.lda[2]=la2; s.B[2]=B2; s.ldb[2]=lb2; s.Ks[2]=K2;
        s.nseg=3; s.Ktot=K0+K1+K2; return s;
    };

    // tile bookkeeping in 32x32 WAVE units
    auto desc = [](const BfSegs& sg, float* C, ushort* Cb, const float* bias,
                   int M, int N, int ldc, int act, int flags, int order) {
        GemmDesc D{}; D.sg=sg; D.C=C; D.Cb=Cb; D.bias=bias;
        D.M=M; D.N=N; D.ldc=ldc; D.act=act; D.flags=flags; D.order=order;
        D.nbx=(N+31)>>5; D.nby=(M+31)>>5; D.nblk=D.nbx*D.nby; D.blk0=0;
        return D;
    };
    auto launch_multi = [&](GemmDesc* ds, int nd) {
        MultiArgs ma{};
        int tot = 0;
        for (int i = 0; i < nd; i++) { ds[i].blk0 = tot; tot += ds[i].nblk; ma.d[i] = ds[i]; }
        ma.nd = nd; ma.tot = tot;
        unsigned blocks = (unsigned)((tot + 3) >> 2);
        unsigned grid = ((blocks + 7) >> 3) << 3;
        mfma_multi<<<grid, 256, 0, stream>>>(ma);
    };

    auto seg3 = [](const float* A0, int la0, const float* B0, int lb0, int K0,
                   const float* A1, int la1, const float* B1, int lb1, int K1,
                   const float* A2, int la2, const float* B2, int lb2, int K2) {
        Segs s{}; s.A[0]=A0; s.lda[0]=la0; s.B[0]=B0; s.ldb[0]=lb0; s.Ks[0]=K0;
        s.A[1]=A1; s.lda[1]=la1; s.B[1]=B1; s.ldb[1]=lb1; s.Ks[1]=K1;
        s.A[2]=A2; s.lda[2]=la2; s.B[2]=B2; s.ldb[2]=lb2; s.Ks[2]=K2;
        s.nseg=3; s.Ktot=K0+K1+K2; return s;
    };
    auto seg4 = [](const float* A0, int la0, const float* B0, int lb0, int K0,
                   const float* A1, int la1, const float* B1, int lb1, int K1,
                   const float* A2, int la2, const float* B2, int lb2, int K2,
                   const float* A3, int la3, const float* B3, int lb3, int K3) {
        Segs s{}; s.A[0]=A0; s.lda[0]=la0; s.B[0]=B0; s.ldb[0]=lb0; s.Ks[0]=K0;
        s.A[1]=A1; s.lda[1]=la1; s.B[1]=B1; s.ldb[1]=lb1; s.Ks[1]=K1;
        s.A[2]=A2; s.lda[2]=la2; s.B[2]=B2; s.ldb[2]=lb2; s.Ks[2]=K2;
        s.A[3]=A3; s.lda[3]=la3; s.B[3]=B3; s.ldb[3]=lb3; s.Ks[3]=K3;
        s.nseg=4; s.Ktot=K0+K1+K2+K3; return s;
    };
    // split-K partial gemm launcher
    auto splitk = [&](float* P, const Segs& sg, int M, int N, int KS) {
        int nbx = (N + 63) >> 6;
        int nby = (M + 63) >> 6;
        int ntile = (sg.Ktot + 31) / 32;
        int tpc = (ntile + KS - 1) / KS;
        int tot_all = nbx * nby * KS;
        unsigned grid = (unsigned)(((tot_all + 7) >> 3) << 3);
        sgemm_splitk<<<grid, 256, 0, stream>>>(P, sg, M, N, nbx, nby, KS, tpc);
    };

    const unsigned r4 = (NUM_E + 3) / 4;

    // ---- prelude ----
    l2norm_rows4<<<100, 256, 0, stream>>>(reln, brel, rel, 400);
    bias_sum<<<3, 256, 0, stream>>>(bsum, b_ih, b_hh);
    cvt_bf16_k<<<nblk(600L*248), 256, 0, stream>>>(bW_ih, W_ih, 600L*248);
    cvt_bf16_k<<<nblk(600L*200), 256, 0, stream>>>(bW_hh, W_hh, 600L*200);
    tcvt_bf16_k<<<nblk(40000), 256, 0, stream>>>(bLp_t, loop_w, 200, 200);
    tcvt_bf16_k<<<nblk(40000), 256, 0, stream>>>(bWn_t,          Wn,          200, 200);
    tcvt_bf16_k<<<nblk(40000), 256, 0, stream>>>(bWn_t + 40000,  Wn + 40000,  200, 200);
    tcvt_bf16_k<<<nblk(40000), 256, 0, stream>>>(bWs_t,          Ws,          200, 200);
    tcvt_bf16_k<<<nblk(40000), 256, 0, stream>>>(bWs_t + 40000,  Ws + 40000,  200, 200);

    // ---- CSR build for ALL 3 graphs (hoisted) ----
    fill_i32<<<nblk(3L * NUM_E), 256, 0, stream>>>(cnt, 3L * NUM_E, 0);
    count_dst3<<<nblk(3L * E_EDGES), 256, 0, stream>>>(dst, cnt);
    scan_rows3<<<3, 1024, 0, stream>>>(cnt, row_start, cursor, degf, invd);
    build_perm3<<<nblk(3L * E_EDGES), 256, 0, stream>>>(src, dst, etype, cursor, ssrc, setype);
    tenc_table3<<<2, 256, 0, stream>>>(ttbl, af, ap, cf, cp);
    tenc_fill3<<<nblk(3L * NUM_E * 6), 256, 0, stream>>>(bte3, degf, ttbl);

    // prev = l2norm(ent @ loop_weight)
    cvt_bf16_k<<<nblk(nE200), 256, 0, stream>>>(btmp, ent, nE200);
    {
        GemmDesc d0 = desc(bseg1(btmp, H_DIM, bLp_t, H_DIM, H_DIM),
                           tmp, nullptr, nullptr, NUM_E, H_DIM, H_DIM, 0, 1, 0);
        launch_multi(&d0, 1);
    }
    l2norm_rows4<<<r4, 256, 0, stream>>>(prev, bprev, tmp, NUM_E);

    for (int i = 0; i < N_HIST; i++) {
        const int* ssrc_g = ssrc + (long)i * E_EDGES;
        const int* sety_g = setype + (long)i * E_EDGES;
        const int* rs_g   = row_start + i * (NUM_E + 4);
        const float* iv_g = invd + i * NUM_E;
        ushort* bte_g     = bte3 + (long)i * NUM_E * TD_DIM;

        seg_gather_norm_bf<<<r4, 256, 0, stream>>>(bh0, bprev, ssrc_g, rs_g, iv_g);

        seg_gather_layer_bf<<<r4, 256, 0, stream>>>(btmp, bh0, brel, ssrc_g, sety_g, rs_g, iv_g);
        {
            GemmDesc d0 = desc(bseg2(btmp, H_DIM, bWn_t,         H_DIM, H_DIM,
                                     bh0,  H_DIM, bWs_t,         H_DIM, H_DIM),
                               nullptr, bh1, nullptr, NUM_E, H_DIM, H_DIM, 1, 2, 0);
            launch_multi(&d0, 1);
        }
        seg_gather_layer_bf<<<r4, 256, 0, stream>>>(btmp, bh1, brel, ssrc_g, sety_g, rs_g, iv_g);
        {
            GemmDesc d0 = desc(bseg2(btmp, H_DIM, bWn_t + 40000, H_DIM, H_DIM,
                                     bh1,  H_DIM, bWs_t + 40000, H_DIM, H_DIM),
                               nullptr, bh0, nullptr, NUM_E, H_DIM, H_DIM, 1, 2, 0);
            launch_multi(&d0, 1);
        }
        l2norm_bf4<<<r4, 256, 0, stream>>>(bh0, NUM_E);

        // Merged GRU GEMMs: rz (sigmoid, N=400), iN (h1), hN (tmp) — one launch,
        // ~16.9k independent wave-tiles, no barriers.
        {
            GemmDesc d3[3];
            d3[0] = desc(bseg3(bh0,   H_DIM,  bW_ih,       248, H_DIM,
                               bte_g, TD_DIM, bW_ih + 200, 248, TD_DIM,
                               bprev, H_DIM,  bW_hh,       200, H_DIM),
                         rz, nullptr, bsum, NUM_E, 400, 400, 2, 1, 0);
            d3[1] = desc(bseg2(bh0,   H_DIM,  bW_ih + 400*248,       248, H_DIM,
                               bte_g, TD_DIM, bW_ih + 400*248 + 200, 248, TD_DIM),
                         h1, nullptr, b_ih + 400, NUM_E, H_DIM, H_DIM, 0, 1, 0);
            d3[2] = desc(bseg1(bprev, H_DIM, bW_hh + 400*200, 200, H_DIM),
                         tmp, nullptr, b_hh + 400, NUM_E, H_DIM, H_DIM, 0, 1, 0);
            launch_multi(d3, 3);
        }

        gru_fused<<<r4, 256, 0, stream>>>(prev, bprev, rz, h1, tmp);
    }

    // ---- batch head ----
    gather_qs_qr3<<<nblk((long)BATCH * H_DIM), 256, 0, stream>>>(qs3, qr3, prev, reln, data);
    semb_kernel<<<dim3(BATCH, 3), 64, 0, stream>>>(semb, prev, his_idx, his_len);
    tenc_batch<<<nblk(3L * BATCH * TD_DIM), 256, 0, stream>>>(teb, his_len, af, ap, cf, cp);

    // abuf = relu([qs|qr|semb|teb] @ Wb_w^T + Wb_b)   -- split-K, partials in h1
    {
        const int KS = 8;
        const int MN = 3 * BATCH * H_DIM;
        splitk(h1, seg4(qs3, H_DIM,  Wb_w,       648, H_DIM,
                        qr3, H_DIM,  Wb_w + 200, 648, H_DIM,
                        semb, H_DIM, Wb_w + 400, 648, H_DIM,
                        teb, TD_DIM, Wb_w + 600, 648, TD_DIM),
               3 * BATCH, H_DIM, KS);
        reduce_relu<<<nblk(MN), 256, 0, stream>>>(abuf, h1, Wb_b, MN, H_DIM, KS);
    }
    att_logits_rows<<<(3 * BATCH + 3) / 4, 256, 0, stream>>>(atts, abuf, Wc_w, Wc_b);
    softmax_out2<<<nblk((long)BATCH * H_DIM), 256, 0, stream>>>(out2, atts, semb);

    // qbuf = relu([qs|qr|out2] @ Wd_w^T + Wd_b) -> hi/lo bf16 split (partials in tmp)
    {
        const int KS = 8;
        const int MN = BATCH * H_DIM;
        splitk(tmp, seg3(qs3, H_DIM,  Wd_w,       600, H_DIM,
                         qr3, H_DIM,  Wd_w + 200, 600, H_DIM,
                         out2, H_DIM, Wd_w + 400, 600, H_DIM),
               BATCH, H_DIM, KS);
        reduce_relu_split<<<nblk(MN), 256, 0, stream>>>(qhi, qlo, tmp, Wd_b, MN, H_DIM, KS);
    }

    // plo = bf16(prev - f32(bprev))  (bprev is the hi part)
    make_lo<<<nblk(nE200), 256, 0, stream>>>(plo, prev, bprev, nE200);

    // result = q @ prev^T via hi/lo-compensated bf16 MFMA:
    //   qhi@phi + qhi@plo + qlo@phi   (3 K-segments, Ktot=600), B-reuse tile order
    {
        GemmDesc d0 = desc(bseg3(qhi, H_DIM, bprev, H_DIM, H_DIM,
                                 qhi, H_DIM, plo,   H_DIM, H_DIM,
                                 qlo, H_DIM, bprev, H_DIM, H_DIM),
                           out_p, nullptr, nullptr, BATCH, NUM_E, NUM_E, 0, 1, 1);
        launch_multi(&d0, 1);
    }
}

// Round 12
// 1093.242 us; speedup vs baseline: 1.3932x; 1.3512x over previous
//
#include <hip/hip_runtime.h>
#include <hip/hip_bf16.h>

#define NUM_E   20000
#define H_DIM   200
#define TD_DIM  48
#define HD_DIM  24
#define L_HIST  32
#define N_HIST  3
#define E_EDGES 200000
#define BATCH   512

// ---------------------------------------------------------------- utilities

__device__ inline float wave_sum64(float x) {
    #pragma unroll
    for (int m = 1; m < 64; m <<= 1) x += __shfl_xor(x, m);
    return x;
}

__device__ inline ushort f2bf(float f) {
    unsigned u = __float_as_uint(f);
    u += 0x7fffu + ((u >> 16) & 1u);
    return (ushort)(u >> 16);
}
__device__ inline float bf2f(ushort u) {
    return __uint_as_float(((unsigned)u) << 16);
}
__device__ inline float4 bf4_to_f4(ushort4 v) {
    return (float4){bf2f(v.x), bf2f(v.y), bf2f(v.z), bf2f(v.w)};
}

__global__ void fill_i32(int* __restrict__ p, long n, int v) {
    long i = (long)blockIdx.x * blockDim.x + threadIdx.x;
    if (i < n) p[i] = v;
}

__global__ void bias_sum(float* __restrict__ bsum, const float* __restrict__ b_ih,
                         const float* __restrict__ b_hh) {
    int j = blockIdx.x * 256 + threadIdx.x;
    if (j < 600) bsum[j] = b_ih[j] + b_hh[j];
}

__global__ void cvt_bf16_k(ushort* __restrict__ o, const float* __restrict__ in, long n) {
    long i = (long)blockIdx.x * 256 + threadIdx.x;
    if (i < n) o[i] = f2bf(in[i]);
}

// lo[i] = bf16(x[i] - f32(hi[i]))
__global__ void make_lo(ushort* __restrict__ lo, const float* __restrict__ x,
                        const ushort* __restrict__ hi, long n) {
    long i = (long)blockIdx.x * 256 + threadIdx.x;
    if (i < n) lo[i] = f2bf(x[i] - bf2f(hi[i]));
}

// in (R,C) row-major f32 -> o (C,R) row-major bf16
__global__ void tcvt_bf16_k(ushort* __restrict__ o, const float* __restrict__ in, int R, int C) {
    int i = blockIdx.x * 256 + threadIdx.x;
    if (i >= R * C) return;
    int r = i / C, c = i - r * C;
    o[(size_t)c * R + r] = f2bf(in[i]);
}

// ---------------------------------------------------------------- f32 split-K GEMM (B^T)
struct Segs {
    const float* A[4];
    const float* B[4];
    int lda[4], ldb[4], Ks[4];
    int nseg, Ktot;
};

__device__ inline void seg_find(const Segs& sg, int gk, int& s, int& loc) {
    s = 0; loc = gk;
    #pragma unroll
    for (int t = 0; t < 3; t++) {
        if (s + 1 < sg.nseg && loc >= sg.Ks[s]) { loc -= sg.Ks[s]; s++; }
    }
}

// Partial GEMM: P[kc][M][N] = A@B^T over k-chunk kc. BM=64, BN=64, BK=32.
__global__ __launch_bounds__(256) void sgemm_splitk(
    float* __restrict__ P, const Segs sg, int M, int N, int nbx, int nby,
    int KS, int tpc)
{
    __shared__ float As[32][68];
    __shared__ float Bs[32][68];

    int tot = nbx * nby;
    int tot_all = tot * KS;
    int chunk = (tot_all + 7) >> 3;
    int v = (int)(blockIdx.x & 7) * chunk + (int)(blockIdx.x >> 3);
    if (v >= tot_all) return;
    int kc = v / tot;
    int tile = v - kc * tot;
    int by = tile / nbx, bx = tile - by * nbx;
    const int bn = bx * 64;
    const int bm = by * 64;
    const int tid = threadIdx.x;
    const int m0 = (tid >> 4) * 4;
    const int n0 = (tid & 15) * 4;

    float acc[4][4];
    #pragma unroll
    for (int i = 0; i < 4; i++)
        #pragma unroll
        for (int j = 0; j < 4; j++) acc[i][j] = 0.f;

    const int Ktot = sg.Ktot;
    const int ntile = (Ktot + 31) / 32;
    const int kt0 = kc * tpc;
    const int kt1 = min(ntile, kt0 + tpc);

    const int a_m  = tid & 31;
    const int a_k4 = (tid >> 5) * 4;
    const int b1_n = tid & 63;
    const int b1_k = (tid >> 6) * 4;

    float4 ra[2], rb[2];
    auto loadA = [&](int k0) {
        int gk = k0 + a_k4;
        bool kin = gk < Ktot;
        int s = 0, loc = 0;
        if (kin) seg_find(sg, gk, s, loc);
        const float* Ab = sg.A[s];
        const int lda = sg.lda[s];
        #pragma unroll
        for (int r = 0; r < 2; r++) {
            int row = bm + a_m + 32 * r;
            float4 vv = {0.f, 0.f, 0.f, 0.f};
            if (kin && row < M) vv = *(const float4*)(Ab + (size_t)row * lda + loc);
            ra[r] = vv;
        }
    };
    auto loadB = [&](int k0) {
        #pragma unroll
        for (int r = 0; r < 2; r++) {
            int k4 = b1_k + 16 * r;
            int gk = k0 + k4;
            bool kin = gk < Ktot;
            int s = 0, loc = 0;
            if (kin) seg_find(sg, gk, s, loc);
            const float* Bb = sg.B[s];
            const int ldb = sg.ldb[s];
            int gn = bn + b1_n;
            float4 vv = {0.f, 0.f, 0.f, 0.f};
            if (kin && gn < N) vv = *(const float4*)(Bb + (size_t)gn * ldb + loc);
            rb[r] = vv;
        }
    };

    if (kt0 < kt1) {
        loadA(kt0 * 32); loadB(kt0 * 32);
        for (int t = kt0; t < kt1; t++) {
            #pragma unroll
            for (int r = 0; r < 2; r++) {
                int m = a_m + 32 * r;
                As[a_k4 + 0][m] = ra[r].x;
                As[a_k4 + 1][m] = ra[r].y;
                As[a_k4 + 2][m] = ra[r].z;
                As[a_k4 + 3][m] = ra[r].w;
            }
            #pragma unroll
            for (int r = 0; r < 2; r++) {
                int k4 = b1_k + 16 * r;
                Bs[k4 + 0][b1_n] = rb[r].x;
                Bs[k4 + 1][b1_n] = rb[r].y;
                Bs[k4 + 2][b1_n] = rb[r].z;
                Bs[k4 + 3][b1_n] = rb[r].w;
            }
            __syncthreads();
            if (t + 1 < kt1) { loadA((t + 1) * 32); loadB((t + 1) * 32); }
            #pragma unroll 8
            for (int kk = 0; kk < 32; kk++) {
                float4 b = *(float4*)&Bs[kk][n0];
                float4 av = *(float4*)&As[kk][m0];
                float a[4] = {av.x, av.y, av.z, av.w};
                #pragma unroll
                for (int i = 0; i < 4; i++) {
                    acc[i][0] += a[i] * b.x;
                    acc[i][1] += a[i] * b.y;
                    acc[i][2] += a[i] * b.z;
                    acc[i][3] += a[i] * b.w;
                }
            }
            __syncthreads();
        }
    }

    int col = bn + n0;
    if (col < N) {
        #pragma unroll
        for (int i = 0; i < 4; i++) {
            int row = bm + m0 + i;
            if (row < M) {
                float4 o = {acc[i][0], acc[i][1], acc[i][2], acc[i][3]};
                *(float4*)(P + ((size_t)kc * M + row) * N + col) = o;
            }
        }
    }
}

// out = relu(sum_kc P + bias)
__global__ void reduce_relu(float* __restrict__ out, const float* __restrict__ P,
                            const float* __restrict__ bias, int MN, int N, int KS)
{
    int i = blockIdx.x * 256 + threadIdx.x;
    if (i >= MN) return;
    float s = bias[i % N];
    for (int k = 0; k < KS; k++) s += P[(size_t)k * MN + i];
    out[i] = fmaxf(s, 0.f);
}

// qhi/qlo = hi/lo bf16 split of relu(sum_kc P + bias)
__global__ void reduce_relu_split(ushort* __restrict__ qhi, ushort* __restrict__ qlo,
                                  const float* __restrict__ P, const float* __restrict__ bias,
                                  int MN, int N, int KS)
{
    int i = blockIdx.x * 256 + threadIdx.x;
    if (i >= MN) return;
    float s = bias[i % N];
    for (int k = 0; k < KS; k++) s += P[(size_t)k * MN + i];
    s = fmaxf(s, 0.f);
    ushort h = f2bf(s);
    qhi[i] = h;
    qlo[i] = f2bf(s - bf2f(h));
}

// ---------------------------------------------------------------- bf16 MFMA multi-GEMM
typedef __attribute__((ext_vector_type(8))) short bfrag;
typedef __attribute__((ext_vector_type(4))) float ffrag;

struct BfSegs {
    const ushort* A[3];
    const ushort* B[3];
    int lda[3], ldb[3], Ks[3];
    int nseg, Ktot;
};

__device__ inline void bseg_find(const BfSegs& sg, int gk, int& s, int& loc) {
    s = 0; loc = gk;
    #pragma unroll
    for (int t = 0; t < 2; t++) {
        if (s + 1 < sg.nseg && loc >= sg.Ks[s]) { loc -= sg.Ks[s]; s++; }
    }
}

// One GEMM description. Tile is 64x64 (4 waves, each 32x32).
// act: 0 none, 1 relu, 2 sigmoid.  flags: 1 = write f32 C, 2 = write bf16 Cb.
// order: 0 = row-major tiles (A-reuse), 1 = col-major tiles (B-reuse, XCD-contig).
struct GemmDesc {
    BfSegs sg;
    float* C;
    ushort* Cb;
    const float* bias;
    int M, N, ldc;
    int act, flags, order;
    int nbx, nby, blk0, nblk;
};

struct MultiArgs {
    GemmDesc d[3];
    int nd;
    int tot;
};

template<int DI>
__device__ __forceinline__ void gemm_body(const MultiArgs& ma, int v,
                                          ushort* __restrict__ Als,
                                          ushort* __restrict__ Bls)
{
    const GemmDesc& D = ma.d[DI];
    const BfSegs& sg = D.sg;
    const int tile = v - D.blk0;
    int by, bx;
    if (D.order == 0) { by = tile / D.nbx; bx = tile - by * D.nbx; }
    else              { bx = tile / D.nby; by = tile - bx * D.nby; }
    const int bm = by * 64, bn = bx * 64;
    const int M = D.M, N = D.N;

    const int tid  = threadIdx.x;
    const int lane = tid & 63;
    const int w    = tid >> 6;
    const int wm   = (w & 1) * 2;
    const int wn   = (w >> 1) * 2;

    ffrag acc[2][2];
    #pragma unroll
    for (int i = 0; i < 2; i++)
        #pragma unroll
        for (int j = 0; j < 2; j++) acc[i][j] = (ffrag){0.f, 0.f, 0.f, 0.f};

    const int Ktot = sg.Ktot;
    const int nkt = (Ktot + 63) >> 6;

    int a_m[2], a_kq[2], a_wc[2];
    #pragma unroll
    for (int i = 0; i < 2; i++) {
        int c = i * 256 + tid;
        a_m[i] = c & 63; a_kq[i] = c >> 6;
        a_wc[i] = ((a_m[i] >> 4) * 2 + (a_kq[i] >> 2)) * 64 + (a_kq[i] & 3) * 16 + (a_m[i] & 15);
    }
    int b_n[2], b_kq[2], b_wc[2];
    #pragma unroll
    for (int i = 0; i < 2; i++) {
        int c = i * 256 + tid;
        b_n[i] = c & 63; b_kq[i] = c >> 6;
        b_wc[i] = ((b_n[i] >> 4) * 2 + (b_kq[i] >> 2)) * 64 + (b_kq[i] & 3) * 16 + (b_n[i] & 15);
    }

    uint4 ra[2], rb[2];
    auto loadA = [&](int k0) {
        #pragma unroll
        for (int i = 0; i < 2; i++) {
            int gk = k0 + a_kq[i] * 8;
            int row = bm + a_m[i];
            uint4 vv = {0u, 0u, 0u, 0u};
            if (gk < Ktot && row < M) {
                int s, loc; bseg_find(sg, gk, s, loc);
                vv = *(const uint4*)(sg.A[s] + (size_t)row * sg.lda[s] + loc);
            }
            ra[i] = vv;
        }
    };
    auto loadB = [&](int k0) {
        #pragma unroll
        for (int i = 0; i < 2; i++) {
            int gk = k0 + b_kq[i] * 8;
            int gn = bn + b_n[i];
            uint4 vv = {0u, 0u, 0u, 0u};
            if (gk < Ktot && gn < N) {
                int s, loc; bseg_find(sg, gk, s, loc);
                vv = *(const uint4*)(sg.B[s] + (size_t)gn * sg.ldb[s] + loc);
            }
            rb[i] = vv;
        }
    };

    loadA(0); loadB(0);

    for (int t = 0; t < nkt; t++) {
        #pragma unroll
        for (int i = 0; i < 2; i++) *(uint4*)(&Als[a_wc[i] * 8]) = ra[i];
        #pragma unroll
        for (int i = 0; i < 2; i++) *(uint4*)(&Bls[b_wc[i] * 8]) = rb[i];
        __syncthreads();

        if (t + 1 < nkt) { loadA((t + 1) << 6); loadB((t + 1) << 6); }

        #pragma unroll
        for (int kt = 0; kt < 2; kt++) {
            bfrag af[2], bf[2];
            #pragma unroll
            for (int i = 0; i < 2; i++)
                af[i] = *(const bfrag*)(&Als[(((wm + i) * 2 + kt) * 64 + lane) * 8]);
            #pragma unroll
            for (int j = 0; j < 2; j++)
                bf[j] = *(const bfrag*)(&Bls[(((wn + j) * 2 + kt) * 64 + lane) * 8]);
            #pragma unroll
            for (int i = 0; i < 2; i++)
                #pragma unroll
                for (int j = 0; j < 2; j++)
                    acc[i][j] = __builtin_amdgcn_mfma_f32_16x16x32_bf16(af[i], bf[j], acc[i][j], 0, 0, 0);
        }
        __syncthreads();
    }

    const int rbase = (lane >> 4) * 4;
    const int cl = lane & 15;
    #pragma unroll
    for (int j = 0; j < 2; j++) {
        int col = bn + (wn + j) * 16 + cl;
        if (col >= N) continue;
        float bv = D.bias ? D.bias[col] : 0.f;
        #pragma unroll
        for (int i = 0; i < 2; i++) {
            int mrow = bm + (wm + i) * 16 + rbase;
            #pragma unroll
            for (int r = 0; r < 4; r++) {
                int row = mrow + r;
                if (row < M) {
                    float o = acc[i][j][r] + bv;
                    if (D.act == 1) o = fmaxf(o, 0.f);
                    else if (D.act == 2) o = 1.f / (1.f + expf(-o));
                    if (D.flags & 1) D.C[(size_t)row * D.ldc + col] = o;
                    if (D.flags & 2) D.Cb[(size_t)row * D.ldc + col] = f2bf(o);
                }
            }
        }
    }
}

__global__ __launch_bounds__(256) void mfma_multi(MultiArgs ma)
{
    __shared__ __align__(16) ushort Als[4096];
    __shared__ __align__(16) ushort Bls[4096];

    int tot = ma.tot;
    int chunk = (tot + 7) >> 3;
    int v = (int)(blockIdx.x & 7) * chunk + (int)(blockIdx.x >> 3);
    if (v >= tot) return;

    int di = 0;
    if (ma.nd > 1 && v >= ma.d[1].blk0) di = 1;
    if (ma.nd > 2 && v >= ma.d[2].blk0) di = 2;

    if (di == 0)      gemm_body<0>(ma, v, Als, Bls);
    else if (di == 1) gemm_body<1>(ma, v, Als, Bls);
    else              gemm_body<2>(ma, v, Als, Bls);
}

// ---------------------------------------------------------------- CSR build (all 3 graphs, hoisted)

// count over all 3 graphs: cnt[g*NUM_E + d]
__global__ void count_dst3(const int* __restrict__ dst, int* __restrict__ cnt) {
    long e = (long)blockIdx.x * 256 + threadIdx.x;
    if (e < (long)N_HIST * E_EDGES) {
        int g = (int)(e / E_EDGES);
        atomicAdd(&cnt[g * NUM_E + dst[e]], 1);
    }
}

// one block per graph (3 concurrent scans)
__global__ __launch_bounds__(1024) void scan_rows3(
    const int* __restrict__ cnt_all, int* __restrict__ row_start_all,
    int* __restrict__ cursor_all, float* __restrict__ degf_all,
    float* __restrict__ invd_all)
{
    __shared__ int part[1024];
    const int g = blockIdx.x;
    const int* cnt = cnt_all + g * NUM_E;
    int* row_start  = row_start_all + g * (NUM_E + 4);
    int* cursor     = cursor_all + g * NUM_E;
    float* degf     = degf_all + g * NUM_E;
    float* invd     = invd_all + g * NUM_E;

    const int CH = (NUM_E + 1023) / 1024;
    int t = threadIdx.x;
    int base = t * CH;
    int local[32];
    int s = 0;
    for (int j = 0; j < CH; j++) {
        int idx = base + j;
        int c = (idx < NUM_E) ? cnt[idx] : 0;
        local[j] = s; s += c;
    }
    part[t] = s;
    __syncthreads();
    for (int off = 1; off < 1024; off <<= 1) {
        int vv = (t >= off) ? part[t - off] : 0;
        __syncthreads();
        part[t] += vv;
        __syncthreads();
    }
    int pre = (t == 0) ? 0 : part[t - 1];
    for (int j = 0; j < CH; j++) {
        int idx = base + j;
        if (idx < NUM_E) {
            int rs = pre + local[j];
            row_start[idx] = rs;
            cursor[idx] = rs;
            int c = cnt[idx];
            degf[idx] = (float)c;
            invd[idx] = 1.f / fmaxf((float)c, 1.f);
        }
    }
    if (t == 1023) row_start[NUM_E] = part[1023];
}

__global__ void build_perm3(const int* __restrict__ src, const int* __restrict__ dst,
                            const int* __restrict__ etype, int* __restrict__ cursor_all,
                            int* __restrict__ ssrc_all, int* __restrict__ setype_all)
{
    long e = (long)blockIdx.x * 256 + threadIdx.x;
    if (e >= (long)N_HIST * E_EDGES) return;
    int g = (int)(e / E_EDGES);
    int pos = atomicAdd(&cursor_all[g * NUM_E + dst[e]], 1);
    ssrc_all[(long)g * E_EDGES + pos]   = src[e];
    setype_all[(long)g * E_EDGES + pos] = etype[e];
}

// ---------------------------------------------------------------- gathers (bf16 in/out)

__global__ __launch_bounds__(256) void seg_gather_norm_bf(
    ushort* __restrict__ bh, const ushort* __restrict__ bprev,
    const int* __restrict__ ssrc, const int* __restrict__ row_start,
    const float* __restrict__ invd)
{
    int v = blockIdx.x * 4 + (threadIdx.x >> 6);
    int lane = threadIdx.x & 63;
    if (v >= NUM_E) return;
    int s0 = row_start[v], s1 = row_start[v + 1];
    bool act = lane < 50;
    float4 acc = {0.f, 0.f, 0.f, 0.f};
    int j = s0;
    for (; j + 1 < s1; j += 2) {
        int sa = ssrc[j], sb = ssrc[j + 1];
        if (act) {
            float4 xa = bf4_to_f4(*(const ushort4*)(bprev + (long)sa * H_DIM + lane * 4));
            float4 xb = bf4_to_f4(*(const ushort4*)(bprev + (long)sb * H_DIM + lane * 4));
            acc.x += xa.x + xb.x; acc.y += xa.y + xb.y;
            acc.z += xa.z + xb.z; acc.w += xa.w + xb.w;
        }
    }
    if (j < s1) {
        int sa = ssrc[j];
        if (act) {
            float4 xa = bf4_to_f4(*(const ushort4*)(bprev + (long)sa * H_DIM + lane * 4));
            acc.x += xa.x; acc.y += xa.y; acc.z += xa.z; acc.w += xa.w;
        }
    }
    float iv = invd[v];
    acc.x *= iv; acc.y *= iv; acc.z *= iv; acc.w *= iv;
    float ss = act ? (acc.x*acc.x + acc.y*acc.y + acc.z*acc.z + acc.w*acc.w) : 0.f;
    ss = wave_sum64(ss);
    float r = 1.f / fmaxf(sqrtf(ss), 1e-12f);
    if (act) {
        ushort4 ob = {f2bf(acc.x * r), f2bf(acc.y * r), f2bf(acc.z * r), f2bf(acc.w * r)};
        *(ushort4*)(bh + (long)v * H_DIM + lane * 4) = ob;
    }
}

__global__ __launch_bounds__(256) void seg_gather_layer_bf(
    ushort* __restrict__ btmp, const ushort* __restrict__ bh, const ushort* __restrict__ brel,
    const int* __restrict__ ssrc, const int* __restrict__ setype,
    const int* __restrict__ row_start, const float* __restrict__ invd)
{
    int v = blockIdx.x * 4 + (threadIdx.x >> 6);
    int lane = threadIdx.x & 63;
    if (v >= NUM_E) return;
    int s0 = row_start[v], s1 = row_start[v + 1];
    bool act = lane < 50;
    float4 acc = {0.f, 0.f, 0.f, 0.f};
    int j = s0;
    for (; j + 1 < s1; j += 2) {
        int sa = ssrc[j], ta = setype[j];
        int sb = ssrc[j + 1], tb = setype[j + 1];
        if (act) {
            float4 xa = bf4_to_f4(*(const ushort4*)(bh   + (long)sa * H_DIM + lane * 4));
            float4 ya = bf4_to_f4(*(const ushort4*)(brel + (long)ta * H_DIM + lane * 4));
            float4 xb = bf4_to_f4(*(const ushort4*)(bh   + (long)sb * H_DIM + lane * 4));
            float4 yb = bf4_to_f4(*(const ushort4*)(brel + (long)tb * H_DIM + lane * 4));
            acc.x += (xa.x + ya.x) + (xb.x + yb.x);
            acc.y += (xa.y + ya.y) + (xb.y + yb.y);
            acc.z += (xa.z + ya.z) + (xb.z + yb.z);
            acc.w += (xa.w + ya.w) + (xb.w + yb.w);
        }
    }
    if (j < s1) {
        int s = ssrc[j];
        int t = setype[j];
        if (act) {
            float4 x = bf4_to_f4(*(const ushort4*)(bh   + (long)s * H_DIM + lane * 4));
            float4 y = bf4_to_f4(*(const ushort4*)(brel + (long)t * H_DIM + lane * 4));
            acc.x += x.x + y.x; acc.y += x.y + y.y;
            acc.z += x.z + y.z; acc.w += x.w + y.w;
        }
    }
    float iv = invd[v];
    if (act) {
        ushort4 ob = {f2bf(acc.x * iv), f2bf(acc.y * iv), f2bf(acc.z * iv), f2bf(acc.w * iv)};
        *(ushort4*)(btmp + (long)v * H_DIM + lane * 4) = ob;
    }
}

// ---------------------------------------------------------------- row kernels

__global__ __launch_bounds__(256) void l2norm_rows4(
    float* __restrict__ out, ushort* __restrict__ bout,
    const float* __restrict__ in, int nrows)
{
    int v = blockIdx.x * 4 + (threadIdx.x >> 6);
    int lane = threadIdx.x & 63;
    if (v >= nrows) return;
    bool act = lane < 50;
    float4 x = {0.f, 0.f, 0.f, 0.f};
    if (act) x = *(const float4*)(in + (long)v * H_DIM + lane * 4);
    float ss = x.x*x.x + x.y*x.y + x.z*x.z + x.w*x.w;
    ss = wave_sum64(ss);
    float r = 1.f / fmaxf(sqrtf(ss), 1e-12f);
    if (act) {
        long base = (long)v * H_DIM + lane * 4;
        float4 o = {x.x * r, x.y * r, x.z * r, x.w * r};
        *(float4*)(out + base) = o;
        if (bout) {
            ushort4 ob = {f2bf(o.x), f2bf(o.y), f2bf(o.z), f2bf(o.w)};
            *(ushort4*)(bout + base) = ob;
        }
    }
}

__global__ __launch_bounds__(256) void l2norm_bf4(ushort* __restrict__ b, int nrows)
{
    int v = blockIdx.x * 4 + (threadIdx.x >> 6);
    int lane = threadIdx.x & 63;
    if (v >= nrows) return;
    bool act = lane < 50;
    float4 x = {0.f, 0.f, 0.f, 0.f};
    long base = (long)v * H_DIM + lane * 4;
    if (act) x = bf4_to_f4(*(const ushort4*)(b + base));
    float ss = x.x*x.x + x.y*x.y + x.z*x.z + x.w*x.w;
    ss = wave_sum64(ss);
    float r = 1.f / fmaxf(sqrtf(ss), 1e-12f);
    if (act) {
        ushort4 ob = {f2bf(x.x * r), f2bf(x.y * r), f2bf(x.z * r), f2bf(x.w * r)};
        *(ushort4*)(b + base) = ob;
    }
}

// 3 graphs x 2 rows x 48 bf16 time-encoding table (row stride 64)
__global__ void tenc_table3(ushort* __restrict__ tbl, const float* __restrict__ af,
                            const float* __restrict__ ap, const float* __restrict__ cf,
                            const float* __restrict__ cp)
{
    int j = blockIdx.x * 256 + threadIdx.x;
    if (j >= 384) return;
    int g = j >> 7;
    int r = j & 127;
    int half = r >> 6;
    int jj = r & 63;
    if (jj >= TD_DIM) return;
    float tcnt = (float)(N_HIST - 1 - g);
    float t = half ? 100.0f : tcnt;
    float val;
    if (jj < HD_DIM) val = tanhf((t + 1.f) * af[jj] + ap[jj]);
    else             val = cosf(t * cf[jj - HD_DIM] + cp[jj - HD_DIM]);
    tbl[g * 128 + half * 64 + jj] = f2bf(val);
}

// bte3[g][v][:] = tbl[g][deg>0 ? 0 : 1][:]  (uint4 copies)
__global__ void tenc_fill3(ushort* __restrict__ bte3, const float* __restrict__ degf_all,
                           const ushort* __restrict__ tbl)
{
    long idx = (long)blockIdx.x * 256 + threadIdx.x;
    if (idx >= (long)N_HIST * NUM_E * 6) return;
    int g = (int)(idx / (NUM_E * 6));
    int rem = (int)(idx - (long)g * NUM_E * 6);
    int v = rem / 6, c = rem - v * 6;
    int base = (degf_all[g * NUM_E + v] > 0.f) ? 0 : 64;
    *(uint4*)(bte3 + ((long)g * NUM_E + v) * TD_DIM + c * 8) =
        *(const uint4*)(tbl + g * 128 + base + c * 8);
}

__global__ __launch_bounds__(256) void gru_fused(
    float* __restrict__ prev, ushort* __restrict__ bprev, const float* __restrict__ rz,
    const float* __restrict__ iN, const float* __restrict__ hN)
{
    int v = blockIdx.x * 4 + (threadIdx.x >> 6);
    int lane = threadIdx.x & 63;
    if (v >= NUM_E) return;
    bool act = lane < 50;
    long b200 = (long)v * H_DIM + lane * 4;
    long b400 = (long)v * 400 + lane * 4;
    float4 o = {0.f, 0.f, 0.f, 0.f};
    if (act) {
        float4 r4 = *(const float4*)(rz + b400);
        float4 z4 = *(const float4*)(rz + b400 + 200);
        float4 n4 = *(const float4*)(iN + b200);
        float4 g4 = *(const float4*)(hN + b200);
        float4 p4 = *(const float4*)(prev + b200);
        float ngx = tanhf(n4.x + r4.x * g4.x);
        float ngy = tanhf(n4.y + r4.y * g4.y);
        float ngz = tanhf(n4.z + r4.z * g4.z);
        float ngw = tanhf(n4.w + r4.w * g4.w);
        o.x = (1.f - z4.x) * ngx + z4.x * p4.x;
        o.y = (1.f - z4.y) * ngy + z4.y * p4.y;
        o.z = (1.f - z4.z) * ngz + z4.z * p4.z;
        o.w = (1.f - z4.w) * ngw + z4.w * p4.w;
    }
    float ss = o.x*o.x + o.y*o.y + o.z*o.z + o.w*o.w;
    ss = wave_sum64(ss);
    float r = 1.f / fmaxf(sqrtf(ss), 1e-12f);
    if (act) {
        float4 wv = {o.x * r, o.y * r, o.z * r, o.w * r};
        *(float4*)(prev + b200) = wv;
        ushort4 ob = {f2bf(wv.x), f2bf(wv.y), f2bf(wv.z), f2bf(wv.w)};
        *(ushort4*)(bprev + b200) = ob;
    }
}

// ---------------------------------------------------------------- batch head

__global__ void gather_qs_qr3(float* __restrict__ qs3, float* __restrict__ qr3,
                              const float* __restrict__ out, const float* __restrict__ reln,
                              const int* __restrict__ data)
{
    long i = (long)blockIdx.x * 256 + threadIdx.x;
    if (i >= (long)BATCH * H_DIM) return;
    int b = (int)(i / H_DIM), j = (int)(i % H_DIM);
    float vs = out[(long)data[b * 4 + 0] * H_DIM + j];
    float vr = reln[(long)data[b * 4 + 1] * H_DIM + j];
    const long S = (long)BATCH * H_DIM;
    qs3[i] = vs; qs3[i + S] = vs; qs3[i + 2*S] = vs;
    qr3[i] = vr; qr3[i + S] = vr; qr3[i + 2*S] = vr;
}

__global__ __launch_bounds__(64) void semb_kernel(
    float* __restrict__ semb, const float* __restrict__ out,
    const int* __restrict__ his_idx, const int* __restrict__ his_len)
{
    int b = blockIdx.x, k = blockIdx.y;
    int lane = threadIdx.x;
    int ln = his_len[b * 3 + k];
    if (ln > L_HIST) ln = L_HIST;
    float vals[4] = {0.f, 0.f, 0.f, 0.f};
    for (int l = 0; l < ln; l++) {
        int idx = his_idx[((long)b * 3 + k) * L_HIST + l];
        #pragma unroll
        for (int t = 0; t < 4; t++) {
            int j = lane + t * 64;
            if (j < H_DIM) vals[t] += out[(long)idx * H_DIM + j];
        }
    }
    float scale = 1.f / fmaxf((float)ln, 1.f);
    float ss = 0.f;
    #pragma unroll
    for (int t = 0; t < 4; t++) { vals[t] *= scale; ss += vals[t] * vals[t]; }
    ss = wave_sum64(ss);
    float r = 1.f / fmaxf(sqrtf(ss), 1e-12f);
    #pragma unroll
    for (int t = 0; t < 4; t++) {
        int j = lane + t * 64;
        if (j < H_DIM) semb[((long)k * BATCH + b) * H_DIM + j] = vals[t] * r;
    }
}

__global__ void tenc_batch(float* __restrict__ teb, const int* __restrict__ his_len,
                           const float* __restrict__ af, const float* __restrict__ ap,
                           const float* __restrict__ cf, const float* __restrict__ cp)
{
    int idx = blockIdx.x * 256 + threadIdx.x;
    if (idx >= 3 * BATCH * TD_DIM) return;
    int k = idx / (BATCH * TD_DIM);
    int rem = idx - k * (BATCH * TD_DIM);
    int b = rem / TD_DIM, j = rem % TD_DIM;
    int ln = his_len[b * 3 + k];
    float t = (ln > 0) ? (float)(2 - k) : 100.0f;
    float val;
    if (j < HD_DIM) val = tanhf((t + 1.f) * af[j] + ap[j]);
    else            val = cosf(t * cf[j - HD_DIM] + cp[j - HD_DIM]);
    teb[idx] = val;
}

__global__ __launch_bounds__(256) void att_logits_rows(
    float* __restrict__ atts, const float* __restrict__ a,
    const float* __restrict__ Wc_w, const float* __restrict__ Wc_b)
{
    int row = blockIdx.x * 4 + (threadIdx.x >> 6);
    int lane = threadIdx.x & 63;
    if (row >= 3 * BATCH) return;
    int k = row >> 9;
    int b = row & 511;
    float s = 0.f;
    for (int j = lane; j < H_DIM; j += 64) s += a[(long)row * H_DIM + j] * Wc_w[j];
    s = wave_sum64(s);
    if (lane == 0) atts[b * 3 + k] = s + Wc_b[0];
}

__global__ void softmax_out2(float* __restrict__ out2, const float* __restrict__ atts,
                             const float* __restrict__ semb)
{
    long i = (long)blockIdx.x * 256 + threadIdx.x;
    if (i >= (long)BATCH * H_DIM) return;
    int b = (int)(i / H_DIM), j = (int)(i % H_DIM);
    float l0 = atts[b * 3 + 0], l1 = atts[b * 3 + 1], l2 = atts[b * 3 + 2];
    float m = fmaxf(l0, fmaxf(l1, l2));
    float e0 = expf(l0 - m), e1 = expf(l1 - m), e2 = expf(l2 - m);
    float s = e0 + e1 + e2;
    float v = (e0 * semb[((long)0 * BATCH + b) * H_DIM + j] +
               e1 * semb[((long)1 * BATCH + b) * H_DIM + j] +
               e2 * semb[((long)2 * BATCH + b) * H_DIM + j]) / s;
    out2[i] = v;
}

// ---------------------------------------------------------------- launch

extern "C" void kernel_launch(void* const* d_in, const int* in_sizes, int n_in,
                              void* d_out, int out_size, void* d_ws, size_t ws_size,
                              hipStream_t stream)
{
    (void)in_sizes; (void)n_in; (void)out_size; (void)ws_size;

    const int*   src     = (const int*)d_in[0];
    const int*   dst     = (const int*)d_in[1];
    const int*   etype   = (const int*)d_in[2];
    const int*   data    = (const int*)d_in[3];
    const int*   his_idx = (const int*)d_in[4];
    const int*   his_len = (const int*)d_in[5];
    const float* ent     = (const float*)d_in[6];
    const float* loop_w  = (const float*)d_in[7];
    const float* rel     = (const float*)d_in[8];
    const float* af      = (const float*)d_in[9];
    const float* ap      = (const float*)d_in[10];
    const float* cf      = (const float*)d_in[11];
    const float* cp      = (const float*)d_in[12];
    const float* Wn      = (const float*)d_in[13];
    const float* Ws      = (const float*)d_in[14];
    const float* W_ih    = (const float*)d_in[15];
    const float* W_hh    = (const float*)d_in[16];
    const float* b_ih    = (const float*)d_in[17];
    const float* b_hh    = (const float*)d_in[18];
    const float* Wb_w    = (const float*)d_in[19];
    const float* Wb_b    = (const float*)d_in[20];
    const float* Wc_w    = (const float*)d_in[21];
    const float* Wc_b    = (const float*)d_in[22];
    const float* Wd_w    = (const float*)d_in[23];
    const float* Wd_b    = (const float*)d_in[24];
    float* out_p = (float*)d_out;

    float* wp = (float*)d_ws;
    size_t off = 0;
    auto alloc = [&](size_t n) {
        size_t n4 = (n + 3) & ~(size_t)3;
        float* p = wp + off; off += n4; return p;
    };
    const long nE200 = (long)NUM_E * H_DIM;
    float* prev   = alloc(nE200);
    float* h1     = alloc(nE200);                       // GRU iN (f32); batch head: split-K partials
    float* tmp    = alloc(nE200);                       // init gemm out; GRU hN; qbuf partials
    float* rz     = out_p;                              // (NUM_E x 400) scratch in d_out
    ushort* bh0   = (ushort*)alloc(nE200 / 2);
    ushort* bh1   = (ushort*)alloc(nE200 / 2);
    ushort* btmp  = (ushort*)alloc(nE200 / 2);
    ushort* bprev = (ushort*)alloc(nE200 / 2);
    ushort* plo   = (ushort*)alloc(nE200 / 2);
    ushort* bte3  = (ushort*)alloc((size_t)N_HIST * NUM_E * TD_DIM / 2);
    ushort* brel  = (ushort*)alloc(400 * H_DIM / 2);
    ushort* bW_ih = (ushort*)alloc(600 * 248 / 2);
    ushort* bW_hh = (ushort*)alloc(600 * 200 / 2);
    ushort* bWn_t = (ushort*)alloc(2 * 200 * 200 / 2);
    ushort* bWs_t = (ushort*)alloc(2 * 200 * 200 / 2);
    ushort* bLp_t = (ushort*)alloc(200 * 200 / 2);
    ushort* qhi   = (ushort*)alloc(BATCH * H_DIM / 2);
    ushort* qlo   = (ushort*)alloc(BATCH * H_DIM / 2);
    ushort* ttbl  = (ushort*)alloc(256);                // 3*128 ushorts
    float* degf   = alloc(3 * NUM_E);
    float* invd   = alloc(3 * NUM_E);
    float* reln   = alloc(400 * H_DIM);
    float* bsum   = alloc(1024);
    float* qs3    = alloc(3 * BATCH * H_DIM);
    float* qr3    = alloc(3 * BATCH * H_DIM);
    float* semb   = alloc(3 * BATCH * H_DIM);
    float* teb    = alloc(3 * BATCH * TD_DIM);
    float* abuf   = alloc(3 * BATCH * H_DIM);
    float* atts   = alloc(2048);
    float* out2   = alloc(BATCH * H_DIM);
    int* cnt       = (int*)alloc(3 * NUM_E);
    int* row_start = (int*)alloc(3 * (NUM_E + 4));
    int* cursor    = (int*)alloc(3 * NUM_E);
    int* ssrc      = (int*)alloc(3L * E_EDGES);
    int* setype    = (int*)alloc(3L * E_EDGES);

    auto nblk = [](long n) { return (unsigned)((n + 255) / 256); };

    auto bseg1 = [](const ushort* A, int la, const ushort* B, int lb, int K) {
        BfSegs s{}; s.A[0]=A; s.lda[0]=la; s.B[0]=B; s.ldb[0]=lb; s.Ks[0]=K;
        s.nseg=1; s.Ktot=K; return s;
    };
    auto bseg2 = [](const ushort* A0, int la0, const ushort* B0, int lb0, int K0,
                    const ushort* A1, int la1, const ushort* B1, int lb1, int K1) {
        BfSegs s{}; s.A[0]=A0; s.lda[0]=la0; s.B[0]=B0; s.ldb[0]=lb0; s.Ks[0]=K0;
        s.A[1]=A1; s.lda[1]=la1; s.B[1]=B1; s.ldb[1]=lb1; s.Ks[1]=K1;
        s.nseg=2; s.Ktot=K0+K1; return s;
    };
    auto bseg3 = [](const ushort* A0, int la0, const ushort* B0, int lb0, int K0,
                    const ushort* A1, int la1, const ushort* B1, int lb1, int K1,
                    const ushort* A2, int la2, const ushort* B2, int lb2, int K2) {
        BfSegs s{}; s.A[0]=A0; s.lda[0]=la0; s.B[0]=B0; s.ldb[0]=lb0; s.Ks[0]=K0;
        s.A[1]=A1; s.lda[1]=la1; s.B[1]=B1; s.ldb[1]=lb1; s.Ks[1]=K1;
        s.A[2]=A2; s.lda[2]=la2; s.B[2]=B2; s.ldb[2]=lb2; s.Ks[2]=K2;
        s.nseg=3; s.Ktot=K0+K1+K2; return s;
    };

    auto desc = [](const BfSegs& sg, float* C, ushort* Cb, const float* bias,
                   int M, int N, int ldc, int act, int flags, int order) {
        GemmDesc D{}; D.sg=sg; D.C=C; D.Cb=Cb; D.bias=bias;
        D.M=M; D.N=N; D.ldc=ldc; D.act=act; D.flags=flags; D.order=order;
        D.nbx=(N+63)>>6; D.nby=(M+63)>>6; D.nblk=D.nbx*D.nby; D.blk0=0;
        return D;
    };
    auto launch_multi = [&](GemmDesc* ds, int nd) {
        MultiArgs ma{};
        int tot = 0;
        for (int i = 0; i < nd; i++) { ds[i].blk0 = tot; tot += ds[i].nblk; ma.d[i] = ds[i]; }
        ma.nd = nd; ma.tot = tot;
        unsigned grid = (unsigned)(((tot + 7) >> 3) << 3);
        mfma_multi<<<grid, 256, 0, stream>>>(ma);
    };

    auto seg3 = [](const float* A0, int la0, const float* B0, int lb0, int K0,
                   const float* A1, int la1, const float* B1, int lb1, int K1,
                   const float* A2, int la2, const float* B2, int lb2, int K2) {
        Segs s{}; s.A[0]=A0; s.lda[0]=la0; s.B[0]=B0; s.ldb[0]=lb0; s.Ks[0]=K0;
        s.A[1]=A1; s.lda[1]=la1; s.B[1]=B1; s.ldb[1]=lb1; s.Ks[1]=K1;
        s.A[2]=A2; s.lda[2]=la2; s.B[2]=B2; s.ldb[2]=lb2; s.Ks[2]=K2;
        s.nseg=3; s.Ktot=K0+K1+K2; return s;
    };
    auto seg4 = [](const float* A0, int la0, const float* B0, int lb0, int K0,
                   const float* A1, int la1, const float* B1, int lb1, int K1,
                   const float* A2, int la2, const float* B2, int lb2, int K2,
                   const float* A3, int la3, const float* B3, int lb3, int K3) {
        Segs s{}; s.A[0]=A0; s.lda[0]=la0; s.B[0]=B0; s.ldb[0]=lb0; s.Ks[0]=K0;
        s.A[1]=A1; s.lda[1]=la1; s.B[1]=B1; s.ldb[1]=lb1; s.Ks[1]=K1;
        s.A[2]=A2; s.lda[2]=la2; s.B[2]=B2; s.ldb[2]=lb2; s.Ks[2]=K2;
        s.A[3]=A3; s.lda[3]=la3; s.B[3]=B3; s.ldb[3]=lb3; s.Ks[3]=K3;
        s.nseg=4; s.Ktot=K0+K1+K2+K3; return s;
    };
    // split-K partial gemm launcher
    auto splitk = [&](float* P, const Segs& sg, int M, int N, int KS) {
        int nbx = (N + 63) >> 6;
        int nby = (M + 63) >> 6;
        int ntile = (sg.Ktot + 31) / 32;
        int tpc = (ntile + KS - 1) / KS;
        int tot_all = nbx * nby * KS;
        unsigned grid = (unsigned)(((tot_all + 7) >> 3) << 3);
        sgemm_splitk<<<grid, 256, 0, stream>>>(P, sg, M, N, nbx, nby, KS, tpc);
    };

    const unsigned r4 = (NUM_E + 3) / 4;

    // ---- prelude ----
    l2norm_rows4<<<100, 256, 0, stream>>>(reln, brel, rel, 400);
    bias_sum<<<3, 256, 0, stream>>>(bsum, b_ih, b_hh);
    cvt_bf16_k<<<nblk(600L*248), 256, 0, stream>>>(bW_ih, W_ih, 600L*248);
    cvt_bf16_k<<<nblk(600L*200), 256, 0, stream>>>(bW_hh, W_hh, 600L*200);
    tcvt_bf16_k<<<nblk(40000), 256, 0, stream>>>(bLp_t, loop_w, 200, 200);
    tcvt_bf16_k<<<nblk(40000), 256, 0, stream>>>(bWn_t,          Wn,          200, 200);
    tcvt_bf16_k<<<nblk(40000), 256, 0, stream>>>(bWn_t + 40000,  Wn + 40000,  200, 200);
    tcvt_bf16_k<<<nblk(40000), 256, 0, stream>>>(bWs_t,          Ws,          200, 200);
    tcvt_bf16_k<<<nblk(40000), 256, 0, stream>>>(bWs_t + 40000,  Ws + 40000,  200, 200);

    // ---- CSR build for ALL 3 graphs (hoisted; 6 launches instead of 18) ----
    fill_i32<<<nblk(3L * NUM_E), 256, 0, stream>>>(cnt, 3L * NUM_E, 0);
    count_dst3<<<nblk(3L * E_EDGES), 256, 0, stream>>>(dst, cnt);
    scan_rows3<<<3, 1024, 0, stream>>>(cnt, row_start, cursor, degf, invd);
    build_perm3<<<nblk(3L * E_EDGES), 256, 0, stream>>>(src, dst, etype, cursor, ssrc, setype);
    tenc_table3<<<2, 256, 0, stream>>>(ttbl, af, ap, cf, cp);
    tenc_fill3<<<nblk(3L * NUM_E * 6), 256, 0, stream>>>(bte3, degf, ttbl);

    // prev = l2norm(ent @ loop_weight)
    cvt_bf16_k<<<nblk(nE200), 256, 0, stream>>>(btmp, ent, nE200);
    {
        GemmDesc d0 = desc(bseg1(btmp, H_DIM, bLp_t, H_DIM, H_DIM),
                           tmp, nullptr, nullptr, NUM_E, H_DIM, H_DIM, 0, 1, 0);
        launch_multi(&d0, 1);
    }
    l2norm_rows4<<<r4, 256, 0, stream>>>(prev, bprev, tmp, NUM_E);

    for (int i = 0; i < N_HIST; i++) {
        const int* ssrc_g = ssrc + (long)i * E_EDGES;
        const int* sety_g = setype + (long)i * E_EDGES;
        const int* rs_g   = row_start + i * (NUM_E + 4);
        const float* iv_g = invd + i * NUM_E;
        ushort* bte_g     = bte3 + (long)i * NUM_E * TD_DIM;

        seg_gather_norm_bf<<<r4, 256, 0, stream>>>(bh0, bprev, ssrc_g, rs_g, iv_g);

        seg_gather_layer_bf<<<r4, 256, 0, stream>>>(btmp, bh0, brel, ssrc_g, sety_g, rs_g, iv_g);
        {
            GemmDesc d0 = desc(bseg2(btmp, H_DIM, bWn_t,         H_DIM, H_DIM,
                                     bh0,  H_DIM, bWs_t,         H_DIM, H_DIM),
                               nullptr, bh1, nullptr, NUM_E, H_DIM, H_DIM, 1, 2, 0);
            launch_multi(&d0, 1);
        }
        seg_gather_layer_bf<<<r4, 256, 0, stream>>>(btmp, bh1, brel, ssrc_g, sety_g, rs_g, iv_g);
        {
            GemmDesc d0 = desc(bseg2(btmp, H_DIM, bWn_t + 40000, H_DIM, H_DIM,
                                     bh1,  H_DIM, bWs_t + 40000, H_DIM, H_DIM),
                               nullptr, bh0, nullptr, NUM_E, H_DIM, H_DIM, 1, 2, 0);
            launch_multi(&d0, 1);
        }
        l2norm_bf4<<<r4, 256, 0, stream>>>(bh0, NUM_E);

        // Merged GRU GEMMs: rz (sigmoid, N=400), iN (h1), hN (tmp) — independent,
        // one launch (~4700 blocks at 64x64) for full-device occupancy.
        {
            GemmDesc d3[3];
            d3[0] = desc(bseg3(bh0,   H_DIM,  bW_ih,       248, H_DIM,
                               bte_g, TD_DIM, bW_ih + 200, 248, TD_DIM,
                               bprev, H_DIM,  bW_hh,       200, H_DIM),
                         rz, nullptr, bsum, NUM_E, 400, 400, 2, 1, 0);
            d3[1] = desc(bseg2(bh0,   H_DIM,  bW_ih + 400*248,       248, H_DIM,
                               bte_g, TD_DIM, bW_ih + 400*248 + 200, 248, TD_DIM),
                         h1, nullptr, b_ih + 400, NUM_E, H_DIM, H_DIM, 0, 1, 0);
            d3[2] = desc(bseg1(bprev, H_DIM, bW_hh + 400*200, 200, H_DIM),
                         tmp, nullptr, b_hh + 400, NUM_E, H_DIM, H_DIM, 0, 1, 0);
            launch_multi(d3, 3);
        }

        gru_fused<<<r4, 256, 0, stream>>>(prev, bprev, rz, h1, tmp);
    }

    // ---- batch head ----
    gather_qs_qr3<<<nblk((long)BATCH * H_DIM), 256, 0, stream>>>(qs3, qr3, prev, reln, data);
    semb_kernel<<<dim3(BATCH, 3), 64, 0, stream>>>(semb, prev, his_idx, his_len);
    tenc_batch<<<nblk(3L * BATCH * TD_DIM), 256, 0, stream>>>(teb, his_len, af, ap, cf, cp);

    // abuf = relu([qs|qr|semb|teb] @ Wb_w^T + Wb_b)   -- split-K, partials in h1
    {
        const int KS = 8;
        const int MN = 3 * BATCH * H_DIM;
        splitk(h1, seg4(qs3, H_DIM,  Wb_w,       648, H_DIM,
                        qr3, H_DIM,  Wb_w + 200, 648, H_DIM,
                        semb, H_DIM, Wb_w + 400, 648, H_DIM,
                        teb, TD_DIM, Wb_w + 600, 648, TD_DIM),
               3 * BATCH, H_DIM, KS);
        reduce_relu<<<nblk(MN), 256, 0, stream>>>(abuf, h1, Wb_b, MN, H_DIM, KS);
    }
    att_logits_rows<<<(3 * BATCH + 3) / 4, 256, 0, stream>>>(atts, abuf, Wc_w, Wc_b);
    softmax_out2<<<nblk((long)BATCH * H_DIM), 256, 0, stream>>>(out2, atts, semb);

    // qbuf = relu([qs|qr|out2] @ Wd_w^T + Wd_b) -> hi/lo bf16 split (partials in tmp)
    {
        const int KS = 8;
        const int MN = BATCH * H_DIM;
        splitk(tmp, seg3(qs3, H_DIM,  Wd_w,       600, H_DIM,
                         qr3, H_DIM,  Wd_w + 200, 600, H_DIM,
                         out2, H_DIM, Wd_w + 400, 600, H_DIM),
               BATCH, H_DIM, KS);
        reduce_relu_split<<<nblk(MN), 256, 0, stream>>>(qhi, qlo, tmp, Wd_b, MN, H_DIM, KS);
    }

    // plo = bf16(prev - f32(bprev))  (bprev is the hi part)
    make_lo<<<nblk(nE200), 256, 0, stream>>>(plo, prev, bprev, nE200);

    // result = q @ prev^T via hi/lo-compensated bf16 MFMA:
    //   qhi@phi + qhi@plo + qlo@phi   (3 K-segments, Ktot=600), B-reuse tile order
    {
        GemmDesc d0 = desc(bseg3(qhi, H_DIM, bprev, H_DIM, H_DIM,
                                 qhi, H_DIM, plo,   H_DIM, H_DIM,
                                 qlo, H_DIM, bprev, H_DIM, H_DIM),
                           out_p, nullptr, nullptr, BATCH, NUM_E, NUM_E, 0, 1, 1);
        launch_multi(&d0, 1);
    }
}

// Round 13
// 1083.813 us; speedup vs baseline: 1.4053x; 1.0087x over previous
//
#include <hip/hip_runtime.h>
#include <hip/hip_bf16.h>

#define NUM_E   20000
#define H_DIM   200
#define TD_DIM  48
#define HD_DIM  24
#define L_HIST  32
#define N_HIST  3
#define E_EDGES 200000
#define BATCH   512

// ---------------------------------------------------------------- utilities

__device__ inline float wave_sum64(float x) {
    #pragma unroll
    for (int m = 1; m < 64; m <<= 1) x += __shfl_xor(x, m);
    return x;
}

__device__ inline ushort f2bf(float f) {
    unsigned u = __float_as_uint(f);
    u += 0x7fffu + ((u >> 16) & 1u);
    return (ushort)(u >> 16);
}
__device__ inline float bf2f(ushort u) {
    return __uint_as_float(((unsigned)u) << 16);
}
__device__ inline float4 bf4_to_f4(ushort4 v) {
    return (float4){bf2f(v.x), bf2f(v.y), bf2f(v.z), bf2f(v.w)};
}

__global__ void fill_i32(int* __restrict__ p, long n, int v) {
    long i = (long)blockIdx.x * blockDim.x + threadIdx.x;
    if (i < n) p[i] = v;
}

__global__ void bias_sum(float* __restrict__ bsum, const float* __restrict__ b_ih,
                         const float* __restrict__ b_hh) {
    int j = blockIdx.x * 256 + threadIdx.x;
    if (j < 600) bsum[j] = b_ih[j] + b_hh[j];
}

__global__ void cvt_bf16_k(ushort* __restrict__ o, const float* __restrict__ in, long n) {
    long i = (long)blockIdx.x * 256 + threadIdx.x;
    if (i < n) o[i] = f2bf(in[i]);
}

// lo[i] = bf16(x[i] - f32(hi[i]))
__global__ void make_lo(ushort* __restrict__ lo, const float* __restrict__ x,
                        const ushort* __restrict__ hi, long n) {
    long i = (long)blockIdx.x * 256 + threadIdx.x;
    if (i < n) lo[i] = f2bf(x[i] - bf2f(hi[i]));
}

// in (R,C) row-major f32 -> o (C,R) row-major bf16
__global__ void tcvt_bf16_k(ushort* __restrict__ o, const float* __restrict__ in, int R, int C) {
    int i = blockIdx.x * 256 + threadIdx.x;
    if (i >= R * C) return;
    int r = i / C, c = i - r * C;
    o[(size_t)c * R + r] = f2bf(in[i]);
}

// ---------------------------------------------------------------- f32 split-K GEMM (B^T)
struct Segs {
    const float* A[4];
    const float* B[4];
    int lda[4], ldb[4], Ks[4];
    int nseg, Ktot;
};

__device__ inline void seg_find(const Segs& sg, int gk, int& s, int& loc) {
    s = 0; loc = gk;
    #pragma unroll
    for (int t = 0; t < 3; t++) {
        if (s + 1 < sg.nseg && loc >= sg.Ks[s]) { loc -= sg.Ks[s]; s++; }
    }
}

// Partial GEMM: P[kc][M][N] = A@B^T over k-chunk kc. BM=64, BN=64, BK=32.
__global__ __launch_bounds__(256) void sgemm_splitk(
    float* __restrict__ P, const Segs sg, int M, int N, int nbx, int nby,
    int KS, int tpc)
{
    __shared__ float As[32][68];
    __shared__ float Bs[32][68];

    int tot = nbx * nby;
    int tot_all = tot * KS;
    int chunk = (tot_all + 7) >> 3;
    int v = (int)(blockIdx.x & 7) * chunk + (int)(blockIdx.x >> 3);
    if (v >= tot_all) return;
    int kc = v / tot;
    int tile = v - kc * tot;
    int by = tile / nbx, bx = tile - by * nbx;
    const int bn = bx * 64;
    const int bm = by * 64;
    const int tid = threadIdx.x;
    const int m0 = (tid >> 4) * 4;
    const int n0 = (tid & 15) * 4;

    float acc[4][4];
    #pragma unroll
    for (int i = 0; i < 4; i++)
        #pragma unroll
        for (int j = 0; j < 4; j++) acc[i][j] = 0.f;

    const int Ktot = sg.Ktot;
    const int ntile = (Ktot + 31) / 32;
    const int kt0 = kc * tpc;
    const int kt1 = min(ntile, kt0 + tpc);

    const int a_m  = tid & 31;
    const int a_k4 = (tid >> 5) * 4;
    const int b1_n = tid & 63;
    const int b1_k = (tid >> 6) * 4;

    float4 ra[2], rb[2];
    auto loadA = [&](int k0) {
        int gk = k0 + a_k4;
        bool kin = gk < Ktot;
        int s = 0, loc = 0;
        if (kin) seg_find(sg, gk, s, loc);
        const float* Ab = sg.A[s];
        const int lda = sg.lda[s];
        #pragma unroll
        for (int r = 0; r < 2; r++) {
            int row = bm + a_m + 32 * r;
            float4 vv = {0.f, 0.f, 0.f, 0.f};
            if (kin && row < M) vv = *(const float4*)(Ab + (size_t)row * lda + loc);
            ra[r] = vv;
        }
    };
    auto loadB = [&](int k0) {
        #pragma unroll
        for (int r = 0; r < 2; r++) {
            int k4 = b1_k + 16 * r;
            int gk = k0 + k4;
            bool kin = gk < Ktot;
            int s = 0, loc = 0;
            if (kin) seg_find(sg, gk, s, loc);
            const float* Bb = sg.B[s];
            const int ldb = sg.ldb[s];
            int gn = bn + b1_n;
            float4 vv = {0.f, 0.f, 0.f, 0.f};
            if (kin && gn < N) vv = *(const float4*)(Bb + (size_t)gn * ldb + loc);
            rb[r] = vv;
        }
    };

    if (kt0 < kt1) {
        loadA(kt0 * 32); loadB(kt0 * 32);
        for (int t = kt0; t < kt1; t++) {
            #pragma unroll
            for (int r = 0; r < 2; r++) {
                int m = a_m + 32 * r;
                As[a_k4 + 0][m] = ra[r].x;
                As[a_k4 + 1][m] = ra[r].y;
                As[a_k4 + 2][m] = ra[r].z;
                As[a_k4 + 3][m] = ra[r].w;
            }
            #pragma unroll
            for (int r = 0; r < 2; r++) {
                int k4 = b1_k + 16 * r;
                Bs[k4 + 0][b1_n] = rb[r].x;
                Bs[k4 + 1][b1_n] = rb[r].y;
                Bs[k4 + 2][b1_n] = rb[r].z;
                Bs[k4 + 3][b1_n] = rb[r].w;
            }
            __syncthreads();
            if (t + 1 < kt1) { loadA((t + 1) * 32); loadB((t + 1) * 32); }
            #pragma unroll 8
            for (int kk = 0; kk < 32; kk++) {
                float4 b = *(float4*)&Bs[kk][n0];
                float4 av = *(float4*)&As[kk][m0];
                float a[4] = {av.x, av.y, av.z, av.w};
                #pragma unroll
                for (int i = 0; i < 4; i++) {
                    acc[i][0] += a[i] * b.x;
                    acc[i][1] += a[i] * b.y;
                    acc[i][2] += a[i] * b.z;
                    acc[i][3] += a[i] * b.w;
                }
            }
            __syncthreads();
        }
    }

    int col = bn + n0;
    if (col < N) {
        #pragma unroll
        for (int i = 0; i < 4; i++) {
            int row = bm + m0 + i;
            if (row < M) {
                float4 o = {acc[i][0], acc[i][1], acc[i][2], acc[i][3]};
                *(float4*)(P + ((size_t)kc * M + row) * N + col) = o;
            }
        }
    }
}

// out = relu(sum_kc P + bias)
__global__ void reduce_relu(float* __restrict__ out, const float* __restrict__ P,
                            const float* __restrict__ bias, int MN, int N, int KS)
{
    int i = blockIdx.x * 256 + threadIdx.x;
    if (i >= MN) return;
    float s = bias[i % N];
    for (int k = 0; k < KS; k++) s += P[(size_t)k * MN + i];
    out[i] = fmaxf(s, 0.f);
}

// qhi/qlo = hi/lo bf16 split of relu(sum_kc P + bias)
__global__ void reduce_relu_split(ushort* __restrict__ qhi, ushort* __restrict__ qlo,
                                  const float* __restrict__ P, const float* __restrict__ bias,
                                  int MN, int N, int KS)
{
    int i = blockIdx.x * 256 + threadIdx.x;
    if (i >= MN) return;
    float s = bias[i % N];
    for (int k = 0; k < KS; k++) s += P[(size_t)k * MN + i];
    s = fmaxf(s, 0.f);
    ushort h = f2bf(s);
    qhi[i] = h;
    qlo[i] = f2bf(s - bf2f(h));
}

// ---------------------------------------------------------------- bf16 MFMA multi-GEMM
typedef __attribute__((ext_vector_type(8))) short bfrag;
typedef __attribute__((ext_vector_type(4))) float ffrag;

struct BfSegs {
    const ushort* A[3];
    const ushort* B[3];
    int lda[3], ldb[3], Ks[3];
    int nseg, Ktot;
};

__device__ inline void bseg_find(const BfSegs& sg, int gk, int& s, int& loc) {
    s = 0; loc = gk;
    #pragma unroll
    for (int t = 0; t < 2; t++) {
        if (s + 1 < sg.nseg && loc >= sg.Ks[s]) { loc -= sg.Ks[s]; s++; }
    }
}

// One GEMM description. Tile is 64x64 (4 waves, each 32x32).
// act: 0 none, 1 relu, 2 sigmoid.  flags: 1 = write f32 C, 2 = write bf16 Cb.
// order: 0 = row-major tiles (A-reuse), 1 = col-major tiles (B-reuse, XCD-contig).
struct GemmDesc {
    BfSegs sg;
    float* C;
    ushort* Cb;
    const float* bias;
    int M, N, ldc;
    int act, flags, order;
    int nbx, nby, blk0, nblk;
};

struct MultiArgs {
    GemmDesc d[3];
    int nd;
    int tot;
};

template<int DI>
__device__ __forceinline__ void gemm_body(const MultiArgs& ma, int v,
                                          ushort* __restrict__ Als,
                                          ushort* __restrict__ Bls)
{
    const GemmDesc& D = ma.d[DI];
    const BfSegs& sg = D.sg;
    const int tile = v - D.blk0;
    int by, bx;
    if (D.order == 0) { by = tile / D.nbx; bx = tile - by * D.nbx; }
    else              { bx = tile / D.nby; by = tile - bx * D.nby; }
    const int bm = by * 64, bn = bx * 64;
    const int M = D.M, N = D.N;

    const int tid  = threadIdx.x;
    const int lane = tid & 63;
    const int w    = tid >> 6;
    const int wm   = (w & 1) * 2;
    const int wn   = (w >> 1) * 2;

    ffrag acc[2][2];
    #pragma unroll
    for (int i = 0; i < 2; i++)
        #pragma unroll
        for (int j = 0; j < 2; j++) acc[i][j] = (ffrag){0.f, 0.f, 0.f, 0.f};

    const int Ktot = sg.Ktot;
    const int nkt = (Ktot + 63) >> 6;

    int a_m[2], a_kq[2], a_wc[2];
    #pragma unroll
    for (int i = 0; i < 2; i++) {
        int c = i * 256 + tid;
        a_m[i] = c & 63; a_kq[i] = c >> 6;
        a_wc[i] = ((a_m[i] >> 4) * 2 + (a_kq[i] >> 2)) * 64 + (a_kq[i] & 3) * 16 + (a_m[i] & 15);
    }
    int b_n[2], b_kq[2], b_wc[2];
    #pragma unroll
    for (int i = 0; i < 2; i++) {
        int c = i * 256 + tid;
        b_n[i] = c & 63; b_kq[i] = c >> 6;
        b_wc[i] = ((b_n[i] >> 4) * 2 + (b_kq[i] >> 2)) * 64 + (b_kq[i] & 3) * 16 + (b_n[i] & 15);
    }

    uint4 ra[2], rb[2];
    auto loadA = [&](int k0) {
        #pragma unroll
        for (int i = 0; i < 2; i++) {
            int gk = k0 + a_kq[i] * 8;
            int row = bm + a_m[i];
            uint4 vv = {0u, 0u, 0u, 0u};
            if (gk < Ktot && row < M) {
                int s, loc; bseg_find(sg, gk, s, loc);
                vv = *(const uint4*)(sg.A[s] + (size_t)row * sg.lda[s] + loc);
            }
            ra[i] = vv;
        }
    };
    auto loadB = [&](int k0) {
        #pragma unroll
        for (int i = 0; i < 2; i++) {
            int gk = k0 + b_kq[i] * 8;
            int gn = bn + b_n[i];
            uint4 vv = {0u, 0u, 0u, 0u};
            if (gk < Ktot && gn < N) {
                int s, loc; bseg_find(sg, gk, s, loc);
                vv = *(const uint4*)(sg.B[s] + (size_t)gn * sg.ldb[s] + loc);
            }
            rb[i] = vv;
        }
    };

    loadA(0); loadB(0);

    for (int t = 0; t < nkt; t++) {
        #pragma unroll
        for (int i = 0; i < 2; i++) *(uint4*)(&Als[a_wc[i] * 8]) = ra[i];
        #pragma unroll
        for (int i = 0; i < 2; i++) *(uint4*)(&Bls[b_wc[i] * 8]) = rb[i];
        __syncthreads();

        if (t + 1 < nkt) { loadA((t + 1) << 6); loadB((t + 1) << 6); }

        #pragma unroll
        for (int kt = 0; kt < 2; kt++) {
            bfrag af[2], bf[2];
            #pragma unroll
            for (int i = 0; i < 2; i++)
                af[i] = *(const bfrag*)(&Als[(((wm + i) * 2 + kt) * 64 + lane) * 8]);
            #pragma unroll
            for (int j = 0; j < 2; j++)
                bf[j] = *(const bfrag*)(&Bls[(((wn + j) * 2 + kt) * 64 + lane) * 8]);
            #pragma unroll
            for (int i = 0; i < 2; i++)
                #pragma unroll
                for (int j = 0; j < 2; j++)
                    acc[i][j] = __builtin_amdgcn_mfma_f32_16x16x32_bf16(af[i], bf[j], acc[i][j], 0, 0, 0);
        }
        __syncthreads();
    }

    const int rbase = (lane >> 4) * 4;
    const int cl = lane & 15;
    #pragma unroll
    for (int j = 0; j < 2; j++) {
        int col = bn + (wn + j) * 16 + cl;
        if (col >= N) continue;
        float bv = D.bias ? D.bias[col] : 0.f;
        #pragma unroll
        for (int i = 0; i < 2; i++) {
            int mrow = bm + (wm + i) * 16 + rbase;
            #pragma unroll
            for (int r = 0; r < 4; r++) {
                int row = mrow + r;
                if (row < M) {
                    float o = acc[i][j][r] + bv;
                    if (D.act == 1) o = fmaxf(o, 0.f);
                    else if (D.act == 2) o = 1.f / (1.f + expf(-o));
                    if (D.flags & 1) D.C[(size_t)row * D.ldc + col] = o;
                    if (D.flags & 2) D.Cb[(size_t)row * D.ldc + col] = f2bf(o);
                }
            }
        }
    }
}

__global__ __launch_bounds__(256) void mfma_multi(MultiArgs ma)
{
    __shared__ __align__(16) ushort Als[4096];
    __shared__ __align__(16) ushort Bls[4096];

    int tot = ma.tot;
    int chunk = (tot + 7) >> 3;
    int v = (int)(blockIdx.x & 7) * chunk + (int)(blockIdx.x >> 3);
    if (v >= tot) return;

    int di = 0;
    if (ma.nd > 1 && v >= ma.d[1].blk0) di = 1;
    if (ma.nd > 2 && v >= ma.d[2].blk0) di = 2;

    if (di == 0)      gemm_body<0>(ma, v, Als, Bls);
    else if (di == 1) gemm_body<1>(ma, v, Als, Bls);
    else              gemm_body<2>(ma, v, Als, Bls);
}

// ---------------------------------------------------------------- CSR build (all 3 graphs, hoisted)

// count over all 3 graphs: cnt[g*NUM_E + d]
__global__ void count_dst3(const int* __restrict__ dst, int* __restrict__ cnt) {
    long e = (long)blockIdx.x * 256 + threadIdx.x;
    if (e < (long)N_HIST * E_EDGES) {
        int g = (int)(e / E_EDGES);
        atomicAdd(&cnt[g * NUM_E + dst[e]], 1);
    }
}

// one block per graph (3 concurrent scans)
__global__ __launch_bounds__(1024) void scan_rows3(
    const int* __restrict__ cnt_all, int* __restrict__ row_start_all,
    int* __restrict__ cursor_all, float* __restrict__ degf_all,
    float* __restrict__ invd_all)
{
    __shared__ int part[1024];
    const int g = blockIdx.x;
    const int* cnt = cnt_all + g * NUM_E;
    int* row_start  = row_start_all + g * (NUM_E + 4);
    int* cursor     = cursor_all + g * NUM_E;
    float* degf     = degf_all + g * NUM_E;
    float* invd     = invd_all + g * NUM_E;

    const int CH = (NUM_E + 1023) / 1024;
    int t = threadIdx.x;
    int base = t * CH;
    int local[32];
    int s = 0;
    for (int j = 0; j < CH; j++) {
        int idx = base + j;
        int c = (idx < NUM_E) ? cnt[idx] : 0;
        local[j] = s; s += c;
    }
    part[t] = s;
    __syncthreads();
    for (int off = 1; off < 1024; off <<= 1) {
        int vv = (t >= off) ? part[t - off] : 0;
        __syncthreads();
        part[t] += vv;
        __syncthreads();
    }
    int pre = (t == 0) ? 0 : part[t - 1];
    for (int j = 0; j < CH; j++) {
        int idx = base + j;
        if (idx < NUM_E) {
            int rs = pre + local[j];
            row_start[idx] = rs;
            cursor[idx] = rs;
            int c = cnt[idx];
            degf[idx] = (float)c;
            invd[idx] = 1.f / fmaxf((float)c, 1.f);
        }
    }
    if (t == 1023) row_start[NUM_E] = part[1023];
}

__global__ void build_perm3(const int* __restrict__ src, const int* __restrict__ dst,
                            const int* __restrict__ etype, int* __restrict__ cursor_all,
                            int* __restrict__ ssrc_all, int* __restrict__ setype_all)
{
    long e = (long)blockIdx.x * 256 + threadIdx.x;
    if (e >= (long)N_HIST * E_EDGES) return;
    int g = (int)(e / E_EDGES);
    int pos = atomicAdd(&cursor_all[g * NUM_E + dst[e]], 1);
    ssrc_all[(long)g * E_EDGES + pos]   = src[e];
    setype_all[(long)g * E_EDGES + pos] = etype[e];
}

// ---------------------------------------------------------------- gathers (bf16 in/out)

__global__ __launch_bounds__(256) void seg_gather_norm_bf(
    ushort* __restrict__ bh, const ushort* __restrict__ bprev,
    const int* __restrict__ ssrc, const int* __restrict__ row_start,
    const float* __restrict__ invd)
{
    int v = blockIdx.x * 4 + (threadIdx.x >> 6);
    int lane = threadIdx.x & 63;
    if (v >= NUM_E) return;
    int s0 = row_start[v], s1 = row_start[v + 1];
    bool act = lane < 50;
    float4 acc = {0.f, 0.f, 0.f, 0.f};
    int j = s0;
    for (; j + 1 < s1; j += 2) {
        int sa = ssrc[j], sb = ssrc[j + 1];
        if (act) {
            float4 xa = bf4_to_f4(*(const ushort4*)(bprev + (long)sa * H_DIM + lane * 4));
            float4 xb = bf4_to_f4(*(const ushort4*)(bprev + (long)sb * H_DIM + lane * 4));
            acc.x += xa.x + xb.x; acc.y += xa.y + xb.y;
            acc.z += xa.z + xb.z; acc.w += xa.w + xb.w;
        }
    }
    if (j < s1) {
        int sa = ssrc[j];
        if (act) {
            float4 xa = bf4_to_f4(*(const ushort4*)(bprev + (long)sa * H_DIM + lane * 4));
            acc.x += xa.x; acc.y += xa.y; acc.z += xa.z; acc.w += xa.w;
        }
    }
    float iv = invd[v];
    acc.x *= iv; acc.y *= iv; acc.z *= iv; acc.w *= iv;
    float ss = act ? (acc.x*acc.x + acc.y*acc.y + acc.z*acc.z + acc.w*acc.w) : 0.f;
    ss = wave_sum64(ss);
    float r = 1.f / fmaxf(sqrtf(ss), 1e-12f);
    if (act) {
        ushort4 ob = {f2bf(acc.x * r), f2bf(acc.y * r), f2bf(acc.z * r), f2bf(acc.w * r)};
        *(ushort4*)(bh + (long)v * H_DIM + lane * 4) = ob;
    }
}

__global__ __launch_bounds__(256) void seg_gather_layer_bf(
    ushort* __restrict__ btmp, const ushort* __restrict__ bh, const ushort* __restrict__ brel,
    const int* __restrict__ ssrc, const int* __restrict__ setype,
    const int* __restrict__ row_start, const float* __restrict__ invd)
{
    int v = blockIdx.x * 4 + (threadIdx.x >> 6);
    int lane = threadIdx.x & 63;
    if (v >= NUM_E) return;
    int s0 = row_start[v], s1 = row_start[v + 1];
    bool act = lane < 50;
    float4 acc = {0.f, 0.f, 0.f, 0.f};
    int j = s0;
    for (; j + 1 < s1; j += 2) {
        int sa = ssrc[j], ta = setype[j];
        int sb = ssrc[j + 1], tb = setype[j + 1];
        if (act) {
            float4 xa = bf4_to_f4(*(const ushort4*)(bh   + (long)sa * H_DIM + lane * 4));
            float4 ya = bf4_to_f4(*(const ushort4*)(brel + (long)ta * H_DIM + lane * 4));
            float4 xb = bf4_to_f4(*(const ushort4*)(bh   + (long)sb * H_DIM + lane * 4));
            float4 yb = bf4_to_f4(*(const ushort4*)(brel + (long)tb * H_DIM + lane * 4));
            acc.x += (xa.x + ya.x) + (xb.x + yb.x);
            acc.y += (xa.y + ya.y) + (xb.y + yb.y);
            acc.z += (xa.z + ya.z) + (xb.z + yb.z);
            acc.w += (xa.w + ya.w) + (xb.w + yb.w);
        }
    }
    if (j < s1) {
        int s = ssrc[j];
        int t = setype[j];
        if (act) {
            float4 x = bf4_to_f4(*(const ushort4*)(bh   + (long)s * H_DIM + lane * 4));
            float4 y = bf4_to_f4(*(const ushort4*)(brel + (long)t * H_DIM + lane * 4));
            acc.x += x.x + y.x; acc.y += x.y + y.y;
            acc.z += x.z + y.z; acc.w += x.w + y.w;
        }
    }
    float iv = invd[v];
    if (act) {
        ushort4 ob = {f2bf(acc.x * iv), f2bf(acc.y * iv), f2bf(acc.z * iv), f2bf(acc.w * iv)};
        *(ushort4*)(btmp + (long)v * H_DIM + lane * 4) = ob;
    }
}

// ---------------------------------------------------------------- row kernels

__global__ __launch_bounds__(256) void l2norm_rows4(
    float* __restrict__ out, ushort* __restrict__ bout,
    const float* __restrict__ in, int nrows)
{
    int v = blockIdx.x * 4 + (threadIdx.x >> 6);
    int lane = threadIdx.x & 63;
    if (v >= nrows) return;
    bool act = lane < 50;
    float4 x = {0.f, 0.f, 0.f, 0.f};
    if (act) x = *(const float4*)(in + (long)v * H_DIM + lane * 4);
    float ss = x.x*x.x + x.y*x.y + x.z*x.z + x.w*x.w;
    ss = wave_sum64(ss);
    float r = 1.f / fmaxf(sqrtf(ss), 1e-12f);
    if (act) {
        long base = (long)v * H_DIM + lane * 4;
        float4 o = {x.x * r, x.y * r, x.z * r, x.w * r};
        *(float4*)(out + base) = o;
        if (bout) {
            ushort4 ob = {f2bf(o.x), f2bf(o.y), f2bf(o.z), f2bf(o.w)};
            *(ushort4*)(bout + base) = ob;
        }
    }
}

__global__ __launch_bounds__(256) void l2norm_bf4(ushort* __restrict__ b, int nrows)
{
    int v = blockIdx.x * 4 + (threadIdx.x >> 6);
    int lane = threadIdx.x & 63;
    if (v >= nrows) return;
    bool act = lane < 50;
    float4 x = {0.f, 0.f, 0.f, 0.f};
    long base = (long)v * H_DIM + lane * 4;
    if (act) x = bf4_to_f4(*(const ushort4*)(b + base));
    float ss = x.x*x.x + x.y*x.y + x.z*x.z + x.w*x.w;
    ss = wave_sum64(ss);
    float r = 1.f / fmaxf(sqrtf(ss), 1e-12f);
    if (act) {
        ushort4 ob = {f2bf(x.x * r), f2bf(x.y * r), f2bf(x.z * r), f2bf(x.w * r)};
        *(ushort4*)(b + base) = ob;
    }
}

// 3 graphs x 2 rows x 48 bf16 time-encoding table (row stride 64)
__global__ void tenc_table3(ushort* __restrict__ tbl, const float* __restrict__ af,
                            const float* __restrict__ ap, const float* __restrict__ cf,
                            const float* __restrict__ cp)
{
    int j = blockIdx.x * 256 + threadIdx.x;
    if (j >= 384) return;
    int g = j >> 7;
    int r = j & 127;
    int half = r >> 6;
    int jj = r & 63;
    if (jj >= TD_DIM) return;
    float tcnt = (float)(N_HIST - 1 - g);
    float t = half ? 100.0f : tcnt;
    float val;
    if (jj < HD_DIM) val = tanhf((t + 1.f) * af[jj] + ap[jj]);
    else             val = cosf(t * cf[jj - HD_DIM] + cp[jj - HD_DIM]);
    tbl[g * 128 + half * 64 + jj] = f2bf(val);
}

// bte3[g][v][:] = tbl[g][deg>0 ? 0 : 1][:]  (uint4 copies)
__global__ void tenc_fill3(ushort* __restrict__ bte3, const float* __restrict__ degf_all,
                           const ushort* __restrict__ tbl)
{
    long idx = (long)blockIdx.x * 256 + threadIdx.x;
    if (idx >= (long)N_HIST * NUM_E * 6) return;
    int g = (int)(idx / (NUM_E * 6));
    int rem = (int)(idx - (long)g * NUM_E * 6);
    int v = rem / 6, c = rem - v * 6;
    int base = (degf_all[g * NUM_E + v] > 0.f) ? 0 : 64;
    *(uint4*)(bte3 + ((long)g * NUM_E + v) * TD_DIM + c * 8) =
        *(const uint4*)(tbl + g * 128 + base + c * 8);
}

// GRU update; gate/candidate inputs are bf16 (rz: NUM_E x 400, iN/hN: NUM_E x 200)
__global__ __launch_bounds__(256) void gru_fused(
    float* __restrict__ prev, ushort* __restrict__ bprev, const ushort* __restrict__ brz,
    const ushort* __restrict__ iN, const ushort* __restrict__ hN)
{
    int v = blockIdx.x * 4 + (threadIdx.x >> 6);
    int lane = threadIdx.x & 63;
    if (v >= NUM_E) return;
    bool act = lane < 50;
    long b200 = (long)v * H_DIM + lane * 4;
    long b400 = (long)v * 400 + lane * 4;
    float4 o = {0.f, 0.f, 0.f, 0.f};
    if (act) {
        float4 r4 = bf4_to_f4(*(const ushort4*)(brz + b400));
        float4 z4 = bf4_to_f4(*(const ushort4*)(brz + b400 + 200));
        float4 n4 = bf4_to_f4(*(const ushort4*)(iN + b200));
        float4 g4 = bf4_to_f4(*(const ushort4*)(hN + b200));
        float4 p4 = *(const float4*)(prev + b200);
        float ngx = tanhf(n4.x + r4.x * g4.x);
        float ngy = tanhf(n4.y + r4.y * g4.y);
        float ngz = tanhf(n4.z + r4.z * g4.z);
        float ngw = tanhf(n4.w + r4.w * g4.w);
        o.x = (1.f - z4.x) * ngx + z4.x * p4.x;
        o.y = (1.f - z4.y) * ngy + z4.y * p4.y;
        o.z = (1.f - z4.z) * ngz + z4.z * p4.z;
        o.w = (1.f - z4.w) * ngw + z4.w * p4.w;
    }
    float ss = o.x*o.x + o.y*o.y + o.z*o.z + o.w*o.w;
    ss = wave_sum64(ss);
    float r = 1.f / fmaxf(sqrtf(ss), 1e-12f);
    if (act) {
        float4 wv = {o.x * r, o.y * r, o.z * r, o.w * r};
        *(float4*)(prev + b200) = wv;
        ushort4 ob = {f2bf(wv.x), f2bf(wv.y), f2bf(wv.z), f2bf(wv.w)};
        *(ushort4*)(bprev + b200) = ob;
    }
}

// ---------------------------------------------------------------- batch head

__global__ void gather_qs_qr3(float* __restrict__ qs3, float* __restrict__ qr3,
                              const float* __restrict__ out, const float* __restrict__ reln,
                              const int* __restrict__ data)
{
    long i = (long)blockIdx.x * 256 + threadIdx.x;
    if (i >= (long)BATCH * H_DIM) return;
    int b = (int)(i / H_DIM), j = (int)(i % H_DIM);
    float vs = out[(long)data[b * 4 + 0] * H_DIM + j];
    float vr = reln[(long)data[b * 4 + 1] * H_DIM + j];
    const long S = (long)BATCH * H_DIM;
    qs3[i] = vs; qs3[i + S] = vs; qs3[i + 2*S] = vs;
    qr3[i] = vr; qr3[i + S] = vr; qr3[i + 2*S] = vr;
}

__global__ __launch_bounds__(64) void semb_kernel(
    float* __restrict__ semb, const float* __restrict__ out,
    const int* __restrict__ his_idx, const int* __restrict__ his_len)
{
    int b = blockIdx.x, k = blockIdx.y;
    int lane = threadIdx.x;
    int ln = his_len[b * 3 + k];
    if (ln > L_HIST) ln = L_HIST;
    float vals[4] = {0.f, 0.f, 0.f, 0.f};
    for (int l = 0; l < ln; l++) {
        int idx = his_idx[((long)b * 3 + k) * L_HIST + l];
        #pragma unroll
        for (int t = 0; t < 4; t++) {
            int j = lane + t * 64;
            if (j < H_DIM) vals[t] += out[(long)idx * H_DIM + j];
        }
    }
    float scale = 1.f / fmaxf((float)ln, 1.f);
    float ss = 0.f;
    #pragma unroll
    for (int t = 0; t < 4; t++) { vals[t] *= scale; ss += vals[t] * vals[t]; }
    ss = wave_sum64(ss);
    float r = 1.f / fmaxf(sqrtf(ss), 1e-12f);
    #pragma unroll
    for (int t = 0; t < 4; t++) {
        int j = lane + t * 64;
        if (j < H_DIM) semb[((long)k * BATCH + b) * H_DIM + j] = vals[t] * r;
    }
}

__global__ void tenc_batch(float* __restrict__ teb, const int* __restrict__ his_len,
                           const float* __restrict__ af, const float* __restrict__ ap,
                           const float* __restrict__ cf, const float* __restrict__ cp)
{
    int idx = blockIdx.x * 256 + threadIdx.x;
    if (idx >= 3 * BATCH * TD_DIM) return;
    int k = idx / (BATCH * TD_DIM);
    int rem = idx - k * (BATCH * TD_DIM);
    int b = rem / TD_DIM, j = rem % TD_DIM;
    int ln = his_len[b * 3 + k];
    float t = (ln > 0) ? (float)(2 - k) : 100.0f;
    float val;
    if (j < HD_DIM) val = tanhf((t + 1.f) * af[j] + ap[j]);
    else            val = cosf(t * cf[j - HD_DIM] + cp[j - HD_DIM]);
    teb[idx] = val;
}

__global__ __launch_bounds__(256) void att_logits_rows(
    float* __restrict__ atts, const float* __restrict__ a,
    const float* __restrict__ Wc_w, const float* __restrict__ Wc_b)
{
    int row = blockIdx.x * 4 + (threadIdx.x >> 6);
    int lane = threadIdx.x & 63;
    if (row >= 3 * BATCH) return;
    int k = row >> 9;
    int b = row & 511;
    float s = 0.f;
    for (int j = lane; j < H_DIM; j += 64) s += a[(long)row * H_DIM + j] * Wc_w[j];
    s = wave_sum64(s);
    if (lane == 0) atts[b * 3 + k] = s + Wc_b[0];
}

__global__ void softmax_out2(float* __restrict__ out2, const float* __restrict__ atts,
                             const float* __restrict__ semb)
{
    long i = (long)blockIdx.x * 256 + threadIdx.x;
    if (i >= (long)BATCH * H_DIM) return;
    int b = (int)(i / H_DIM), j = (int)(i % H_DIM);
    float l0 = atts[b * 3 + 0], l1 = atts[b * 3 + 1], l2 = atts[b * 3 + 2];
    float m = fmaxf(l0, fmaxf(l1, l2));
    float e0 = expf(l0 - m), e1 = expf(l1 - m), e2 = expf(l2 - m);
    float s = e0 + e1 + e2;
    float v = (e0 * semb[((long)0 * BATCH + b) * H_DIM + j] +
               e1 * semb[((long)1 * BATCH + b) * H_DIM + j] +
               e2 * semb[((long)2 * BATCH + b) * H_DIM + j]) / s;
    out2[i] = v;
}

// ---------------------------------------------------------------- launch

extern "C" void kernel_launch(void* const* d_in, const int* in_sizes, int n_in,
                              void* d_out, int out_size, void* d_ws, size_t ws_size,
                              hipStream_t stream)
{
    (void)in_sizes; (void)n_in; (void)out_size; (void)ws_size;

    const int*   src     = (const int*)d_in[0];
    const int*   dst     = (const int*)d_in[1];
    const int*   etype   = (const int*)d_in[2];
    const int*   data    = (const int*)d_in[3];
    const int*   his_idx = (const int*)d_in[4];
    const int*   his_len = (const int*)d_in[5];
    const float* ent     = (const float*)d_in[6];
    const float* loop_w  = (const float*)d_in[7];
    const float* rel     = (const float*)d_in[8];
    const float* af      = (const float*)d_in[9];
    const float* ap      = (const float*)d_in[10];
    const float* cf      = (const float*)d_in[11];
    const float* cp      = (const float*)d_in[12];
    const float* Wn      = (const float*)d_in[13];
    const float* Ws      = (const float*)d_in[14];
    const float* W_ih    = (const float*)d_in[15];
    const float* W_hh    = (const float*)d_in[16];
    const float* b_ih    = (const float*)d_in[17];
    const float* b_hh    = (const float*)d_in[18];
    const float* Wb_w    = (const float*)d_in[19];
    const float* Wb_b    = (const float*)d_in[20];
    const float* Wc_w    = (const float*)d_in[21];
    const float* Wc_b    = (const float*)d_in[22];
    const float* Wd_w    = (const float*)d_in[23];
    const float* Wd_b    = (const float*)d_in[24];
    float* out_p = (float*)d_out;

    float* wp = (float*)d_ws;
    size_t off = 0;
    auto alloc = [&](size_t n) {
        size_t n4 = (n + 3) & ~(size_t)3;
        float* p = wp + off; off += n4; return p;
    };
    const long nE200 = (long)NUM_E * H_DIM;
    float* prev   = alloc(nE200);
    float* h1     = alloc(nE200);                       // batch head: split-K partials
    float* tmp    = alloc(nE200);                       // init gemm out; qbuf partials
    ushort* brz16 = (ushort*)out_p;                     // GRU gates bf16 (NUM_E x 400) in d_out scratch
    ushort* bh0   = (ushort*)alloc(nE200 / 2);
    ushort* bh1   = (ushort*)alloc(nE200 / 2);          // layer out; GRU iN bf16
    ushort* btmp  = (ushort*)alloc(nE200 / 2);          // gather out; GRU hN bf16
    ushort* bprev = (ushort*)alloc(nE200 / 2);
    ushort* plo   = (ushort*)alloc(nE200 / 2);
    ushort* bte3  = (ushort*)alloc((size_t)N_HIST * NUM_E * TD_DIM / 2);
    ushort* brel  = (ushort*)alloc(400 * H_DIM / 2);
    ushort* bW_ih = (ushort*)alloc(600 * 248 / 2);
    ushort* bW_hh = (ushort*)alloc(600 * 200 / 2);
    ushort* bWn_t = (ushort*)alloc(2 * 200 * 200 / 2);
    ushort* bWs_t = (ushort*)alloc(2 * 200 * 200 / 2);
    ushort* bLp_t = (ushort*)alloc(200 * 200 / 2);
    ushort* qhi   = (ushort*)alloc(BATCH * H_DIM / 2);
    ushort* qlo   = (ushort*)alloc(BATCH * H_DIM / 2);
    ushort* ttbl  = (ushort*)alloc(256);                // 3*128 ushorts
    float* degf   = alloc(3 * NUM_E);
    float* invd   = alloc(3 * NUM_E);
    float* reln   = alloc(400 * H_DIM);
    float* bsum   = alloc(1024);
    float* qs3    = alloc(3 * BATCH * H_DIM);
    float* qr3    = alloc(3 * BATCH * H_DIM);
    float* semb   = alloc(3 * BATCH * H_DIM);
    float* teb    = alloc(3 * BATCH * TD_DIM);
    float* abuf   = alloc(3 * BATCH * H_DIM);
    float* atts   = alloc(2048);
    float* out2   = alloc(BATCH * H_DIM);
    int* cnt       = (int*)alloc(3 * NUM_E);
    int* row_start = (int*)alloc(3 * (NUM_E + 4));
    int* cursor    = (int*)alloc(3 * NUM_E);
    int* ssrc      = (int*)alloc(3L * E_EDGES);
    int* setype    = (int*)alloc(3L * E_EDGES);

    auto nblk = [](long n) { return (unsigned)((n + 255) / 256); };

    auto bseg1 = [](const ushort* A, int la, const ushort* B, int lb, int K) {
        BfSegs s{}; s.A[0]=A; s.lda[0]=la; s.B[0]=B; s.ldb[0]=lb; s.Ks[0]=K;
        s.nseg=1; s.Ktot=K; return s;
    };
    auto bseg2 = [](const ushort* A0, int la0, const ushort* B0, int lb0, int K0,
                    const ushort* A1, int la1, const ushort* B1, int lb1, int K1) {
        BfSegs s{}; s.A[0]=A0; s.lda[0]=la0; s.B[0]=B0; s.ldb[0]=lb0; s.Ks[0]=K0;
        s.A[1]=A1; s.lda[1]=la1; s.B[1]=B1; s.ldb[1]=lb1; s.Ks[1]=K1;
        s.nseg=2; s.Ktot=K0+K1; return s;
    };
    auto bseg3 = [](const ushort* A0, int la0, const ushort* B0, int lb0, int K0,
                    const ushort* A1, int la1, const ushort* B1, int lb1, int K1,
                    const ushort* A2, int la2, const ushort* B2, int lb2, int K2) {
        BfSegs s{}; s.A[0]=A0; s.lda[0]=la0; s.B[0]=B0; s.ldb[0]=lb0; s.Ks[0]=K0;
        s.A[1]=A1; s.lda[1]=la1; s.B[1]=B1; s.ldb[1]=lb1; s.Ks[1]=K1;
        s.A[2]=A2; s.lda[2]=la2; s.B[2]=B2; s.ldb[2]=lb2; s.Ks[2]=K2;
        s.nseg=3; s.Ktot=K0+K1+K2; return s;
    };

    auto desc = [](const BfSegs& sg, float* C, ushort* Cb, const float* bias,
                   int M, int N, int ldc, int act, int flags, int order) {
        GemmDesc D{}; D.sg=sg; D.C=C; D.Cb=Cb; D.bias=bias;
        D.M=M; D.N=N; D.ldc=ldc; D.act=act; D.flags=flags; D.order=order;
        D.nbx=(N+63)>>6; D.nby=(M+63)>>6; D.nblk=D.nbx*D.nby; D.blk0=0;
        return D;
    };
    auto launch_multi = [&](GemmDesc* ds, int nd) {
        MultiArgs ma{};
        int tot = 0;
        for (int i = 0; i < nd; i++) { ds[i].blk0 = tot; tot += ds[i].nblk; ma.d[i] = ds[i]; }
        ma.nd = nd; ma.tot = tot;
        unsigned grid = (unsigned)(((tot + 7) >> 3) << 3);
        mfma_multi<<<grid, 256, 0, stream>>>(ma);
    };

    auto seg3 = [](const float* A0, int la0, const float* B0, int lb0, int K0,
                   const float* A1, int la1, const float* B1, int lb1, int K1,
                   const float* A2, int la2, const float* B2, int lb2, int K2) {
        Segs s{}; s.A[0]=A0; s.lda[0]=la0; s.B[0]=B0; s.ldb[0]=lb0; s.Ks[0]=K0;
        s.A[1]=A1; s.lda[1]=la1; s.B[1]=B1; s.ldb[1]=lb1; s.Ks[1]=K1;
        s.A[2]=A2; s.lda[2]=la2; s.B[2]=B2; s.ldb[2]=lb2; s.Ks[2]=K2;
        s.nseg=3; s.Ktot=K0+K1+K2; return s;
    };
    auto seg4 = [](const float* A0, int la0, const float* B0, int lb0, int K0,
                   const float* A1, int la1, const float* B1, int lb1, int K1,
                   const float* A2, int la2, const float* B2, int lb2, int K2,
                   const float* A3, int la3, const float* B3, int lb3, int K3) {
        Segs s{}; s.A[0]=A0; s.lda[0]=la0; s.B[0]=B0; s.ldb[0]=lb0; s.Ks[0]=K0;
        s.A[1]=A1; s.lda[1]=la1; s.B[1]=B1; s.ldb[1]=lb1; s.Ks[1]=K1;
        s.A[2]=A2; s.lda[2]=la2; s.B[2]=B2; s.ldb[2]=lb2; s.Ks[2]=K2;
        s.A[3]=A3; s.lda[3]=la3; s.B[3]=B3; s.ldb[3]=lb3; s.Ks[3]=K3;
        s.nseg=4; s.Ktot=K0+K1+K2+K3; return s;
    };
    // split-K partial gemm launcher
    auto splitk = [&](float* P, const Segs& sg, int M, int N, int KS) {
        int nbx = (N + 63) >> 6;
        int nby = (M + 63) >> 6;
        int ntile = (sg.Ktot + 31) / 32;
        int tpc = (ntile + KS - 1) / KS;
        int tot_all = nbx * nby * KS;
        unsigned grid = (unsigned)(((tot_all + 7) >> 3) << 3);
        sgemm_splitk<<<grid, 256, 0, stream>>>(P, sg, M, N, nbx, nby, KS, tpc);
    };

    const unsigned r4 = (NUM_E + 3) / 4;

    // ---- prelude ----
    l2norm_rows4<<<100, 256, 0, stream>>>(reln, brel, rel, 400);
    bias_sum<<<3, 256, 0, stream>>>(bsum, b_ih, b_hh);
    cvt_bf16_k<<<nblk(600L*248), 256, 0, stream>>>(bW_ih, W_ih, 600L*248);
    cvt_bf16_k<<<nblk(600L*200), 256, 0, stream>>>(bW_hh, W_hh, 600L*200);
    tcvt_bf16_k<<<nblk(40000), 256, 0, stream>>>(bLp_t, loop_w, 200, 200);
    tcvt_bf16_k<<<nblk(40000), 256, 0, stream>>>(bWn_t,          Wn,          200, 200);
    tcvt_bf16_k<<<nblk(40000), 256, 0, stream>>>(bWn_t + 40000,  Wn + 40000,  200, 200);
    tcvt_bf16_k<<<nblk(40000), 256, 0, stream>>>(bWs_t,          Ws,          200, 200);
    tcvt_bf16_k<<<nblk(40000), 256, 0, stream>>>(bWs_t + 40000,  Ws + 40000,  200, 200);

    // ---- CSR build for ALL 3 graphs (hoisted) ----
    fill_i32<<<nblk(3L * NUM_E), 256, 0, stream>>>(cnt, 3L * NUM_E, 0);
    count_dst3<<<nblk(3L * E_EDGES), 256, 0, stream>>>(dst, cnt);
    scan_rows3<<<3, 1024, 0, stream>>>(cnt, row_start, cursor, degf, invd);
    build_perm3<<<nblk(3L * E_EDGES), 256, 0, stream>>>(src, dst, etype, cursor, ssrc, setype);
    tenc_table3<<<2, 256, 0, stream>>>(ttbl, af, ap, cf, cp);
    tenc_fill3<<<nblk(3L * NUM_E * 6), 256, 0, stream>>>(bte3, degf, ttbl);

    // prev = l2norm(ent @ loop_weight)
    cvt_bf16_k<<<nblk(nE200), 256, 0, stream>>>(btmp, ent, nE200);
    {
        GemmDesc d0 = desc(bseg1(btmp, H_DIM, bLp_t, H_DIM, H_DIM),
                           tmp, nullptr, nullptr, NUM_E, H_DIM, H_DIM, 0, 1, 0);
        launch_multi(&d0, 1);
    }
    l2norm_rows4<<<r4, 256, 0, stream>>>(prev, bprev, tmp, NUM_E);

    for (int i = 0; i < N_HIST; i++) {
        const int* ssrc_g = ssrc + (long)i * E_EDGES;
        const int* sety_g = setype + (long)i * E_EDGES;
        const int* rs_g   = row_start + i * (NUM_E + 4);
        const float* iv_g = invd + i * NUM_E;
        ushort* bte_g     = bte3 + (long)i * NUM_E * TD_DIM;

        seg_gather_norm_bf<<<r4, 256, 0, stream>>>(bh0, bprev, ssrc_g, rs_g, iv_g);

        seg_gather_layer_bf<<<r4, 256, 0, stream>>>(btmp, bh0, brel, ssrc_g, sety_g, rs_g, iv_g);
        {
            GemmDesc d0 = desc(bseg2(btmp, H_DIM, bWn_t,         H_DIM, H_DIM,
                                     bh0,  H_DIM, bWs_t,         H_DIM, H_DIM),
                               nullptr, bh1, nullptr, NUM_E, H_DIM, H_DIM, 1, 2, 0);
            launch_multi(&d0, 1);
        }
        seg_gather_layer_bf<<<r4, 256, 0, stream>>>(btmp, bh1, brel, ssrc_g, sety_g, rs_g, iv_g);
        {
            GemmDesc d0 = desc(bseg2(btmp, H_DIM, bWn_t + 40000, H_DIM, H_DIM,
                                     bh1,  H_DIM, bWs_t + 40000, H_DIM, H_DIM),
                               nullptr, bh0, nullptr, NUM_E, H_DIM, H_DIM, 1, 2, 0);
            launch_multi(&d0, 1);
        }
        l2norm_bf4<<<r4, 256, 0, stream>>>(bh0, NUM_E);

        // Merged GRU GEMMs: rz (sigmoid, N=400), iN, hN — bf16 outputs (halves
        // trio write traffic; gates in [0,1] and tanh preacts tolerate bf16).
        // bh1/btmp are dead here (consumed by the layer GEMMs above).
        {
            GemmDesc d3[3];
            d3[0] = desc(bseg3(bh0,   H_DIM,  bW_ih,       248, H_DIM,
                               bte_g, TD_DIM, bW_ih + 200, 248, TD_DIM,
                               bprev, H_DIM,  bW_hh,       200, H_DIM),
                         nullptr, brz16, bsum, NUM_E, 400, 400, 2, 2, 0);
            d3[1] = desc(bseg2(bh0,   H_DIM,  bW_ih + 400*248,       248, H_DIM,
                               bte_g, TD_DIM, bW_ih + 400*248 + 200, 248, TD_DIM),
                         nullptr, bh1, b_ih + 400, NUM_E, H_DIM, H_DIM, 0, 2, 0);
            d3[2] = desc(bseg1(bprev, H_DIM, bW_hh + 400*200, 200, H_DIM),
                         nullptr, btmp, b_hh + 400, NUM_E, H_DIM, H_DIM, 0, 2, 0);
            launch_multi(d3, 3);
        }

        gru_fused<<<r4, 256, 0, stream>>>(prev, bprev, brz16, bh1, btmp);
    }

    // ---- batch head ----
    gather_qs_qr3<<<nblk((long)BATCH * H_DIM), 256, 0, stream>>>(qs3, qr3, prev, reln, data);
    semb_kernel<<<dim3(BATCH, 3), 64, 0, stream>>>(semb, prev, his_idx, his_len);
    tenc_batch<<<nblk(3L * BATCH * TD_DIM), 256, 0, stream>>>(teb, his_len, af, ap, cf, cp);

    // abuf = relu([qs|qr|semb|teb] @ Wb_w^T + Wb_b)   -- split-K, partials in h1
    {
        const int KS = 8;
        const int MN = 3 * BATCH * H_DIM;
        splitk(h1, seg4(qs3, H_DIM,  Wb_w,       648, H_DIM,
                        qr3, H_DIM,  Wb_w + 200, 648, H_DIM,
                        semb, H_DIM, Wb_w + 400, 648, H_DIM,
                        teb, TD_DIM, Wb_w + 600, 648, TD_DIM),
               3 * BATCH, H_DIM, KS);
        reduce_relu<<<nblk(MN), 256, 0, stream>>>(abuf, h1, Wb_b, MN, H_DIM, KS);
    }
    att_logits_rows<<<(3 * BATCH + 3) / 4, 256, 0, stream>>>(atts, abuf, Wc_w, Wc_b);
    softmax_out2<<<nblk((long)BATCH * H_DIM), 256, 0, stream>>>(out2, atts, semb);

    // qbuf = relu([qs|qr|out2] @ Wd_w^T + Wd_b) -> hi/lo bf16 split (partials in tmp)
    {
        const int KS = 8;
        const int MN = BATCH * H_DIM;
        splitk(tmp, seg3(qs3, H_DIM,  Wd_w,       600, H_DIM,
                         qr3, H_DIM,  Wd_w + 200, 600, H_DIM,
                         out2, H_DIM, Wd_w + 400, 600, H_DIM),
               BATCH, H_DIM, KS);
        reduce_relu_split<<<nblk(MN), 256, 0, stream>>>(qhi, qlo, tmp, Wd_b, MN, H_DIM, KS);
    }

    // plo = bf16(prev - f32(bprev))  (bprev is the hi part)
    make_lo<<<nblk(nE200), 256, 0, stream>>>(plo, prev, bprev, nE200);

    // result = q @ prev^T via hi/lo-compensated bf16 MFMA:
    //   qhi@phi + qhi@plo + qlo@phi   (3 K-segments, Ktot=600), B-reuse tile order
    {
        GemmDesc d0 = desc(bseg3(qhi, H_DIM, bprev, H_DIM, H_DIM,
                                 qhi, H_DIM, plo,   H_DIM, H_DIM,
                                 qlo, H_DIM, bprev, H_DIM, H_DIM),
                           out_p, nullptr, nullptr, BATCH, NUM_E, NUM_E, 0, 1, 1);
        launch_multi(&d0, 1);
    }
}